// Round 4
// baseline (337.767 us; speedup 1.0000x reference)
//
#include <hip/hip_runtime.h>
#include <hip/hip_bf16.h>
#include <math.h>

#define B_SZ 2
#define SEQ 4096
#define DMODEL 768
#define DSTATE 128
#define HEADDIM 64
#define DINNER 1536
#define NHEADS 24
#define DXBC 1792
#define DPROJ 3352
#define NPAD1 3456
#define CHUNK 128
#define NCHUNK 32
#define ROWS (B_SZ*SEQ)
#define LDTC 136   // padded LDS stride for conv input tile
#define LDE 136    // padded LDS stride (bf16) for epilogue tiles
#define LDE2 132   // padded LDS stride (fp32) for gemm2 epilogue tile

typedef float floatx4 __attribute__((ext_vector_type(4)));
typedef __bf16 bf16x8 __attribute__((ext_vector_type(8)));

__device__ __forceinline__ float sigmoidf_(float x){ return 1.f/(1.f+expf(-x)); }
__device__ __forceinline__ float siluf_(float x){ return x/(1.f+expf(-x)); }
__device__ __forceinline__ float softplusf_(float x){ return (x>20.f)? x : log1pf(expf(x)); }
__device__ __forceinline__ __bf16 cvt_bf(float x){ __hip_bfloat16 t = __float2bfloat16(x); return *(__bf16*)&t; }

__device__ __forceinline__ void gload_lds16(const __hip_bfloat16* g, __hip_bfloat16* l){
    __builtin_amdgcn_global_load_lds(
        (const __attribute__((address_space(1))) void*)g,
        (__attribute__((address_space(3))) void*)l, 16, 0, 0);
}

// ======== GEMM1: 256x128 tile, 8 waves; epilogue -> z16 / xbc16 / dtb ========
// R0-exact structure: BK=64, serial stage, 48 KiB LDS, 3 blocks/CU co-residency.
// Measured conflict-free LDS layout: 64-elem rows, 8-slot XOR swizzle (full
// 128B bank period from column bits alone). Do NOT shrink BK below 64: a 64B
// row folds row parity into the bank index -> measured 4-way conflict (R3).
__global__ __launch_bounds__(512)
void gemm1_mfma(const __hip_bfloat16* __restrict__ A,   // fbf [ROWS][768]
                const __hip_bfloat16* __restrict__ W,   // wbf [3456][768]
                __hip_bfloat16* __restrict__ z16, __hip_bfloat16* __restrict__ xbc16,
                float* __restrict__ dtb, const float* __restrict__ dt_bias)
{
    __shared__ __align__(16) char smem[49152];          // Asm 32K + Wsm 16K
    __hip_bfloat16* Asm = (__hip_bfloat16*)smem;        // [256][64]
    __hip_bfloat16* Wsm = Asm + 256*64;                 // [128][64]
    const int tid = threadIdx.x;
    const int lane = tid & 63, wave = tid >> 6;
    const int blk = blockIdx.x;
    const int m_tile = ((blk & 7) << 2) | ((blk >> 3) & 3);   // 32 M-tiles, XCD band
    const int bx = blk >> 5;                                   // N-tile 0..26
    const int bm = m_tile*256, bn = bx*128;
    const int wm = (wave & 3)*64, wn = (wave >> 2)*64;
    const int r16 = lane & 15, qbase = lane >> 4, sw = r16 & 7;
    floatx4 acc[4][4] = {};
    for (int k0 = 0; k0 < DMODEL; k0 += 64) {
#pragma unroll
        for (int j = 0; j < 4; ++j) {
            int cc = j*512 + tid;                // A: 2048 chunks
            int row = cc >> 3, jc = cc & 7;
            int sj = jc ^ (row & 7);
            gload_lds16(A + (size_t)(bm+row)*DMODEL + k0 + sj*8, Asm + cc*8);
        }
#pragma unroll
        for (int j = 0; j < 2; ++j) {
            int cc = j*512 + tid;                // W: 1024 chunks
            int row = cc >> 3, jc = cc & 7;
            int sj = jc ^ (row & 7);
            gload_lds16(W + (size_t)(bn+row)*DMODEL + k0 + sj*8, Wsm + cc*8);
        }
        __syncthreads();
#pragma unroll
        for (int ks = 0; ks < 2; ++ks) {
            const int kq = ((qbase + ks*4) ^ sw)*8;
            bf16x8 af[4], wf[4];
#pragma unroll
            for (int i = 0; i < 4; ++i) {
                af[i] = *(const bf16x8*)(Asm + (wm + i*16 + r16)*64 + kq);
                wf[i] = *(const bf16x8*)(Wsm + (wn + i*16 + r16)*64 + kq);
            }
#pragma unroll
            for (int mi = 0; mi < 4; ++mi)
#pragma unroll
                for (int ni = 0; ni < 4; ++ni)
                    acc[mi][ni] = __builtin_amdgcn_mfma_f32_16x16x32_bf16(
                        af[mi], wf[ni], acc[mi][ni], 0, 0, 0);
        }
        __syncthreads();
    }
    const int col = lane & 15, rowq = (lane >> 4)*4;
    if (bx == 26) {
        if (wn == 0) {
#pragma unroll
            for (int mi = 0; mi < 4; ++mi)
#pragma unroll
                for (int ni = 0; ni < 2; ++ni) {
                    int h = ni*16 + col;
                    if (h < NHEADS)
#pragma unroll
                        for (int r = 0; r < 4; ++r) {
                            int m = bm + wm + mi*16 + rowq + r;
                            dtb[(size_t)m*NHEADS + h] =
                                softplusf_(acc[mi][ni][r] + dt_bias[h]);
                        }
                }
        }
        return;
    }
    __hip_bfloat16* Tsm = (__hip_bfloat16*)smem;   // [128][LDE]
    __hip_bfloat16* dst; int ldd;
    if (bx < 12) { dst = z16 + bn;            ldd = DINNER; }
    else         { dst = xbc16 + bn - DINNER; ldd = DXBC;  }
    for (int half = 0; half < 2; ++half) {
        if (((wave & 3) >> 1) == half) {
#pragma unroll
            for (int mi = 0; mi < 4; ++mi)
#pragma unroll
                for (int ni = 0; ni < 4; ++ni)
#pragma unroll
                    for (int r = 0; r < 4; ++r)
                        Tsm[(wm - half*128 + mi*16 + rowq + r)*LDE + wn + ni*16 + col] =
                            __float2bfloat16(acc[mi][ni][r]);
        }
        __syncthreads();
#pragma unroll
        for (int it = 0; it < 4; ++it) {
            int e = it*512 + tid;
            int row = e >> 4, c0 = (e & 15)*8;
            bf16x8 v = *(const bf16x8*)(Tsm + row*LDE + c0);
            *(bf16x8*)(dst + (size_t)(bm + half*128 + row)*ldd + c0) = v;
        }
        __syncthreads();
    }
}

// ======== GEMM2: 256x128 tile; out = sig(gate)*rms_scale_r*(g @ Wn^T) + feature ====
__global__ __launch_bounds__(512)
void gemm2_mfma(const __hip_bfloat16* __restrict__ A,   // y16 [ROWS][1536] (gated)
                const __hip_bfloat16* __restrict__ W,   // owbf [768][1536]
                float* __restrict__ C,
                const float* __restrict__ gate, const float* __restrict__ resid,
                const float* __restrict__ rowsq)
{
    __shared__ __align__(16) char smem[49152];
    __shared__ float scale_lds[256];
    __hip_bfloat16* Asm = (__hip_bfloat16*)smem;        // [256][64]
    __hip_bfloat16* Wsm = Asm + 256*64;                 // [128][64]
    const int tid = threadIdx.x;
    const int lane = tid & 63, wave = tid >> 6;
    const int blk = blockIdx.x;
    const int m_tile = ((blk & 7) << 2) | ((blk >> 3) & 3);
    const int bm = m_tile*256, bn = (blk >> 5)*128;     // n-tile 0..5
    const int wm = (wave & 3)*64, wn = (wave >> 2)*64;
    const int r16 = lane & 15, qbase = lane >> 4, sw = r16 & 7;
    floatx4 acc[4][4] = {};
    for (int k0 = 0; k0 < DINNER; k0 += 64) {
#pragma unroll
        for (int j = 0; j < 4; ++j) {
            int cc = j*512 + tid;
            int row = cc >> 3, jc = cc & 7;
            int sj = jc ^ (row & 7);
            gload_lds16(A + (size_t)(bm+row)*DINNER + k0 + sj*8, Asm + cc*8);
        }
#pragma unroll
        for (int j = 0; j < 2; ++j) {
            int cc = j*512 + tid;
            int row = cc >> 3, jc = cc & 7;
            int sj = jc ^ (row & 7);
            gload_lds16(W + (size_t)(bn+row)*DINNER + k0 + sj*8, Wsm + cc*8);
        }
        __syncthreads();
#pragma unroll
        for (int ks = 0; ks < 2; ++ks) {
            const int kq = ((qbase + ks*4) ^ sw)*8;
            bf16x8 af[4], wf[4];
#pragma unroll
            for (int i = 0; i < 4; ++i) {
                af[i] = *(const bf16x8*)(Asm + (wm + i*16 + r16)*64 + kq);
                wf[i] = *(const bf16x8*)(Wsm + (wn + i*16 + r16)*64 + kq);
            }
#pragma unroll
            for (int mi = 0; mi < 4; ++mi)
#pragma unroll
                for (int ni = 0; ni < 4; ++ni)
                    acc[mi][ni] = __builtin_amdgcn_mfma_f32_16x16x32_bf16(
                        af[mi], wf[ni], acc[mi][ni], 0, 0, 0);
        }
        __syncthreads();
    }
    if (tid < 256)
        scale_lds[tid] = rsqrtf(rowsq[bm + tid] * (1.f/DINNER) + 1e-5f);
    float gs = sigmoidf_(gate[0]);
    __syncthreads();
    const int col = lane & 15, rowq = (lane >> 4)*4;
    float* Tsm = (float*)smem;   // 64 x LDE2 fp32
    for (int qp = 0; qp < 4; ++qp) {
        if ((wave & 3) == qp) {
#pragma unroll
            for (int mi = 0; mi < 4; ++mi)
#pragma unroll
                for (int ni = 0; ni < 4; ++ni)
#pragma unroll
                    for (int r = 0; r < 4; ++r)
                        Tsm[(mi*16 + rowq + r)*LDE2 + wn + ni*16 + col] = acc[mi][ni][r];
        }
        __syncthreads();
#pragma unroll
        for (int it = 0; it < 4; ++it) {
            int e = it*512 + tid;
            int row = e >> 5, c0 = (e & 31)*4;
            float4 v = *(const float4*)(Tsm + row*LDE2 + c0);
            float sc = gs * scale_lds[qp*64 + row];
            size_t off = (size_t)(bm + qp*64 + row)*DMODEL + bn + c0;
            float4 rv = *(const float4*)(resid + off);
            v.x = sc*v.x + rv.x; v.y = sc*v.y + rv.y;
            v.z = sc*v.z + rv.z; v.w = sc*v.w + rv.w;
            *(float4*)(C + off) = v;
        }
        __syncthreads();
    }
}

// ---------------- fused fp32 -> bf16 casts, vectorized 8 elem/thread ----------------
#define NC1 (ROWS*DMODEL)
#define NC2 (NPAD1*DMODEL)
#define NC3 (DMODEL*DINNER)
#define NV1 (NC1/8)
#define NV2 (NC2/8)
#define NV3 (NC3/8)
__global__ __launch_bounds__(256)
void cast_all(const float* __restrict__ feature, const float* __restrict__ in_w,
              const float* __restrict__ out_w, const float* __restrict__ nw,
              __hip_bfloat16* __restrict__ fbf, __hip_bfloat16* __restrict__ wbf,
              __hip_bfloat16* __restrict__ owbf)
{
    int v = blockIdx.x*256 + threadIdx.x;
    if (v < NV1) {
        int i = v*8;
        float4 a = *(const float4*)(feature + i);
        float4 b = *(const float4*)(feature + i + 4);
        bf16x8 o;
        o[0]=cvt_bf(a.x); o[1]=cvt_bf(a.y); o[2]=cvt_bf(a.z); o[3]=cvt_bf(a.w);
        o[4]=cvt_bf(b.x); o[5]=cvt_bf(b.y); o[6]=cvt_bf(b.z); o[7]=cvt_bf(b.w);
        *(bf16x8*)(fbf + i) = o;
    } else if (v < NV1 + NV2) {
        int j = (v - NV1)*8;
        int n = j / DMODEL, k = j - n*DMODEL;
        bf16x8 o;
        if (n < DPROJ) {
            const float* s = in_w + (size_t)n*DMODEL + k;
            float4 a = *(const float4*)(s);
            float4 b = *(const float4*)(s + 4);
            o[0]=cvt_bf(a.x); o[1]=cvt_bf(a.y); o[2]=cvt_bf(a.z); o[3]=cvt_bf(a.w);
            o[4]=cvt_bf(b.x); o[5]=cvt_bf(b.y); o[6]=cvt_bf(b.z); o[7]=cvt_bf(b.w);
        } else {
#pragma unroll
            for (int q = 0; q < 8; ++q) o[q] = (__bf16)0.f;
        }
        *(bf16x8*)(wbf + j) = o;
    } else if (v < NV1 + NV2 + NV3) {
        int j = (v - NV1 - NV2)*8;
        int k = j % DINNER;
        float4 a  = *(const float4*)(out_w + j);
        float4 b  = *(const float4*)(out_w + j + 4);
        float4 na = *(const float4*)(nw + k);
        float4 nb = *(const float4*)(nw + k + 4);
        bf16x8 o;
        o[0]=cvt_bf(a.x*na.x); o[1]=cvt_bf(a.y*na.y); o[2]=cvt_bf(a.z*na.z); o[3]=cvt_bf(a.w*na.w);
        o[4]=cvt_bf(b.x*nb.x); o[5]=cvt_bf(b.y*nb.y); o[6]=cvt_bf(b.z*nb.z); o[7]=cvt_bf(b.w*nb.w);
        *(bf16x8*)(owbf + j) = o;
    }
}

// ======== conv4+SiLU, emits x_t/B_n/B_t/C_n in MFMA-ready layouts ========
__global__ __launch_bounds__(256)
void conv_k(const __hip_bfloat16* __restrict__ xbc16, const float* __restrict__ cw,
            const float* __restrict__ cbias,
            __hip_bfloat16* __restrict__ x_t,
            __hip_bfloat16* __restrict__ B_n, __hip_bfloat16* __restrict__ B_t,
            __hip_bfloat16* __restrict__ C_n)
{
    __shared__ __align__(16) __hip_bfloat16 in[131*LDTC];
    int ct = blockIdx.x, lt = blockIdx.y, b = blockIdx.z;
    int tid = threadIdx.x;
    int base = lt*128;
    for (int it = 0; it < 2096; it += 256) {
        int e = it + tid; if (e >= 2096) break;
        int row = e >> 4, c0 = (e & 15)*8;
        int l = base - 3 + row;
        bf16x8 v;
        if (l < 0) { for (int j = 0; j < 8; ++j) v[j] = (__bf16)0.f; }
        else v = *(const bf16x8*)(xbc16 + ((size_t)b*SEQ + l)*DXBC + ct*128 + c0);
        *(bf16x8*)(in + row*LDTC + c0) = v;
    }
    __syncthreads();
    int ch = tid & 127, lh = tid >> 7, l0 = lh*64;
    int g = ct*128 + ch;
    float w0 = cw[g*4+0], w1 = cw[g*4+1], w2 = cw[g*4+2], w3 = cw[g*4+3];
    float bias = cbias[g];
    float a0 = __bfloat162float(in[(l0+0)*LDTC + ch]);
    float a1 = __bfloat162float(in[(l0+1)*LDTC + ch]);
    float a2 = __bfloat162float(in[(l0+2)*LDTC + ch]);
    size_t trow = 0;
    if (ct < 12)      trow = ((size_t)b*NHEADS + (g>>6))*HEADDIM + (g & 63);
    else if (ct == 12) trow = (size_t)b*DSTATE + ch;
    bf16x8 obuf;
#pragma unroll
    for (int li = 0; li < 64; ++li) {
        float a3 = __bfloat162float(in[(l0+li+3)*LDTC + ch]);
        float o = siluf_(bias + w0*a0 + w1*a1 + w2*a2 + w3*a3);
        a0 = a1; a1 = a2; a2 = a3;
        __hip_bfloat16 ob = __float2bfloat16(o);
        size_t rr = (size_t)b*SEQ + base + l0 + li;
        if (ct == 12)      B_n[rr*DSTATE + ch] = ob;
        else if (ct == 13) C_n[rr*DSTATE + ch] = ob;
        obuf[li & 7] = *(const __bf16*)&ob;
        if ((li & 7) == 7 && ct <= 12) {
            __hip_bfloat16* dst = (ct < 12) ? x_t : B_t;
            *(bf16x8*)(dst + trow*SEQ + base + l0 + (li - 7)) = obuf;
        }
    }
}

// ---------------- intra-chunk inclusive cumsum of dt*A ----------------
__global__ __launch_bounds__(128)
void scan_k(const float* __restrict__ dtb, const float* __restrict__ A_log,
            float* __restrict__ acum)
{
    int c = blockIdx.x & 31;
    int h = (blockIdx.x >> 5) % NHEADS;
    int b = blockIdx.x / (32*NHEADS);
    int l = threadIdx.x;
    float A = -expf(A_log[h]);
    size_t row = (size_t)b*SEQ + c*CHUNK + l;
    float v = dtb[row*NHEADS + h] * A;
    __shared__ float sh[128];
    sh[l] = v; __syncthreads();
    for (int off=1; off<128; off<<=1){
        float t = (l>=off) ? sh[l-off] : 0.f;
        __syncthreads();
        sh[l] += t;
        __syncthreads();
    }
    acum[((b*NHEADS+h)*NCHUNK + c)*CHUNK + l] = sh[l];
}

// ======== CB[l][s] = sum_n C[l][n]*B[s][n], per (b,c), LDS-free, tril tiles only ========
__global__ __launch_bounds__(256)
void cb_mfma(const __hip_bfloat16* __restrict__ B_n, const __hip_bfloat16* __restrict__ C_n,
             __hip_bfloat16* __restrict__ CB16)
{
    int c = blockIdx.x & 31, b = blockIdx.x >> 5;
    size_t base = (size_t)b*SEQ + c*CHUNK;
    int tid = threadIdx.x, lane = tid & 63, wave = tid >> 6;
    int r16 = lane & 15, kq = (lane>>4)*8;
    floatx4 acc[2][8] = {};
#pragma unroll
    for (int ks = 0; ks < 4; ++ks) {
        int k0 = ks*32 + kq;
        bf16x8 af[2], bfv[8];
#pragma unroll
        for (int mt = 0; mt < 2; ++mt)
            af[mt] = *(const bf16x8*)(C_n + (base + (wave*2+mt)*16 + r16)*DSTATE + k0);
#pragma unroll
        for (int st = 0; st < 8; ++st)
            bfv[st] = *(const bf16x8*)(B_n + (base + st*16 + r16)*DSTATE + k0);
#pragma unroll
        for (int mt = 0; mt < 2; ++mt)
#pragma unroll
            for (int st = 0; st < 8; ++st)
                if (st <= wave*2+mt)
                    acc[mt][st] = __builtin_amdgcn_mfma_f32_16x16x32_bf16(
                        af[mt], bfv[st], acc[mt][st], 0,0,0);
    }
    size_t cbb = (size_t)(b*NCHUNK+c)*CHUNK*CHUNK;
    int scol = lane & 15, rowq = (lane>>4)*4;
#pragma unroll
    for (int mt = 0; mt < 2; ++mt)
#pragma unroll
        for (int st = 0; st < 8; ++st)
            if (st <= wave*2+mt)
#pragma unroll
                for (int r = 0; r < 4; ++r)
                    CB16[cbb + (size_t)((wave*2+mt)*16 + rowq + r)*CHUNK + st*16 + scol] =
                        __float2bfloat16(acc[mt][st][r]);
}

// ======== states[p][n] = sum_l (x[l,p]*f[l]) * B[l,n], f = dt*dec ========
__global__ __launch_bounds__(256)
void states_mfma(const __hip_bfloat16* __restrict__ x_t, const __hip_bfloat16* __restrict__ B_t,
                 const float* __restrict__ dtb, const float* __restrict__ acum,
                 __hip_bfloat16* __restrict__ states)
{
    __shared__ float f[128];
    int c = blockIdx.x & 31;
    int h = (blockIdx.x>>5) % NHEADS;
    int b = blockIdx.x/(32*NHEADS);
    int tid = threadIdx.x, lane = tid & 63, wave = tid >> 6;
    int arow = ((b*NHEADS+h)*NCHUNK + c)*CHUNK;
    size_t rbase = (size_t)b*SEQ + c*CHUNK;
    if (tid < 128) {
        float alast = acum[arow + 127];
        f[tid] = dtb[(rbase + tid)*NHEADS + h] * expf(alast - acum[arow + tid]);
    }
    __syncthreads();
    int r16 = lane & 15, kq = (lane>>4)*8;
    size_t xtb = ((size_t)b*NHEADS + h)*HEADDIM;
    int cl = c*CHUNK;
    floatx4 acc[8] = {};
#pragma unroll
    for (int ks = 0; ks < 4; ++ks) {
        int k0 = ks*32 + kq;
        bf16x8 xa = *(const bf16x8*)(x_t + (xtb + wave*16 + r16)*SEQ + cl + k0);
        bf16x8 af;
#pragma unroll
        for (int j = 0; j < 8; ++j)
            af[j] = (__bf16)((float)xa[j] * f[k0 + j]);
        bf16x8 bfv[8];
#pragma unroll
        for (int nt = 0; nt < 8; ++nt)
            bfv[nt] = *(const bf16x8*)(B_t + ((size_t)b*DSTATE + nt*16 + r16)*SEQ + cl + k0);
#pragma unroll
        for (int nt = 0; nt < 8; ++nt)
            acc[nt] = __builtin_amdgcn_mfma_f32_16x16x32_bf16(af, bfv[nt], acc[nt], 0,0,0);
    }
    size_t sb = ((size_t)(b*NCHUNK+c)*NHEADS + h)*(HEADDIM*DSTATE);
    int ncol = lane & 15, rowq = (lane>>4)*4;
#pragma unroll
    for (int nt = 0; nt < 8; ++nt)
#pragma unroll
        for (int r = 0; r < 4; ++r)
            states[sb + (size_t)(wave*16 + rowq + r)*DSTATE + nt*16 + ncol] =
                __float2bfloat16(acc[nt][r]);
}

// ---- sequential inter-chunk recurrence, in place (bf16): states[c] := prev[c] ----
// All 32 chunk loads hoisted up front (independent addresses) so HBM/L2 latency
// is paid once, not 32x serially; the only serial chain left is the register FMA.
__global__ __launch_bounds__(256)
void recur_k(__hip_bfloat16* __restrict__ states, const float* __restrict__ acum)
{
    int pb = blockIdx.x & 3;
    int bh = blockIdx.x >> 2;
    int h = bh % NHEADS, b = bh / NHEADS;
    int voff = (pb*256 + threadIdx.x)*8;
    const size_t cstride = (size_t)NHEADS*HEADDIM*DSTATE;
    size_t base0 = ((size_t)(b*NCHUNK)*NHEADS + h)*(HEADDIM*DSTATE) + voff;
    bf16x8 st[NCHUNK];
    float ev[NCHUNK];
#pragma unroll
    for (int c = 0; c < NCHUNK; ++c)
        st[c] = *(const bf16x8*)(states + base0 + (size_t)c*cstride);
#pragma unroll
    for (int c = 0; c < NCHUNK; ++c)
        ev[c] = expf(acum[((b*NHEADS+h)*NCHUNK + c)*CHUNK + 127]);
    float S[8] = {};
#pragma unroll
    for (int c = 0; c < NCHUNK; ++c) {
        bf16x8 pv;
#pragma unroll
        for (int j = 0; j < 8; ++j) {
            pv[j] = (__bf16)S[j];
            S[j] = S[j]*ev[c] + (float)st[c][j];
        }
        *(bf16x8*)(states + base0 + (size_t)c*cstride) = pv;
    }
}

// ======== Y = [tril(CB*exp(dAc)*dt)+D*I] @ x + (C*exp(ac)) @ prev^T; then
//          g = Y*silu(z) -> y16; rowsq += per-row sum(g^2) (atomic) ========
__global__ __launch_bounds__(512)
void y_mfma(const __hip_bfloat16* __restrict__ x_t, const __hip_bfloat16* __restrict__ z16,
            const __hip_bfloat16* __restrict__ C_n, const __hip_bfloat16* __restrict__ CB16,
            const __hip_bfloat16* __restrict__ states, const float* __restrict__ dtb,
            const float* __restrict__ acum, const float* __restrict__ Dp,
            __hip_bfloat16* __restrict__ y16, float* __restrict__ rowsq)
{
    __shared__ float ac[128], dts[128];
    int c = blockIdx.x & 31;
    int h = (blockIdx.x>>5) % NHEADS;
    int b = blockIdx.x/(32*NHEADS);
    int tid = threadIdx.x, lane = tid & 63, wave = tid >> 6;
    int arow = ((b*NHEADS+h)*NCHUNK + c)*CHUNK;
    size_t rbase = (size_t)b*SEQ + c*CHUNK;
    if (tid < 128) {
        ac[tid]  = acum[arow + tid];
        dts[tid] = dtb[(rbase + tid)*NHEADS + h];
    }
    __syncthreads();
    int r16 = lane & 15, kq = (lane>>4)*8;
    int l = wave*16 + r16;
    float acl = ac[l];
    float Dh = Dp[h];
    size_t cbb = (size_t)(b*NCHUNK+c)*CHUNK*CHUNK;
    size_t xtb = ((size_t)b*NHEADS + h)*HEADDIM;
    int cl = c*CHUNK;
    floatx4 acc[4] = {};
    int nks = ((wave+1)*16 + 31) >> 5;
    for (int ks = 0; ks < nks; ++ks) {
        int k0 = ks*32 + kq;
        bf16x8 cbv = *(const bf16x8*)(CB16 + cbb + (size_t)l*CHUNK + k0);
        bf16x8 af;
#pragma unroll
        for (int j = 0; j < 8; ++j) {
            int s = k0 + j;
            float w = (s <= l) ? (float)cbv[j] * expf(acl - ac[s]) * dts[s] : 0.f;
            if (s == l) w += Dh;               // D*x folded into the diagonal
            af[j] = (__bf16)w;
        }
        bf16x8 bfv[4];
#pragma unroll
        for (int pt = 0; pt < 4; ++pt)
            bfv[pt] = *(const bf16x8*)(x_t + (xtb + pt*16 + r16)*SEQ + cl + k0);
#pragma unroll
        for (int pt = 0; pt < 4; ++pt)
            acc[pt] = __builtin_amdgcn_mfma_f32_16x16x32_bf16(af, bfv[pt], acc[pt], 0,0,0);
    }
    float eal = expf(acl);
    size_t sb = ((size_t)(b*NCHUNK+c)*NHEADS + h)*(HEADDIM*DSTATE);
#pragma unroll
    for (int ks = 0; ks < 4; ++ks) {
        int k0 = ks*32 + kq;
        bf16x8 cv = *(const bf16x8*)(C_n + (rbase + l)*DSTATE + k0);
        bf16x8 af;
#pragma unroll
        for (int j = 0; j < 8; ++j)
            af[j] = (__bf16)((float)cv[j] * eal);
        bf16x8 bfv[4];
#pragma unroll
        for (int pt = 0; pt < 4; ++pt)
            bfv[pt] = *(const bf16x8*)(states + sb + (size_t)(pt*16 + r16)*DSTATE + k0);
#pragma unroll
        for (int pt = 0; pt < 4; ++pt)
            acc[pt] = __builtin_amdgcn_mfma_f32_16x16x32_bf16(af, bfv[pt], acc[pt], 0,0,0);
    }
    // epilogue: g = acc * silu(z); store; per-row sumsq via shuffle + atomic
    int pcol = lane & 15, rowq = (lane>>4)*4;
    float sr[4] = {0.f, 0.f, 0.f, 0.f};
#pragma unroll
    for (int pt = 0; pt < 4; ++pt)
#pragma unroll
        for (int r = 0; r < 4; ++r) {
            int ll = wave*16 + rowq + r;
            int p = pt*16 + pcol;
            size_t rr = rbase + ll;
            float zv = __bfloat162float(z16[rr*DINNER + h*HEADDIM + p]);
            float g = acc[pt][r] * siluf_(zv);
            y16[rr*DINNER + h*HEADDIM + p] = __float2bfloat16(g);
            sr[r] += g*g;
        }
#pragma unroll
    for (int r = 0; r < 4; ++r) {
        float s = sr[r];
        s += __shfl_xor(s, 1); s += __shfl_xor(s, 2);
        s += __shfl_xor(s, 4); s += __shfl_xor(s, 8);
        if (pcol == 0)
            atomicAdd(rowsq + rbase + wave*16 + rowq + r, s);
    }
}

extern "C" void kernel_launch(void* const* d_in, const int* in_sizes, int n_in,
                              void* d_out, int out_size, void* d_ws, size_t ws_size,
                              hipStream_t stream)
{
    const float* feature = (const float*)d_in[0];
    const float* gate1   = (const float*)d_in[1];
    const float* in_w    = (const float*)d_in[2];
    const float* conv_w  = (const float*)d_in[3];
    const float* conv_b  = (const float*)d_in[4];
    const float* dt_bias = (const float*)d_in[5];
    const float* A_log   = (const float*)d_in[6];
    const float* Dp      = (const float*)d_in[7];
    const float* norm_w  = (const float*)d_in[8];
    const float* out_w   = (const float*)d_in[9];
    float* out = (float*)d_out;

    // workspace layout — ~161 MB (< 256 MiB)
    char* p = (char*)d_ws;
    __hip_bfloat16* z16   = (__hip_bfloat16*)p; p += (size_t)ROWS*DINNER*2;  // 25.2 MB
    __hip_bfloat16* xbc16 = (__hip_bfloat16*)p; p += (size_t)ROWS*DXBC*2;    // 29.4 MB
    __hip_bfloat16* x_t   = (__hip_bfloat16*)p; p += (size_t)ROWS*DINNER*2;  // 25.2 MB
    __hip_bfloat16* B_n   = (__hip_bfloat16*)p; p += (size_t)ROWS*DSTATE*2;  // 2.1 MB
    __hip_bfloat16* B_t   = (__hip_bfloat16*)p; p += (size_t)ROWS*DSTATE*2;  // 2.1 MB
    __hip_bfloat16* C_n   = (__hip_bfloat16*)p; p += (size_t)ROWS*DSTATE*2;  // 2.1 MB
    float* dtb    = (float*)p;            p += (size_t)ROWS*NHEADS*4;        // 0.8 MB
    float* acum   = (float*)p;            p += (size_t)B_SZ*NHEADS*NCHUNK*CHUNK*4; // 0.8 MB
    float* rowsq  = (float*)p;            p += (size_t)ROWS*4;               // 32 KB
    __hip_bfloat16* CB16 = (__hip_bfloat16*)p; p += (size_t)B_SZ*NCHUNK*CHUNK*CHUNK*2; // 2.1 MB
    __hip_bfloat16* states = (__hip_bfloat16*)p; p += (size_t)B_SZ*NCHUNK*NHEADS*HEADDIM*DSTATE*2; // 25.2 MB
    __hip_bfloat16* y16  = (__hip_bfloat16*)p; p += (size_t)ROWS*DINNER*2;   // 25.2 MB
    __hip_bfloat16* fbf  = (__hip_bfloat16*)p; p += (size_t)ROWS*DMODEL*2;   // 12.6 MB
    __hip_bfloat16* wbf  = (__hip_bfloat16*)p; p += (size_t)NPAD1*DMODEL*2;  //  5.3 MB
    __hip_bfloat16* owbf = (__hip_bfloat16*)p; p += (size_t)DMODEL*DINNER*2; //  2.4 MB

    cast_all<<<(NV1+NV2+NV3+255)/256, 256, 0, stream>>>(feature, in_w, out_w, norm_w,
                                                        fbf, wbf, owbf);
    hipMemsetAsync(rowsq, 0, (size_t)ROWS*4, stream);

    gemm1_mfma<<<27*32, 512, 0, stream>>>(fbf, wbf, z16, xbc16, dtb, dt_bias);
    conv_k<<<dim3(14, 32, B_SZ), 256, 0, stream>>>(xbc16, conv_w, conv_b,
                                                   x_t, B_n, B_t, C_n);
    scan_k<<<B_SZ*NHEADS*NCHUNK, 128, 0, stream>>>(dtb, A_log, acum);
    cb_mfma<<<B_SZ*NCHUNK, 256, 0, stream>>>(B_n, C_n, CB16);
    states_mfma<<<B_SZ*NHEADS*NCHUNK, 256, 0, stream>>>(x_t, B_t, dtb, acum, states);
    recur_k<<<B_SZ*NHEADS*4, 256, 0, stream>>>(states, acum);
    y_mfma<<<B_SZ*NHEADS*NCHUNK, 512, 0, stream>>>(x_t, z16, C_n, CB16, states,
                                                   dtb, acum, Dp, y16, rowsq);
    gemm2_mfma<<<6*32, 512, 0, stream>>>(y16, owbf, out, gate1, feature, rowsq);
}

// Round 5
// 316.782 us; speedup vs baseline: 1.0662x; 1.0662x over previous
//
#include <hip/hip_runtime.h>
#include <hip/hip_bf16.h>
#include <math.h>

#define B_SZ 2
#define SEQ 4096
#define DMODEL 768
#define DSTATE 128
#define HEADDIM 64
#define DINNER 1536
#define NHEADS 24
#define DXBC 1792
#define DPROJ 3352
#define NPAD1 3456
#define CHUNK 128
#define NCHUNK 32
#define ROWS (B_SZ*SEQ)
#define LDTC 136   // padded LDS stride for conv input tile
#define LDE 136    // padded LDS stride (bf16) for epilogue tiles
#define LDE2 132   // padded LDS stride (fp32) for gemm2 epilogue tile

typedef float floatx4 __attribute__((ext_vector_type(4)));
typedef __bf16 bf16x8 __attribute__((ext_vector_type(8)));

// fast-exp variants: all consumers are bf16 casts / bf16 MFMA operands, so
// __expf's 2-4 ulp f32 error is far below bf16 rounding.
__device__ __forceinline__ float sigmoidf_(float x){ return 1.f/(1.f+__expf(-x)); }
__device__ __forceinline__ float siluf_(float x){ return x/(1.f+__expf(-x)); }
__device__ __forceinline__ float softplusf_(float x){ return (x>20.f)? x : __logf(1.f+__expf(x)); }
__device__ __forceinline__ __bf16 cvt_bf(float x){ __hip_bfloat16 t = __float2bfloat16(x); return *(__bf16*)&t; }

__device__ __forceinline__ void gload_lds16(const __hip_bfloat16* g, __hip_bfloat16* l){
    __builtin_amdgcn_global_load_lds(
        (const __attribute__((address_space(1))) void*)g,
        (__attribute__((address_space(3))) void*)l, 16, 0, 0);
}

// ======== GEMM1: 256x128 tile, 8 waves; epilogue -> z16 / xbc16 / dtb ========
// R0-exact structure: BK=64, serial stage, 48 KiB LDS, 3 blocks/CU co-residency.
// Measured conflict-free LDS layout: 64-elem rows, 8-slot XOR swizzle. Do NOT
// shrink BK below 64 (R3: 64B rows fold row parity into bank -> 4-way conflict).
__global__ __launch_bounds__(512)
void gemm1_mfma(const __hip_bfloat16* __restrict__ A,   // fbf [ROWS][768]
                const __hip_bfloat16* __restrict__ W,   // wbf [3456][768]
                __hip_bfloat16* __restrict__ z16, __hip_bfloat16* __restrict__ xbc16,
                float* __restrict__ dtb, const float* __restrict__ dt_bias)
{
    __shared__ __align__(16) char smem[49152];          // Asm 32K + Wsm 16K
    __hip_bfloat16* Asm = (__hip_bfloat16*)smem;        // [256][64]
    __hip_bfloat16* Wsm = Asm + 256*64;                 // [128][64]
    const int tid = threadIdx.x;
    const int lane = tid & 63, wave = tid >> 6;
    const int blk = blockIdx.x;
    const int m_tile = ((blk & 7) << 2) | ((blk >> 3) & 3);   // 32 M-tiles, XCD band
    const int bx = blk >> 5;                                   // N-tile 0..26
    const int bm = m_tile*256, bn = bx*128;
    const int wm = (wave & 3)*64, wn = (wave >> 2)*64;
    const int r16 = lane & 15, qbase = lane >> 4, sw = r16 & 7;
    floatx4 acc[4][4] = {};
    for (int k0 = 0; k0 < DMODEL; k0 += 64) {
#pragma unroll
        for (int j = 0; j < 4; ++j) {
            int cc = j*512 + tid;                // A: 2048 chunks
            int row = cc >> 3, jc = cc & 7;
            int sj = jc ^ (row & 7);
            gload_lds16(A + (size_t)(bm+row)*DMODEL + k0 + sj*8, Asm + cc*8);
        }
#pragma unroll
        for (int j = 0; j < 2; ++j) {
            int cc = j*512 + tid;                // W: 1024 chunks
            int row = cc >> 3, jc = cc & 7;
            int sj = jc ^ (row & 7);
            gload_lds16(W + (size_t)(bn+row)*DMODEL + k0 + sj*8, Wsm + cc*8);
        }
        __syncthreads();
#pragma unroll
        for (int ks = 0; ks < 2; ++ks) {
            const int kq = ((qbase + ks*4) ^ sw)*8;
            bf16x8 af[4], wf[4];
#pragma unroll
            for (int i = 0; i < 4; ++i) {
                af[i] = *(const bf16x8*)(Asm + (wm + i*16 + r16)*64 + kq);
                wf[i] = *(const bf16x8*)(Wsm + (wn + i*16 + r16)*64 + kq);
            }
#pragma unroll
            for (int mi = 0; mi < 4; ++mi)
#pragma unroll
                for (int ni = 0; ni < 4; ++ni)
                    acc[mi][ni] = __builtin_amdgcn_mfma_f32_16x16x32_bf16(
                        af[mi], wf[ni], acc[mi][ni], 0, 0, 0);
        }
        __syncthreads();
    }
    const int col = lane & 15, rowq = (lane >> 4)*4;
    if (bx == 26) {
        if (wn == 0) {
#pragma unroll
            for (int mi = 0; mi < 4; ++mi)
#pragma unroll
                for (int ni = 0; ni < 2; ++ni) {
                    int h = ni*16 + col;
                    if (h < NHEADS)
#pragma unroll
                        for (int r = 0; r < 4; ++r) {
                            int m = bm + wm + mi*16 + rowq + r;
                            dtb[(size_t)m*NHEADS + h] =
                                softplusf_(acc[mi][ni][r] + dt_bias[h]);
                        }
                }
        }
        return;
    }
    __hip_bfloat16* Tsm = (__hip_bfloat16*)smem;   // [128][LDE]
    __hip_bfloat16* dst; int ldd;
    if (bx < 12) { dst = z16 + bn;            ldd = DINNER; }
    else         { dst = xbc16 + bn - DINNER; ldd = DXBC;  }
    for (int half = 0; half < 2; ++half) {
        if (((wave & 3) >> 1) == half) {
#pragma unroll
            for (int mi = 0; mi < 4; ++mi)
#pragma unroll
                for (int ni = 0; ni < 4; ++ni)
#pragma unroll
                    for (int r = 0; r < 4; ++r)
                        Tsm[(wm - half*128 + mi*16 + rowq + r)*LDE + wn + ni*16 + col] =
                            __float2bfloat16(acc[mi][ni][r]);
        }
        __syncthreads();
#pragma unroll
        for (int it = 0; it < 4; ++it) {
            int e = it*512 + tid;
            int row = e >> 4, c0 = (e & 15)*8;
            bf16x8 v = *(const bf16x8*)(Tsm + row*LDE + c0);
            *(bf16x8*)(dst + (size_t)(bm + half*128 + row)*ldd + c0) = v;
        }
        __syncthreads();
    }
}

// ======== GEMM2: 256x128 tile; out = sig(gate)*rms_scale_r*(g @ Wn^T) + feature ====
__global__ __launch_bounds__(512)
void gemm2_mfma(const __hip_bfloat16* __restrict__ A,   // y16 [ROWS][1536] (gated)
                const __hip_bfloat16* __restrict__ W,   // owbf [768][1536]
                float* __restrict__ C,
                const float* __restrict__ gate, const float* __restrict__ resid,
                const float* __restrict__ rowsq)
{
    __shared__ __align__(16) char smem[49152];
    __shared__ float scale_lds[256];
    __hip_bfloat16* Asm = (__hip_bfloat16*)smem;        // [256][64]
    __hip_bfloat16* Wsm = Asm + 256*64;                 // [128][64]
    const int tid = threadIdx.x;
    const int lane = tid & 63, wave = tid >> 6;
    const int blk = blockIdx.x;
    const int m_tile = ((blk & 7) << 2) | ((blk >> 3) & 3);
    const int bm = m_tile*256, bn = (blk >> 5)*128;     // n-tile 0..5
    const int wm = (wave & 3)*64, wn = (wave >> 2)*64;
    const int r16 = lane & 15, qbase = lane >> 4, sw = r16 & 7;
    floatx4 acc[4][4] = {};
    for (int k0 = 0; k0 < DINNER; k0 += 64) {
#pragma unroll
        for (int j = 0; j < 4; ++j) {
            int cc = j*512 + tid;
            int row = cc >> 3, jc = cc & 7;
            int sj = jc ^ (row & 7);
            gload_lds16(A + (size_t)(bm+row)*DINNER + k0 + sj*8, Asm + cc*8);
        }
#pragma unroll
        for (int j = 0; j < 2; ++j) {
            int cc = j*512 + tid;
            int row = cc >> 3, jc = cc & 7;
            int sj = jc ^ (row & 7);
            gload_lds16(W + (size_t)(bn+row)*DINNER + k0 + sj*8, Wsm + cc*8);
        }
        __syncthreads();
#pragma unroll
        for (int ks = 0; ks < 2; ++ks) {
            const int kq = ((qbase + ks*4) ^ sw)*8;
            bf16x8 af[4], wf[4];
#pragma unroll
            for (int i = 0; i < 4; ++i) {
                af[i] = *(const bf16x8*)(Asm + (wm + i*16 + r16)*64 + kq);
                wf[i] = *(const bf16x8*)(Wsm + (wn + i*16 + r16)*64 + kq);
            }
#pragma unroll
            for (int mi = 0; mi < 4; ++mi)
#pragma unroll
                for (int ni = 0; ni < 4; ++ni)
                    acc[mi][ni] = __builtin_amdgcn_mfma_f32_16x16x32_bf16(
                        af[mi], wf[ni], acc[mi][ni], 0, 0, 0);
        }
        __syncthreads();
    }
    if (tid < 256)
        scale_lds[tid] = rsqrtf(rowsq[bm + tid] * (1.f/DINNER) + 1e-5f);
    float gs = sigmoidf_(gate[0]);
    __syncthreads();
    const int col = lane & 15, rowq = (lane >> 4)*4;
    float* Tsm = (float*)smem;   // 64 x LDE2 fp32
    for (int qp = 0; qp < 4; ++qp) {
        if ((wave & 3) == qp) {
#pragma unroll
            for (int mi = 0; mi < 4; ++mi)
#pragma unroll
                for (int ni = 0; ni < 4; ++ni)
#pragma unroll
                    for (int r = 0; r < 4; ++r)
                        Tsm[(mi*16 + rowq + r)*LDE2 + wn + ni*16 + col] = acc[mi][ni][r];
        }
        __syncthreads();
#pragma unroll
        for (int it = 0; it < 4; ++it) {
            int e = it*512 + tid;
            int row = e >> 5, c0 = (e & 31)*4;
            float4 v = *(const float4*)(Tsm + row*LDE2 + c0);
            float sc = gs * scale_lds[qp*64 + row];
            size_t off = (size_t)(bm + qp*64 + row)*DMODEL + bn + c0;
            float4 rv = *(const float4*)(resid + off);
            v.x = sc*v.x + rv.x; v.y = sc*v.y + rv.y;
            v.z = sc*v.z + rv.z; v.w = sc*v.w + rv.w;
            *(float4*)(C + off) = v;
        }
        __syncthreads();
    }
}

// ---------------- fused fp32 -> bf16 casts, vectorized 8 elem/thread ----------------
#define NC1 (ROWS*DMODEL)
#define NC2 (NPAD1*DMODEL)
#define NC3 (DMODEL*DINNER)
#define NV1 (NC1/8)
#define NV2 (NC2/8)
#define NV3 (NC3/8)
__global__ __launch_bounds__(256)
void cast_all(const float* __restrict__ feature, const float* __restrict__ in_w,
              const float* __restrict__ out_w, const float* __restrict__ nw,
              __hip_bfloat16* __restrict__ fbf, __hip_bfloat16* __restrict__ wbf,
              __hip_bfloat16* __restrict__ owbf)
{
    int v = blockIdx.x*256 + threadIdx.x;
    if (v < NV1) {
        int i = v*8;
        float4 a = *(const float4*)(feature + i);
        float4 b = *(const float4*)(feature + i + 4);
        bf16x8 o;
        o[0]=cvt_bf(a.x); o[1]=cvt_bf(a.y); o[2]=cvt_bf(a.z); o[3]=cvt_bf(a.w);
        o[4]=cvt_bf(b.x); o[5]=cvt_bf(b.y); o[6]=cvt_bf(b.z); o[7]=cvt_bf(b.w);
        *(bf16x8*)(fbf + i) = o;
    } else if (v < NV1 + NV2) {
        int j = (v - NV1)*8;
        int n = j / DMODEL, k = j - n*DMODEL;
        bf16x8 o;
        if (n < DPROJ) {
            const float* s = in_w + (size_t)n*DMODEL + k;
            float4 a = *(const float4*)(s);
            float4 b = *(const float4*)(s + 4);
            o[0]=cvt_bf(a.x); o[1]=cvt_bf(a.y); o[2]=cvt_bf(a.z); o[3]=cvt_bf(a.w);
            o[4]=cvt_bf(b.x); o[5]=cvt_bf(b.y); o[6]=cvt_bf(b.z); o[7]=cvt_bf(b.w);
        } else {
#pragma unroll
            for (int q = 0; q < 8; ++q) o[q] = (__bf16)0.f;
        }
        *(bf16x8*)(wbf + j) = o;
    } else if (v < NV1 + NV2 + NV3) {
        int j = (v - NV1 - NV2)*8;
        int k = j % DINNER;
        float4 a  = *(const float4*)(out_w + j);
        float4 b  = *(const float4*)(out_w + j + 4);
        float4 na = *(const float4*)(nw + k);
        float4 nb = *(const float4*)(nw + k + 4);
        bf16x8 o;
        o[0]=cvt_bf(a.x*na.x); o[1]=cvt_bf(a.y*na.y); o[2]=cvt_bf(a.z*na.z); o[3]=cvt_bf(a.w*na.w);
        o[4]=cvt_bf(b.x*nb.x); o[5]=cvt_bf(b.y*nb.y); o[6]=cvt_bf(b.z*nb.z); o[7]=cvt_bf(b.w*nb.w);
        *(bf16x8*)(owbf + j) = o;
    }
}

// ======== FUSED conv4+SiLU (blockIdx.x<14) + intra-chunk cumsum scan (>=14) ========
// Both depend only on gemm1 outputs; fusing removes one launch gap and overlaps
// conv's tail with scan's fill. Barriers are block-uniform (branch on blockIdx).
__global__ __launch_bounds__(256)
void conv_scan_k(const __hip_bfloat16* __restrict__ xbc16, const float* __restrict__ cw,
                 const float* __restrict__ cbias,
                 __hip_bfloat16* __restrict__ x_t,
                 __hip_bfloat16* __restrict__ B_n, __hip_bfloat16* __restrict__ B_t,
                 __hip_bfloat16* __restrict__ C_n,
                 const float* __restrict__ dtb, const float* __restrict__ A_log,
                 float* __restrict__ acum)
{
    int xb = blockIdx.x;
    if (xb >= 14) {
        // ---- scan path: h = xb-14, c = blockIdx.y, b = blockIdx.z ----
        // duplicated in both 128-halves for symmetric barrier participation.
        __shared__ float sh2[256];
        int h = xb - 14, c = blockIdx.y, b = blockIdx.z;
        int tid = threadIdx.x;
        int l = tid & 127, g2 = tid >> 7;
        float* sh = sh2 + g2*128;
        float Aa = -__expf(A_log[h]);
        size_t row = (size_t)b*SEQ + c*CHUNK + l;
        float v = dtb[row*NHEADS + h] * Aa;
        sh[l] = v; __syncthreads();
        for (int off=1; off<128; off<<=1){
            float t = (l>=off) ? sh[l-off] : 0.f;
            __syncthreads();
            sh[l] += t;
            __syncthreads();
        }
        if (g2 == 0)
            acum[((b*NHEADS+h)*NCHUNK + c)*CHUNK + l] = sh[l];
        return;
    }
    // ---- conv path ----
    __shared__ __align__(16) __hip_bfloat16 in[131*LDTC];
    int ct = xb, lt = blockIdx.y, b = blockIdx.z;
    int tid = threadIdx.x;
    int base = lt*128;
    for (int it = 0; it < 2096; it += 256) {
        int e = it + tid; if (e >= 2096) break;
        int row = e >> 4, c0 = (e & 15)*8;
        int l = base - 3 + row;
        bf16x8 v;
        if (l < 0) { for (int j = 0; j < 8; ++j) v[j] = (__bf16)0.f; }
        else v = *(const bf16x8*)(xbc16 + ((size_t)b*SEQ + l)*DXBC + ct*128 + c0);
        *(bf16x8*)(in + row*LDTC + c0) = v;
    }
    __syncthreads();
    int ch = tid & 127, lh = tid >> 7, l0 = lh*64;
    int g = ct*128 + ch;
    float w0 = cw[g*4+0], w1 = cw[g*4+1], w2 = cw[g*4+2], w3 = cw[g*4+3];
    float bias = cbias[g];
    float a0 = __bfloat162float(in[(l0+0)*LDTC + ch]);
    float a1 = __bfloat162float(in[(l0+1)*LDTC + ch]);
    float a2 = __bfloat162float(in[(l0+2)*LDTC + ch]);
    size_t trow = 0;
    if (ct < 12)      trow = ((size_t)b*NHEADS + (g>>6))*HEADDIM + (g & 63);
    else if (ct == 12) trow = (size_t)b*DSTATE + ch;
    bf16x8 obuf;
#pragma unroll
    for (int li = 0; li < 64; ++li) {
        float a3 = __bfloat162float(in[(l0+li+3)*LDTC + ch]);
        float o = siluf_(bias + w0*a0 + w1*a1 + w2*a2 + w3*a3);
        a0 = a1; a1 = a2; a2 = a3;
        __hip_bfloat16 ob = __float2bfloat16(o);
        size_t rr = (size_t)b*SEQ + base + l0 + li;
        if (ct == 12)      B_n[rr*DSTATE + ch] = ob;
        else if (ct == 13) C_n[rr*DSTATE + ch] = ob;
        obuf[li & 7] = *(const __bf16*)&ob;
        if ((li & 7) == 7 && ct <= 12) {
            __hip_bfloat16* dst = (ct < 12) ? x_t : B_t;
            *(bf16x8*)(dst + trow*SEQ + base + l0 + (li - 7)) = obuf;
        }
    }
}

// ======== FUSED CB (blockIdx.x<64) + states (>=64) ========
// Both depend on conv+scan outputs only.
__global__ __launch_bounds__(256)
void cbst_k(const __hip_bfloat16* __restrict__ B_n, const __hip_bfloat16* __restrict__ C_n,
            __hip_bfloat16* __restrict__ CB16,
            const __hip_bfloat16* __restrict__ x_t, const __hip_bfloat16* __restrict__ B_t,
            const float* __restrict__ dtb, const float* __restrict__ acum,
            __hip_bfloat16* __restrict__ states)
{
    int bid = blockIdx.x;
    int tid = threadIdx.x, lane = tid & 63, wave = tid >> 6;
    if (bid < 64) {
        // ---- CB[l][s] = sum_n C[l][n]*B[s][n], tril tiles only ----
        int c = bid & 31, b = bid >> 5;
        size_t base = (size_t)b*SEQ + c*CHUNK;
        int r16 = lane & 15, kq = (lane>>4)*8;
        floatx4 acc[2][8] = {};
#pragma unroll
        for (int ks = 0; ks < 4; ++ks) {
            int k0 = ks*32 + kq;
            bf16x8 af[2], bfv[8];
#pragma unroll
            for (int mt = 0; mt < 2; ++mt)
                af[mt] = *(const bf16x8*)(C_n + (base + (wave*2+mt)*16 + r16)*DSTATE + k0);
#pragma unroll
            for (int st = 0; st < 8; ++st)
                bfv[st] = *(const bf16x8*)(B_n + (base + st*16 + r16)*DSTATE + k0);
#pragma unroll
            for (int mt = 0; mt < 2; ++mt)
#pragma unroll
                for (int st = 0; st < 8; ++st)
                    if (st <= wave*2+mt)
                        acc[mt][st] = __builtin_amdgcn_mfma_f32_16x16x32_bf16(
                            af[mt], bfv[st], acc[mt][st], 0,0,0);
        }
        size_t cbb = (size_t)(b*NCHUNK+c)*CHUNK*CHUNK;
        int scol = lane & 15, rowq = (lane>>4)*4;
#pragma unroll
        for (int mt = 0; mt < 2; ++mt)
#pragma unroll
            for (int st = 0; st < 8; ++st)
                if (st <= wave*2+mt)
#pragma unroll
                    for (int r = 0; r < 4; ++r)
                        CB16[cbb + (size_t)((wave*2+mt)*16 + rowq + r)*CHUNK + st*16 + scol] =
                            __float2bfloat16(acc[mt][st][r]);
        return;
    }
    // ---- states[p][n] = sum_l (x[l,p]*f[l]) * B[l,n], f = dt*dec ----
    __shared__ float f[128];
    int t = bid - 64;
    int c = t & 31;
    int h = (t>>5) % NHEADS;
    int b = t/(32*NHEADS);
    int arow = ((b*NHEADS+h)*NCHUNK + c)*CHUNK;
    size_t rbase = (size_t)b*SEQ + c*CHUNK;
    if (tid < 128) {
        float alast = acum[arow + 127];
        f[tid] = dtb[(rbase + tid)*NHEADS + h] * __expf(alast - acum[arow + tid]);
    }
    __syncthreads();
    int r16 = lane & 15, kq = (lane>>4)*8;
    size_t xtb = ((size_t)b*NHEADS + h)*HEADDIM;
    int cl = c*CHUNK;
    floatx4 acc[8] = {};
#pragma unroll
    for (int ks = 0; ks < 4; ++ks) {
        int k0 = ks*32 + kq;
        bf16x8 xa = *(const bf16x8*)(x_t + (xtb + wave*16 + r16)*SEQ + cl + k0);
        bf16x8 af;
#pragma unroll
        for (int j = 0; j < 8; ++j)
            af[j] = (__bf16)((float)xa[j] * f[k0 + j]);
        bf16x8 bfv[8];
#pragma unroll
        for (int nt = 0; nt < 8; ++nt)
            bfv[nt] = *(const bf16x8*)(B_t + ((size_t)b*DSTATE + nt*16 + r16)*SEQ + cl + k0);
#pragma unroll
        for (int nt = 0; nt < 8; ++nt)
            acc[nt] = __builtin_amdgcn_mfma_f32_16x16x32_bf16(af, bfv[nt], acc[nt], 0,0,0);
    }
    size_t sb = ((size_t)(b*NCHUNK+c)*NHEADS + h)*(HEADDIM*DSTATE);
    int ncol = lane & 15, rowq = (lane>>4)*4;
#pragma unroll
    for (int nt = 0; nt < 8; ++nt)
#pragma unroll
        for (int r = 0; r < 4; ++r)
            states[sb + (size_t)(wave*16 + rowq + r)*DSTATE + nt*16 + ncol] =
                __float2bfloat16(acc[nt][r]);
}

// ---- sequential inter-chunk recurrence, in place (bf16): states[c] := prev[c] ----
// 64-thread blocks x 768: covers all 256 CUs (192x256 left 64 CUs idle).
// All 32 chunk loads hoisted up front so HBM/L2 latency is paid once.
__global__ __launch_bounds__(64)
void recur_k(__hip_bfloat16* __restrict__ states, const float* __restrict__ acum)
{
    int pb = blockIdx.x & 15;
    int bh = blockIdx.x >> 4;
    int h = bh % NHEADS, b = bh / NHEADS;
    int voff = (pb*64 + threadIdx.x)*8;
    const size_t cstride = (size_t)NHEADS*HEADDIM*DSTATE;
    size_t base0 = ((size_t)(b*NCHUNK)*NHEADS + h)*(HEADDIM*DSTATE) + voff;
    bf16x8 st[NCHUNK];
    float ev[NCHUNK];
#pragma unroll
    for (int c = 0; c < NCHUNK; ++c)
        st[c] = *(const bf16x8*)(states + base0 + (size_t)c*cstride);
#pragma unroll
    for (int c = 0; c < NCHUNK; ++c)
        ev[c] = __expf(acum[((b*NHEADS+h)*NCHUNK + c)*CHUNK + 127]);
    float S[8] = {};
#pragma unroll
    for (int c = 0; c < NCHUNK; ++c) {
        bf16x8 pv;
#pragma unroll
        for (int j = 0; j < 8; ++j) {
            pv[j] = (__bf16)S[j];
            S[j] = S[j]*ev[c] + (float)st[c][j];
        }
        *(bf16x8*)(states + base0 + (size_t)c*cstride) = pv;
    }
}

// ======== Y = [tril(CB*exp(dAc)*dt)+D*I] @ x + (C*exp(ac)) @ prev^T; then
//          g = Y*silu(z) -> y16; rowsq += per-row sum(g^2) (atomic) ========
// exp factored out of the hot loop: exp(acl-ac[s])*dt[s] =
//   exp(acl-ac[kb]) * [exp(ac[kb]-ac[s])*dt[s]]   (kb = 32-aligned block base)
// bracket precomputed once into LDS gk[128]; kb<=l always so the per-lane
// factor fl<=1 (no overflow); gk bounded by exp(~32*|dtA|max) — in fp32 range.
__global__ __launch_bounds__(512)
void y_mfma(const __hip_bfloat16* __restrict__ x_t, const __hip_bfloat16* __restrict__ z16,
            const __hip_bfloat16* __restrict__ C_n, const __hip_bfloat16* __restrict__ CB16,
            const __hip_bfloat16* __restrict__ states, const float* __restrict__ dtb,
            const float* __restrict__ acum, const float* __restrict__ Dp,
            __hip_bfloat16* __restrict__ y16, float* __restrict__ rowsq)
{
    __shared__ float ac[128], dts[128], gk[128];
    int c = blockIdx.x & 31;
    int h = (blockIdx.x>>5) % NHEADS;
    int b = blockIdx.x/(32*NHEADS);
    int tid = threadIdx.x, lane = tid & 63, wave = tid >> 6;
    int arow = ((b*NHEADS+h)*NCHUNK + c)*CHUNK;
    size_t rbase = (size_t)b*SEQ + c*CHUNK;
    if (tid < 128) {
        ac[tid]  = acum[arow + tid];
        dts[tid] = dtb[(rbase + tid)*NHEADS + h];
    }
    __syncthreads();
    if (tid < 128)
        gk[tid] = __expf(ac[tid & 96] - ac[tid]) * dts[tid];
    __syncthreads();
    int r16 = lane & 15, kq = (lane>>4)*8;
    int l = wave*16 + r16;
    float acl = ac[l];
    float Dh = Dp[h];
    size_t cbb = (size_t)(b*NCHUNK+c)*CHUNK*CHUNK;
    size_t xtb = ((size_t)b*NHEADS + h)*HEADDIM;
    int cl = c*CHUNK;
    floatx4 acc[4] = {};
    int nks = ((wave+1)*16 + 31) >> 5;
    for (int ks = 0; ks < nks; ++ks) {
        int k0 = ks*32 + kq;
        float fl = __expf(acl - ac[ks*32]);   // <= 1 (kb <= l)
        bf16x8 cbv = *(const bf16x8*)(CB16 + cbb + (size_t)l*CHUNK + k0);
        bf16x8 af;
#pragma unroll
        for (int j = 0; j < 8; ++j) {
            int s = k0 + j;
            float w = (s <= l) ? (float)cbv[j] * (fl * gk[s]) : 0.f;
            if (s == l) w += Dh;               // D*x folded into the diagonal
            af[j] = (__bf16)w;
        }
        bf16x8 bfv[4];
#pragma unroll
        for (int pt = 0; pt < 4; ++pt)
            bfv[pt] = *(const bf16x8*)(x_t + (xtb + pt*16 + r16)*SEQ + cl + k0);
#pragma unroll
        for (int pt = 0; pt < 4; ++pt)
            acc[pt] = __builtin_amdgcn_mfma_f32_16x16x32_bf16(af, bfv[pt], acc[pt], 0,0,0);
    }
    float eal = __expf(acl);
    size_t sb = ((size_t)(b*NCHUNK+c)*NHEADS + h)*(HEADDIM*DSTATE);
#pragma unroll
    for (int ks = 0; ks < 4; ++ks) {
        int k0 = ks*32 + kq;
        bf16x8 cv = *(const bf16x8*)(C_n + (rbase + l)*DSTATE + k0);
        bf16x8 af;
#pragma unroll
        for (int j = 0; j < 8; ++j)
            af[j] = (__bf16)((float)cv[j] * eal);
        bf16x8 bfv[4];
#pragma unroll
        for (int pt = 0; pt < 4; ++pt)
            bfv[pt] = *(const bf16x8*)(states + sb + (size_t)(pt*16 + r16)*DSTATE + k0);
#pragma unroll
        for (int pt = 0; pt < 4; ++pt)
            acc[pt] = __builtin_amdgcn_mfma_f32_16x16x32_bf16(af, bfv[pt], acc[pt], 0,0,0);
    }
    // epilogue: g = acc * silu(z); store; per-row sumsq via shuffle + atomic
    int pcol = lane & 15, rowq = (lane>>4)*4;
    float sr[4] = {0.f, 0.f, 0.f, 0.f};
#pragma unroll
    for (int pt = 0; pt < 4; ++pt)
#pragma unroll
        for (int r = 0; r < 4; ++r) {
            int ll = wave*16 + rowq + r;
            int p = pt*16 + pcol;
            size_t rr = rbase + ll;
            float zv = __bfloat162float(z16[rr*DINNER + h*HEADDIM + p]);
            float g = acc[pt][r] * siluf_(zv);
            y16[rr*DINNER + h*HEADDIM + p] = __float2bfloat16(g);
            sr[r] += g*g;
        }
#pragma unroll
    for (int r = 0; r < 4; ++r) {
        float s = sr[r];
        s += __shfl_xor(s, 1); s += __shfl_xor(s, 2);
        s += __shfl_xor(s, 4); s += __shfl_xor(s, 8);
        if (pcol == 0)
            atomicAdd(rowsq + rbase + wave*16 + rowq + r, s);
    }
}

extern "C" void kernel_launch(void* const* d_in, const int* in_sizes, int n_in,
                              void* d_out, int out_size, void* d_ws, size_t ws_size,
                              hipStream_t stream)
{
    const float* feature = (const float*)d_in[0];
    const float* gate1   = (const float*)d_in[1];
    const float* in_w    = (const float*)d_in[2];
    const float* conv_w  = (const float*)d_in[3];
    const float* conv_b  = (const float*)d_in[4];
    const float* dt_bias = (const float*)d_in[5];
    const float* A_log   = (const float*)d_in[6];
    const float* Dp      = (const float*)d_in[7];
    const float* norm_w  = (const float*)d_in[8];
    const float* out_w   = (const float*)d_in[9];
    float* out = (float*)d_out;

    // workspace layout — ~161 MB (< 256 MiB)
    char* p = (char*)d_ws;
    __hip_bfloat16* z16   = (__hip_bfloat16*)p; p += (size_t)ROWS*DINNER*2;  // 25.2 MB
    __hip_bfloat16* xbc16 = (__hip_bfloat16*)p; p += (size_t)ROWS*DXBC*2;    // 29.4 MB
    __hip_bfloat16* x_t   = (__hip_bfloat16*)p; p += (size_t)ROWS*DINNER*2;  // 25.2 MB
    __hip_bfloat16* B_n   = (__hip_bfloat16*)p; p += (size_t)ROWS*DSTATE*2;  // 2.1 MB
    __hip_bfloat16* B_t   = (__hip_bfloat16*)p; p += (size_t)ROWS*DSTATE*2;  // 2.1 MB
    __hip_bfloat16* C_n   = (__hip_bfloat16*)p; p += (size_t)ROWS*DSTATE*2;  // 2.1 MB
    float* dtb    = (float*)p;            p += (size_t)ROWS*NHEADS*4;        // 0.8 MB
    float* acum   = (float*)p;            p += (size_t)B_SZ*NHEADS*NCHUNK*CHUNK*4; // 0.8 MB
    float* rowsq  = (float*)p;            p += (size_t)ROWS*4;               // 32 KB
    __hip_bfloat16* CB16 = (__hip_bfloat16*)p; p += (size_t)B_SZ*NCHUNK*CHUNK*CHUNK*2; // 2.1 MB
    __hip_bfloat16* states = (__hip_bfloat16*)p; p += (size_t)B_SZ*NCHUNK*NHEADS*HEADDIM*DSTATE*2; // 25.2 MB
    __hip_bfloat16* y16  = (__hip_bfloat16*)p; p += (size_t)ROWS*DINNER*2;   // 25.2 MB
    __hip_bfloat16* fbf  = (__hip_bfloat16*)p; p += (size_t)ROWS*DMODEL*2;   // 12.6 MB
    __hip_bfloat16* wbf  = (__hip_bfloat16*)p; p += (size_t)NPAD1*DMODEL*2;  //  5.3 MB
    __hip_bfloat16* owbf = (__hip_bfloat16*)p; p += (size_t)DMODEL*DINNER*2; //  2.4 MB

    cast_all<<<(NV1+NV2+NV3+255)/256, 256, 0, stream>>>(feature, in_w, out_w, norm_w,
                                                        fbf, wbf, owbf);
    hipMemsetAsync(rowsq, 0, (size_t)ROWS*4, stream);

    gemm1_mfma<<<27*32, 512, 0, stream>>>(fbf, wbf, z16, xbc16, dtb, dt_bias);
    conv_scan_k<<<dim3(14 + NHEADS, 32, B_SZ), 256, 0, stream>>>(
        xbc16, conv_w, conv_b, x_t, B_n, B_t, C_n, dtb, A_log, acum);
    cbst_k<<<64 + B_SZ*NHEADS*NCHUNK, 256, 0, stream>>>(
        B_n, C_n, CB16, x_t, B_t, dtb, acum, states);
    recur_k<<<B_SZ*NHEADS*16, 64, 0, stream>>>(states, acum);
    y_mfma<<<B_SZ*NHEADS*NCHUNK, 512, 0, stream>>>(x_t, z16, C_n, CB16, states,
                                                   dtb, acum, Dp, y16, rowsq);
    gemm2_mfma<<<6*32, 512, 0, stream>>>(y16, owbf, out, gate1, feature, rowsq);
}

// Round 6
// 309.508 us; speedup vs baseline: 1.0913x; 1.0235x over previous
//
#include <hip/hip_runtime.h>
#include <hip/hip_bf16.h>
#include <math.h>

#define B_SZ 2
#define SEQ 4096
#define DMODEL 768
#define DSTATE 128
#define HEADDIM 64
#define DINNER 1536
#define NHEADS 24
#define DXBC 1792
#define DPROJ 3352
#define NPAD1 3456
#define CHUNK 128
#define NCHUNK 32
#define ROWS (B_SZ*SEQ)
#define LDTC 136   // padded LDS stride for conv input tile
#define LDE 136    // padded LDS stride (bf16) for epilogue tiles
#define LDE2 132   // padded LDS stride (fp32) for gemm2 epilogue tile
#define LDEY 68    // padded LDS stride (fp32) for y_mfma epilogue tile

typedef float floatx4 __attribute__((ext_vector_type(4)));
typedef __bf16 bf16x8 __attribute__((ext_vector_type(8)));

// fast-exp variants: all consumers are bf16 casts / bf16 MFMA operands, so
// __expf's 2-4 ulp f32 error is far below bf16 rounding.
__device__ __forceinline__ float sigmoidf_(float x){ return 1.f/(1.f+__expf(-x)); }
__device__ __forceinline__ float siluf_(float x){ return x/(1.f+__expf(-x)); }
__device__ __forceinline__ float softplusf_(float x){ return (x>20.f)? x : __logf(1.f+__expf(x)); }
__device__ __forceinline__ __bf16 cvt_bf(float x){ __hip_bfloat16 t = __float2bfloat16(x); return *(__bf16*)&t; }

__device__ __forceinline__ void gload_lds16(const __hip_bfloat16* g, __hip_bfloat16* l){
    __builtin_amdgcn_global_load_lds(
        (const __attribute__((address_space(1))) void*)g,
        (__attribute__((address_space(3))) void*)l, 16, 0, 0);
}

// ======== GEMM1: 256x128 tile, 8 waves; epilogue -> z16 / xbc16 / dtb ========
// R0-exact structure: BK=64, serial stage, 48 KiB LDS, 3 blocks/CU co-residency.
// Measured conflict-free LDS layout: 64-elem rows, 8-slot XOR swizzle. Do NOT
// shrink BK below 64 (R3: 64B rows fold row parity into bank -> 4-way conflict).
__global__ __launch_bounds__(512)
void gemm1_mfma(const __hip_bfloat16* __restrict__ A,   // fbf [ROWS][768]
                const __hip_bfloat16* __restrict__ W,   // wbf [3456][768]
                __hip_bfloat16* __restrict__ z16, __hip_bfloat16* __restrict__ xbc16,
                float* __restrict__ dtb, const float* __restrict__ dt_bias)
{
    __shared__ __align__(16) char smem[49152];          // Asm 32K + Wsm 16K
    __hip_bfloat16* Asm = (__hip_bfloat16*)smem;        // [256][64]
    __hip_bfloat16* Wsm = Asm + 256*64;                 // [128][64]
    const int tid = threadIdx.x;
    const int lane = tid & 63, wave = tid >> 6;
    const int blk = blockIdx.x;
    const int m_tile = ((blk & 7) << 2) | ((blk >> 3) & 3);   // 32 M-tiles, XCD band
    const int bx = blk >> 5;                                   // N-tile 0..26
    const int bm = m_tile*256, bn = bx*128;
    const int wm = (wave & 3)*64, wn = (wave >> 2)*64;
    const int r16 = lane & 15, qbase = lane >> 4, sw = r16 & 7;
    floatx4 acc[4][4] = {};
    for (int k0 = 0; k0 < DMODEL; k0 += 64) {
#pragma unroll
        for (int j = 0; j < 4; ++j) {
            int cc = j*512 + tid;                // A: 2048 chunks
            int row = cc >> 3, jc = cc & 7;
            int sj = jc ^ (row & 7);
            gload_lds16(A + (size_t)(bm+row)*DMODEL + k0 + sj*8, Asm + cc*8);
        }
#pragma unroll
        for (int j = 0; j < 2; ++j) {
            int cc = j*512 + tid;                // W: 1024 chunks
            int row = cc >> 3, jc = cc & 7;
            int sj = jc ^ (row & 7);
            gload_lds16(W + (size_t)(bn+row)*DMODEL + k0 + sj*8, Wsm + cc*8);
        }
        __syncthreads();
#pragma unroll
        for (int ks = 0; ks < 2; ++ks) {
            const int kq = ((qbase + ks*4) ^ sw)*8;
            bf16x8 af[4], wf[4];
#pragma unroll
            for (int i = 0; i < 4; ++i) {
                af[i] = *(const bf16x8*)(Asm + (wm + i*16 + r16)*64 + kq);
                wf[i] = *(const bf16x8*)(Wsm + (wn + i*16 + r16)*64 + kq);
            }
#pragma unroll
            for (int mi = 0; mi < 4; ++mi)
#pragma unroll
                for (int ni = 0; ni < 4; ++ni)
                    acc[mi][ni] = __builtin_amdgcn_mfma_f32_16x16x32_bf16(
                        af[mi], wf[ni], acc[mi][ni], 0, 0, 0);
        }
        __syncthreads();
    }
    const int col = lane & 15, rowq = (lane >> 4)*4;
    if (bx == 26) {
        if (wn == 0) {
#pragma unroll
            for (int mi = 0; mi < 4; ++mi)
#pragma unroll
                for (int ni = 0; ni < 2; ++ni) {
                    int h = ni*16 + col;
                    if (h < NHEADS)
#pragma unroll
                        for (int r = 0; r < 4; ++r) {
                            int m = bm + wm + mi*16 + rowq + r;
                            dtb[(size_t)m*NHEADS + h] =
                                softplusf_(acc[mi][ni][r] + dt_bias[h]);
                        }
                }
        }
        return;
    }
    __hip_bfloat16* Tsm = (__hip_bfloat16*)smem;   // [128][LDE]
    __hip_bfloat16* dst; int ldd;
    if (bx < 12) { dst = z16 + bn;            ldd = DINNER; }
    else         { dst = xbc16 + bn - DINNER; ldd = DXBC;  }
    for (int half = 0; half < 2; ++half) {
        if (((wave & 3) >> 1) == half) {
#pragma unroll
            for (int mi = 0; mi < 4; ++mi)
#pragma unroll
                for (int ni = 0; ni < 4; ++ni)
#pragma unroll
                    for (int r = 0; r < 4; ++r)
                        Tsm[(wm - half*128 + mi*16 + rowq + r)*LDE + wn + ni*16 + col] =
                            __float2bfloat16(acc[mi][ni][r]);
        }
        __syncthreads();
#pragma unroll
        for (int it = 0; it < 4; ++it) {
            int e = it*512 + tid;
            int row = e >> 4, c0 = (e & 15)*8;
            bf16x8 v = *(const bf16x8*)(Tsm + row*LDE + c0);
            *(bf16x8*)(dst + (size_t)(bm + half*128 + row)*ldd + c0) = v;
        }
        __syncthreads();
    }
}

// ======== GEMM2: 256x128 tile; out = sig(gate)*rms_scale_r*(g @ Wn^T) + feature ====
__global__ __launch_bounds__(512)
void gemm2_mfma(const __hip_bfloat16* __restrict__ A,   // y16 [ROWS][1536] (gated)
                const __hip_bfloat16* __restrict__ W,   // owbf [768][1536]
                float* __restrict__ C,
                const float* __restrict__ gate, const float* __restrict__ resid,
                const float* __restrict__ rowsq)
{
    __shared__ __align__(16) char smem[49152];
    __shared__ float scale_lds[256];
    __hip_bfloat16* Asm = (__hip_bfloat16*)smem;        // [256][64]
    __hip_bfloat16* Wsm = Asm + 256*64;                 // [128][64]
    const int tid = threadIdx.x;
    const int lane = tid & 63, wave = tid >> 6;
    const int blk = blockIdx.x;
    const int m_tile = ((blk & 7) << 2) | ((blk >> 3) & 3);
    const int bm = m_tile*256, bn = (blk >> 5)*128;     // n-tile 0..5
    const int wm = (wave & 3)*64, wn = (wave >> 2)*64;
    const int r16 = lane & 15, qbase = lane >> 4, sw = r16 & 7;
    floatx4 acc[4][4] = {};
    for (int k0 = 0; k0 < DINNER; k0 += 64) {
#pragma unroll
        for (int j = 0; j < 4; ++j) {
            int cc = j*512 + tid;
            int row = cc >> 3, jc = cc & 7;
            int sj = jc ^ (row & 7);
            gload_lds16(A + (size_t)(bm+row)*DINNER + k0 + sj*8, Asm + cc*8);
        }
#pragma unroll
        for (int j = 0; j < 2; ++j) {
            int cc = j*512 + tid;
            int row = cc >> 3, jc = cc & 7;
            int sj = jc ^ (row & 7);
            gload_lds16(W + (size_t)(bn+row)*DINNER + k0 + sj*8, Wsm + cc*8);
        }
        __syncthreads();
#pragma unroll
        for (int ks = 0; ks < 2; ++ks) {
            const int kq = ((qbase + ks*4) ^ sw)*8;
            bf16x8 af[4], wf[4];
#pragma unroll
            for (int i = 0; i < 4; ++i) {
                af[i] = *(const bf16x8*)(Asm + (wm + i*16 + r16)*64 + kq);
                wf[i] = *(const bf16x8*)(Wsm + (wn + i*16 + r16)*64 + kq);
            }
#pragma unroll
            for (int mi = 0; mi < 4; ++mi)
#pragma unroll
                for (int ni = 0; ni < 4; ++ni)
                    acc[mi][ni] = __builtin_amdgcn_mfma_f32_16x16x32_bf16(
                        af[mi], wf[ni], acc[mi][ni], 0, 0, 0);
        }
        __syncthreads();
    }
    if (tid < 256)
        scale_lds[tid] = rsqrtf(rowsq[bm + tid] * (1.f/DINNER) + 1e-5f);
    float gs = sigmoidf_(gate[0]);
    __syncthreads();
    const int col = lane & 15, rowq = (lane >> 4)*4;
    float* Tsm = (float*)smem;   // 64 x LDE2 fp32
    for (int qp = 0; qp < 4; ++qp) {
        if ((wave & 3) == qp) {
#pragma unroll
            for (int mi = 0; mi < 4; ++mi)
#pragma unroll
                for (int ni = 0; ni < 4; ++ni)
#pragma unroll
                    for (int r = 0; r < 4; ++r)
                        Tsm[(mi*16 + rowq + r)*LDE2 + wn + ni*16 + col] = acc[mi][ni][r];
        }
        __syncthreads();
#pragma unroll
        for (int it = 0; it < 4; ++it) {
            int e = it*512 + tid;
            int row = e >> 5, c0 = (e & 31)*4;
            float4 v = *(const float4*)(Tsm + row*LDE2 + c0);
            float sc = gs * scale_lds[qp*64 + row];
            size_t off = (size_t)(bm + qp*64 + row)*DMODEL + bn + c0;
            float4 rv = *(const float4*)(resid + off);
            v.x = sc*v.x + rv.x; v.y = sc*v.y + rv.y;
            v.z = sc*v.z + rv.z; v.w = sc*v.w + rv.w;
            *(float4*)(C + off) = v;
        }
        __syncthreads();
    }
}

// ---------------- fused fp32 -> bf16 casts, vectorized 8 elem/thread ----------------
#define NC1 (ROWS*DMODEL)
#define NC2 (NPAD1*DMODEL)
#define NC3 (DMODEL*DINNER)
#define NV1 (NC1/8)
#define NV2 (NC2/8)
#define NV3 (NC3/8)
__global__ __launch_bounds__(256)
void cast_all(const float* __restrict__ feature, const float* __restrict__ in_w,
              const float* __restrict__ out_w, const float* __restrict__ nw,
              __hip_bfloat16* __restrict__ fbf, __hip_bfloat16* __restrict__ wbf,
              __hip_bfloat16* __restrict__ owbf)
{
    int v = blockIdx.x*256 + threadIdx.x;
    if (v < NV1) {
        int i = v*8;
        float4 a = *(const float4*)(feature + i);
        float4 b = *(const float4*)(feature + i + 4);
        bf16x8 o;
        o[0]=cvt_bf(a.x); o[1]=cvt_bf(a.y); o[2]=cvt_bf(a.z); o[3]=cvt_bf(a.w);
        o[4]=cvt_bf(b.x); o[5]=cvt_bf(b.y); o[6]=cvt_bf(b.z); o[7]=cvt_bf(b.w);
        *(bf16x8*)(fbf + i) = o;
    } else if (v < NV1 + NV2) {
        int j = (v - NV1)*8;
        int n = j / DMODEL, k = j - n*DMODEL;
        bf16x8 o;
        if (n < DPROJ) {
            const float* s = in_w + (size_t)n*DMODEL + k;
            float4 a = *(const float4*)(s);
            float4 b = *(const float4*)(s + 4);
            o[0]=cvt_bf(a.x); o[1]=cvt_bf(a.y); o[2]=cvt_bf(a.z); o[3]=cvt_bf(a.w);
            o[4]=cvt_bf(b.x); o[5]=cvt_bf(b.y); o[6]=cvt_bf(b.z); o[7]=cvt_bf(b.w);
        } else {
#pragma unroll
            for (int q = 0; q < 8; ++q) o[q] = (__bf16)0.f;
        }
        *(bf16x8*)(wbf + j) = o;
    } else if (v < NV1 + NV2 + NV3) {
        int j = (v - NV1 - NV2)*8;
        int k = j % DINNER;
        float4 a  = *(const float4*)(out_w + j);
        float4 b  = *(const float4*)(out_w + j + 4);
        float4 na = *(const float4*)(nw + k);
        float4 nb = *(const float4*)(nw + k + 4);
        bf16x8 o;
        o[0]=cvt_bf(a.x*na.x); o[1]=cvt_bf(a.y*na.y); o[2]=cvt_bf(a.z*na.z); o[3]=cvt_bf(a.w*na.w);
        o[4]=cvt_bf(b.x*nb.x); o[5]=cvt_bf(b.y*nb.y); o[6]=cvt_bf(b.z*nb.z); o[7]=cvt_bf(b.w*nb.w);
        *(bf16x8*)(owbf + j) = o;
    }
}

// ======== FUSED conv4+SiLU (blockIdx.x<14) + intra-chunk cumsum scan (>=14) ========
__global__ __launch_bounds__(256)
void conv_scan_k(const __hip_bfloat16* __restrict__ xbc16, const float* __restrict__ cw,
                 const float* __restrict__ cbias,
                 __hip_bfloat16* __restrict__ x_t,
                 __hip_bfloat16* __restrict__ B_n, __hip_bfloat16* __restrict__ B_t,
                 __hip_bfloat16* __restrict__ C_n,
                 const float* __restrict__ dtb, const float* __restrict__ A_log,
                 float* __restrict__ acum)
{
    int xb = blockIdx.x;
    if (xb >= 14) {
        // ---- scan path: h = xb-14, c = blockIdx.y, b = blockIdx.z ----
        __shared__ float sh2[256];
        int h = xb - 14, c = blockIdx.y, b = blockIdx.z;
        int tid = threadIdx.x;
        int l = tid & 127, g2 = tid >> 7;
        float* sh = sh2 + g2*128;
        float Aa = -__expf(A_log[h]);
        size_t row = (size_t)b*SEQ + c*CHUNK + l;
        float v = dtb[row*NHEADS + h] * Aa;
        sh[l] = v; __syncthreads();
        for (int off=1; off<128; off<<=1){
            float t = (l>=off) ? sh[l-off] : 0.f;
            __syncthreads();
            sh[l] += t;
            __syncthreads();
        }
        if (g2 == 0)
            acum[((b*NHEADS+h)*NCHUNK + c)*CHUNK + l] = sh[l];
        return;
    }
    // ---- conv path ----
    __shared__ __align__(16) __hip_bfloat16 in[131*LDTC];
    int ct = xb, lt = blockIdx.y, b = blockIdx.z;
    int tid = threadIdx.x;
    int base = lt*128;
    for (int it = 0; it < 2096; it += 256) {
        int e = it + tid; if (e >= 2096) break;
        int row = e >> 4, c0 = (e & 15)*8;
        int l = base - 3 + row;
        bf16x8 v;
        if (l < 0) { for (int j = 0; j < 8; ++j) v[j] = (__bf16)0.f; }
        else v = *(const bf16x8*)(xbc16 + ((size_t)b*SEQ + l)*DXBC + ct*128 + c0);
        *(bf16x8*)(in + row*LDTC + c0) = v;
    }
    __syncthreads();
    int ch = tid & 127, lh = tid >> 7, l0 = lh*64;
    int g = ct*128 + ch;
    float w0 = cw[g*4+0], w1 = cw[g*4+1], w2 = cw[g*4+2], w3 = cw[g*4+3];
    float bias = cbias[g];
    float a0 = __bfloat162float(in[(l0+0)*LDTC + ch]);
    float a1 = __bfloat162float(in[(l0+1)*LDTC + ch]);
    float a2 = __bfloat162float(in[(l0+2)*LDTC + ch]);
    size_t trow = 0;
    if (ct < 12)      trow = ((size_t)b*NHEADS + (g>>6))*HEADDIM + (g & 63);
    else if (ct == 12) trow = (size_t)b*DSTATE + ch;
    bf16x8 obuf;
#pragma unroll
    for (int li = 0; li < 64; ++li) {
        float a3 = __bfloat162float(in[(l0+li+3)*LDTC + ch]);
        float o = siluf_(bias + w0*a0 + w1*a1 + w2*a2 + w3*a3);
        a0 = a1; a1 = a2; a2 = a3;
        __hip_bfloat16 ob = __float2bfloat16(o);
        size_t rr = (size_t)b*SEQ + base + l0 + li;
        if (ct == 12)      B_n[rr*DSTATE + ch] = ob;
        else if (ct == 13) C_n[rr*DSTATE + ch] = ob;
        obuf[li & 7] = *(const __bf16*)&ob;
        if ((li & 7) == 7 && ct <= 12) {
            __hip_bfloat16* dst = (ct < 12) ? x_t : B_t;
            *(bf16x8*)(dst + trow*SEQ + base + l0 + (li - 7)) = obuf;
        }
    }
}

// ======== FUSED CB (blockIdx.x<64) + states (>=64) ========
__global__ __launch_bounds__(256)
void cbst_k(const __hip_bfloat16* __restrict__ B_n, const __hip_bfloat16* __restrict__ C_n,
            __hip_bfloat16* __restrict__ CB16,
            const __hip_bfloat16* __restrict__ x_t, const __hip_bfloat16* __restrict__ B_t,
            const float* __restrict__ dtb, const float* __restrict__ acum,
            __hip_bfloat16* __restrict__ states)
{
    int bid = blockIdx.x;
    int tid = threadIdx.x, lane = tid & 63, wave = tid >> 6;
    if (bid < 64) {
        int c = bid & 31, b = bid >> 5;
        size_t base = (size_t)b*SEQ + c*CHUNK;
        int r16 = lane & 15, kq = (lane>>4)*8;
        floatx4 acc[2][8] = {};
#pragma unroll
        for (int ks = 0; ks < 4; ++ks) {
            int k0 = ks*32 + kq;
            bf16x8 af[2], bfv[8];
#pragma unroll
            for (int mt = 0; mt < 2; ++mt)
                af[mt] = *(const bf16x8*)(C_n + (base + (wave*2+mt)*16 + r16)*DSTATE + k0);
#pragma unroll
            for (int st = 0; st < 8; ++st)
                bfv[st] = *(const bf16x8*)(B_n + (base + st*16 + r16)*DSTATE + k0);
#pragma unroll
            for (int mt = 0; mt < 2; ++mt)
#pragma unroll
                for (int st = 0; st < 8; ++st)
                    if (st <= wave*2+mt)
                        acc[mt][st] = __builtin_amdgcn_mfma_f32_16x16x32_bf16(
                            af[mt], bfv[st], acc[mt][st], 0,0,0);
        }
        size_t cbb = (size_t)(b*NCHUNK+c)*CHUNK*CHUNK;
        int scol = lane & 15, rowq = (lane>>4)*4;
#pragma unroll
        for (int mt = 0; mt < 2; ++mt)
#pragma unroll
            for (int st = 0; st < 8; ++st)
                if (st <= wave*2+mt)
#pragma unroll
                    for (int r = 0; r < 4; ++r)
                        CB16[cbb + (size_t)((wave*2+mt)*16 + rowq + r)*CHUNK + st*16 + scol] =
                            __float2bfloat16(acc[mt][st][r]);
        return;
    }
    // ---- states[p][n] = sum_l (x[l,p]*f[l]) * B[l,n], f = dt*dec ----
    __shared__ float f[128];
    int t = bid - 64;
    int c = t & 31;
    int h = (t>>5) % NHEADS;
    int b = t/(32*NHEADS);
    int arow = ((b*NHEADS+h)*NCHUNK + c)*CHUNK;
    size_t rbase = (size_t)b*SEQ + c*CHUNK;
    if (tid < 128) {
        float alast = acum[arow + 127];
        f[tid] = dtb[(rbase + tid)*NHEADS + h] * __expf(alast - acum[arow + tid]);
    }
    __syncthreads();
    int r16 = lane & 15, kq = (lane>>4)*8;
    size_t xtb = ((size_t)b*NHEADS + h)*HEADDIM;
    int cl = c*CHUNK;
    floatx4 acc[8] = {};
#pragma unroll
    for (int ks = 0; ks < 4; ++ks) {
        int k0 = ks*32 + kq;
        bf16x8 xa = *(const bf16x8*)(x_t + (xtb + wave*16 + r16)*SEQ + cl + k0);
        bf16x8 af;
#pragma unroll
        for (int j = 0; j < 8; ++j)
            af[j] = (__bf16)((float)xa[j] * f[k0 + j]);
        bf16x8 bfv[8];
#pragma unroll
        for (int nt = 0; nt < 8; ++nt)
            bfv[nt] = *(const bf16x8*)(B_t + ((size_t)b*DSTATE + nt*16 + r16)*SEQ + cl + k0);
#pragma unroll
        for (int nt = 0; nt < 8; ++nt)
            acc[nt] = __builtin_amdgcn_mfma_f32_16x16x32_bf16(af, bfv[nt], acc[nt], 0,0,0);
    }
    size_t sb = ((size_t)(b*NCHUNK+c)*NHEADS + h)*(HEADDIM*DSTATE);
    int ncol = lane & 15, rowq = (lane>>4)*4;
#pragma unroll
    for (int nt = 0; nt < 8; ++nt)
#pragma unroll
        for (int r = 0; r < 4; ++r)
            states[sb + (size_t)(wave*16 + rowq + r)*DSTATE + nt*16 + ncol] =
                __float2bfloat16(acc[nt][r]);
}

// ---- sequential inter-chunk recurrence, in place (bf16): states[c] := prev[c] ----
__global__ __launch_bounds__(64)
void recur_k(__hip_bfloat16* __restrict__ states, const float* __restrict__ acum)
{
    int pb = blockIdx.x & 15;
    int bh = blockIdx.x >> 4;
    int h = bh % NHEADS, b = bh / NHEADS;
    int voff = (pb*64 + threadIdx.x)*8;
    const size_t cstride = (size_t)NHEADS*HEADDIM*DSTATE;
    size_t base0 = ((size_t)(b*NCHUNK)*NHEADS + h)*(HEADDIM*DSTATE) + voff;
    bf16x8 st[NCHUNK];
    float ev[NCHUNK];
#pragma unroll
    for (int c = 0; c < NCHUNK; ++c)
        st[c] = *(const bf16x8*)(states + base0 + (size_t)c*cstride);
#pragma unroll
    for (int c = 0; c < NCHUNK; ++c)
        ev[c] = __expf(acum[((b*NHEADS+h)*NCHUNK + c)*CHUNK + 127]);
    float S[8] = {};
#pragma unroll
    for (int c = 0; c < NCHUNK; ++c) {
        bf16x8 pv;
#pragma unroll
        for (int j = 0; j < 8; ++j) {
            pv[j] = (__bf16)S[j];
            S[j] = S[j]*ev[c] + (float)st[c][j];
        }
        *(bf16x8*)(states + base0 + (size_t)c*cstride) = pv;
    }
}

// ======== Y = [tril(CB*exp(dAc)*dt)+D*I] @ x + (C*exp(ac)) @ prev^T; then
//          g = Y*silu(z) -> y16; rowsq += per-row sum(g^2) (atomic) ========
// Persistent grid: 768 blocks (3/CU, all co-resident), 2 units each — no tail.
// x_t/states tiles staged once per unit into LDS (shared by all 8 waves),
// chunk-XOR swizzled via pre-swizzled global source (linear LDS dest).
// Epilogue via LDS-fp32 transpose (reuses staging region): vectorized bf16x8
// z-loads / y-stores instead of 16+16 scalar ops per lane.
__global__ __launch_bounds__(512)
void y_mfma(const __hip_bfloat16* __restrict__ x_t, const __hip_bfloat16* __restrict__ z16,
            const __hip_bfloat16* __restrict__ C_n, const __hip_bfloat16* __restrict__ CB16,
            const __hip_bfloat16* __restrict__ states, const float* __restrict__ dtb,
            const float* __restrict__ acum, const float* __restrict__ Dp,
            __hip_bfloat16* __restrict__ y16, float* __restrict__ rowsq)
{
    __shared__ __align__(16) char smem[32768];
    __hip_bfloat16* XT = (__hip_bfloat16*)smem;   // [64 p][128 k] swizzled (16KB)
    __hip_bfloat16* ST = XT + 64*128;             // [64 p][128 n] swizzled (16KB)
    float* Tsm = (float*)smem;                    // [64][LDEY] fp32 epilogue reuse
    __shared__ float ac[128], dts[128], gk[128];
    const int tid = threadIdx.x, lane = tid & 63, wave = tid >> 6;
    const int r16 = lane & 15, kq = (lane>>4)*8;
    const int l = wave*16 + r16;
    const int pcol = lane & 15, rowq = (lane>>4)*4;
#pragma unroll 1
    for (int u = blockIdx.x; u < B_SZ*NHEADS*NCHUNK; u += 768) {
        int c = u & 31;
        int h = (u>>5) % NHEADS;
        int b = u/(32*NHEADS);
        int arow = ((b*NHEADS+h)*NCHUNK + c)*CHUNK;
        size_t rbase = (size_t)b*SEQ + c*CHUNK;
        size_t xtb = ((size_t)b*NHEADS + h)*HEADDIM;
        size_t sb  = ((size_t)(b*NCHUNK+c)*NHEADS + h)*(HEADDIM*DSTATE);
        int cl = c*CHUNK;
        // stage x_t and states tiles (1024 16B-chunks each; 4 per thread)
#pragma unroll
        for (int j = 0; j < 2; ++j) {
            int cc = j*512 + tid;
            int p = cc >> 4, ch = cc & 15;
            int sj = ch ^ (p & 7);
            gload_lds16(x_t + (xtb + p)*SEQ + cl + sj*8, XT + cc*8);
            gload_lds16(states + sb + (size_t)p*DSTATE + sj*8, ST + cc*8);
        }
        if (tid < 128) {
            ac[tid]  = acum[arow + tid];
            dts[tid] = dtb[(rbase + tid)*NHEADS + h];
        }
        __syncthreads();   // drains gload_lds + ac/dts visible
        if (tid < 128)
            gk[tid] = __expf(ac[tid & 96] - ac[tid]) * dts[tid];
        __syncthreads();
        float acl = ac[l];
        float Dh = Dp[h];
        size_t cbb = (size_t)(b*NCHUNK+c)*CHUNK*CHUNK;
        floatx4 acc[4] = {};
        int nks = (wave >> 1) + 1;
        for (int ks = 0; ks < nks; ++ks) {
            int k0 = ks*32 + kq;
            float fl = __expf(acl - ac[ks*32]);   // <= 1 (block base <= l)
            bf16x8 cbv = *(const bf16x8*)(CB16 + cbb + (size_t)l*CHUNK + k0);
            bf16x8 af;
#pragma unroll
            for (int j = 0; j < 8; ++j) {
                int s = k0 + j;
                float w = (s <= l) ? (float)cbv[j] * (fl * gk[s]) : 0.f;
                if (s == l) w += Dh;               // D*x folded into the diagonal
                af[j] = (__bf16)w;
            }
            int chL = k0 >> 3;
            bf16x8 bfv[4];
#pragma unroll
            for (int pt = 0; pt < 4; ++pt) {
                int row = pt*16 + r16;
                bfv[pt] = *(const bf16x8*)(XT + (row*16 + (chL ^ (row & 7)))*8);
            }
#pragma unroll
            for (int pt = 0; pt < 4; ++pt)
                acc[pt] = __builtin_amdgcn_mfma_f32_16x16x32_bf16(af, bfv[pt], acc[pt], 0,0,0);
        }
        float eal = __expf(acl);
#pragma unroll
        for (int ks = 0; ks < 4; ++ks) {
            int k0 = ks*32 + kq;
            bf16x8 cv = *(const bf16x8*)(C_n + (rbase + l)*DSTATE + k0);
            bf16x8 af;
#pragma unroll
            for (int j = 0; j < 8; ++j)
                af[j] = (__bf16)((float)cv[j] * eal);
            int chL = k0 >> 3;
            bf16x8 bfv[4];
#pragma unroll
            for (int pt = 0; pt < 4; ++pt) {
                int row = pt*16 + r16;
                bfv[pt] = *(const bf16x8*)(ST + (row*16 + (chL ^ (row & 7)))*8);
            }
#pragma unroll
            for (int pt = 0; pt < 4; ++pt)
                acc[pt] = __builtin_amdgcn_mfma_f32_16x16x32_bf16(af, bfv[pt], acc[pt], 0,0,0);
        }
        __syncthreads();   // all XT/ST reads complete before Tsm overwrite
        // epilogue: two 64-row halves through LDS fp32, vectorized global I/O
        for (int h2 = 0; h2 < 2; ++h2) {
            if ((wave >> 2) == h2) {
#pragma unroll
                for (int pt = 0; pt < 4; ++pt)
#pragma unroll
                    for (int r = 0; r < 4; ++r)
                        Tsm[((wave & 3)*16 + rowq + r)*LDEY + pt*16 + pcol] = acc[pt][r];
            }
            __syncthreads();
            {
                int row = tid >> 3, c0 = (tid & 7)*8;
                size_t grow = rbase + h2*64 + row;
                bf16x8 zv8 = *(const bf16x8*)(z16 + grow*DINNER + h*HEADDIM + c0);
                float s = 0.f; bf16x8 o;
#pragma unroll
                for (int j2 = 0; j2 < 8; ++j2) {
                    float g = Tsm[row*LDEY + c0 + j2] * siluf_(__bfloat162float(zv8[j2]));
                    o[j2] = cvt_bf(g); s += g*g;
                }
                *(bf16x8*)(y16 + grow*DINNER + h*HEADDIM + c0) = o;
                s += __shfl_xor(s, 1); s += __shfl_xor(s, 2); s += __shfl_xor(s, 4);
                if ((tid & 7) == 0)
                    atomicAdd(rowsq + grow, s);
            }
            __syncthreads();
        }
    }
}

extern "C" void kernel_launch(void* const* d_in, const int* in_sizes, int n_in,
                              void* d_out, int out_size, void* d_ws, size_t ws_size,
                              hipStream_t stream)
{
    const float* feature = (const float*)d_in[0];
    const float* gate1   = (const float*)d_in[1];
    const float* in_w    = (const float*)d_in[2];
    const float* conv_w  = (const float*)d_in[3];
    const float* conv_b  = (const float*)d_in[4];
    const float* dt_bias = (const float*)d_in[5];
    const float* A_log   = (const float*)d_in[6];
    const float* Dp      = (const float*)d_in[7];
    const float* norm_w  = (const float*)d_in[8];
    const float* out_w   = (const float*)d_in[9];
    float* out = (float*)d_out;

    // workspace layout — ~161 MB (< 256 MiB)
    char* p = (char*)d_ws;
    __hip_bfloat16* z16   = (__hip_bfloat16*)p; p += (size_t)ROWS*DINNER*2;  // 25.2 MB
    __hip_bfloat16* xbc16 = (__hip_bfloat16*)p; p += (size_t)ROWS*DXBC*2;    // 29.4 MB
    __hip_bfloat16* x_t   = (__hip_bfloat16*)p; p += (size_t)ROWS*DINNER*2;  // 25.2 MB
    __hip_bfloat16* B_n   = (__hip_bfloat16*)p; p += (size_t)ROWS*DSTATE*2;  // 2.1 MB
    __hip_bfloat16* B_t   = (__hip_bfloat16*)p; p += (size_t)ROWS*DSTATE*2;  // 2.1 MB
    __hip_bfloat16* C_n   = (__hip_bfloat16*)p; p += (size_t)ROWS*DSTATE*2;  // 2.1 MB
    float* dtb    = (float*)p;            p += (size_t)ROWS*NHEADS*4;        // 0.8 MB
    float* acum   = (float*)p;            p += (size_t)B_SZ*NHEADS*NCHUNK*CHUNK*4; // 0.8 MB
    float* rowsq  = (float*)p;            p += (size_t)ROWS*4;               // 32 KB
    __hip_bfloat16* CB16 = (__hip_bfloat16*)p; p += (size_t)B_SZ*NCHUNK*CHUNK*CHUNK*2; // 2.1 MB
    __hip_bfloat16* states = (__hip_bfloat16*)p; p += (size_t)B_SZ*NCHUNK*NHEADS*HEADDIM*DSTATE*2; // 25.2 MB
    __hip_bfloat16* y16  = (__hip_bfloat16*)p; p += (size_t)ROWS*DINNER*2;   // 25.2 MB
    __hip_bfloat16* fbf  = (__hip_bfloat16*)p; p += (size_t)ROWS*DMODEL*2;   // 12.6 MB
    __hip_bfloat16* wbf  = (__hip_bfloat16*)p; p += (size_t)NPAD1*DMODEL*2;  //  5.3 MB
    __hip_bfloat16* owbf = (__hip_bfloat16*)p; p += (size_t)DMODEL*DINNER*2; //  2.4 MB

    cast_all<<<(NV1+NV2+NV3+255)/256, 256, 0, stream>>>(feature, in_w, out_w, norm_w,
                                                        fbf, wbf, owbf);
    hipMemsetAsync(rowsq, 0, (size_t)ROWS*4, stream);

    gemm1_mfma<<<27*32, 512, 0, stream>>>(fbf, wbf, z16, xbc16, dtb, dt_bias);
    conv_scan_k<<<dim3(14 + NHEADS, 32, B_SZ), 256, 0, stream>>>(
        xbc16, conv_w, conv_b, x_t, B_n, B_t, C_n, dtb, A_log, acum);
    cbst_k<<<64 + B_SZ*NHEADS*NCHUNK, 256, 0, stream>>>(
        B_n, C_n, CB16, x_t, B_t, dtb, acum, states);
    recur_k<<<B_SZ*NHEADS*16, 64, 0, stream>>>(states, acum);
    y_mfma<<<768, 512, 0, stream>>>(x_t, z16, C_n, CB16, states,
                                    dtb, acum, Dp, y16, rowsq);
    gemm2_mfma<<<6*32, 512, 0, stream>>>(y16, owbf, out, gate1, feature, rowsq);
}

// Round 7
// 290.595 us; speedup vs baseline: 1.1623x; 1.0651x over previous
//
#include <hip/hip_runtime.h>
#include <hip/hip_bf16.h>
#include <math.h>

#define B_SZ 2
#define SEQ 4096
#define DMODEL 768
#define DSTATE 128
#define HEADDIM 64
#define DINNER 1536
#define NHEADS 24
#define DXBC 1792
#define DPROJ 3352
#define NPAD1 3456
#define CHUNK 128
#define NCHUNK 32
#define ROWS (B_SZ*SEQ)
#define LDTC 136   // padded LDS stride for conv input tile
#define LDE 136    // padded LDS stride (bf16) for epilogue tiles
#define LDE2 132   // padded LDS stride (fp32) for gemm2 epilogue tile
#define LDEY 65    // padded LDS stride (fp32) for y_mfma epilogue (65 ≡ 1 mod 32: bank = row+col)

typedef float floatx4 __attribute__((ext_vector_type(4)));
typedef __bf16 bf16x8 __attribute__((ext_vector_type(8)));

// fast-exp variants: all consumers are bf16 casts / bf16 MFMA operands, so
// __expf's 2-4 ulp f32 error is far below bf16 rounding.
__device__ __forceinline__ float sigmoidf_(float x){ return 1.f/(1.f+__expf(-x)); }
__device__ __forceinline__ float siluf_(float x){ return x/(1.f+__expf(-x)); }
__device__ __forceinline__ float softplusf_(float x){ return (x>20.f)? x : __logf(1.f+__expf(x)); }
__device__ __forceinline__ __bf16 cvt_bf(float x){ __hip_bfloat16 t = __float2bfloat16(x); return *(__bf16*)&t; }

__device__ __forceinline__ void gload_lds16(const __hip_bfloat16* g, __hip_bfloat16* l){
    __builtin_amdgcn_global_load_lds(
        (const __attribute__((address_space(1))) void*)g,
        (__attribute__((address_space(3))) void*)l, 16, 0, 0);
}

// ======== GEMM1: 256x128 tile, 8 waves; epilogue -> z16 / xbc16 / dtb ========
// R0-exact structure: BK=64, serial stage, 48 KiB LDS, 3 blocks/CU co-residency.
// Measured conflict-free LDS layout: 64-elem rows, 8-slot XOR swizzle. Do NOT
// shrink BK below 64 (R3: 64B rows fold row parity into bank -> 4-way conflict).
__global__ __launch_bounds__(512)
void gemm1_mfma(const __hip_bfloat16* __restrict__ A,   // fbf [ROWS][768]
                const __hip_bfloat16* __restrict__ W,   // wbf [3456][768]
                __hip_bfloat16* __restrict__ z16, __hip_bfloat16* __restrict__ xbc16,
                float* __restrict__ dtb, const float* __restrict__ dt_bias)
{
    __shared__ __align__(16) char smem[49152];          // Asm 32K + Wsm 16K
    __hip_bfloat16* Asm = (__hip_bfloat16*)smem;        // [256][64]
    __hip_bfloat16* Wsm = Asm + 256*64;                 // [128][64]
    const int tid = threadIdx.x;
    const int lane = tid & 63, wave = tid >> 6;
    const int blk = blockIdx.x;
    const int m_tile = ((blk & 7) << 2) | ((blk >> 3) & 3);   // 32 M-tiles, XCD band
    const int bx = blk >> 5;                                   // N-tile 0..26
    const int bm = m_tile*256, bn = bx*128;
    const int wm = (wave & 3)*64, wn = (wave >> 2)*64;
    const int r16 = lane & 15, qbase = lane >> 4, sw = r16 & 7;
    floatx4 acc[4][4] = {};
    for (int k0 = 0; k0 < DMODEL; k0 += 64) {
#pragma unroll
        for (int j = 0; j < 4; ++j) {
            int cc = j*512 + tid;                // A: 2048 chunks
            int row = cc >> 3, jc = cc & 7;
            int sj = jc ^ (row & 7);
            gload_lds16(A + (size_t)(bm+row)*DMODEL + k0 + sj*8, Asm + cc*8);
        }
#pragma unroll
        for (int j = 0; j < 2; ++j) {
            int cc = j*512 + tid;                // W: 1024 chunks
            int row = cc >> 3, jc = cc & 7;
            int sj = jc ^ (row & 7);
            gload_lds16(W + (size_t)(bn+row)*DMODEL + k0 + sj*8, Wsm + cc*8);
        }
        __syncthreads();
#pragma unroll
        for (int ks = 0; ks < 2; ++ks) {
            const int kq = ((qbase + ks*4) ^ sw)*8;
            bf16x8 af[4], wf[4];
#pragma unroll
            for (int i = 0; i < 4; ++i) {
                af[i] = *(const bf16x8*)(Asm + (wm + i*16 + r16)*64 + kq);
                wf[i] = *(const bf16x8*)(Wsm + (wn + i*16 + r16)*64 + kq);
            }
#pragma unroll
            for (int mi = 0; mi < 4; ++mi)
#pragma unroll
                for (int ni = 0; ni < 4; ++ni)
                    acc[mi][ni] = __builtin_amdgcn_mfma_f32_16x16x32_bf16(
                        af[mi], wf[ni], acc[mi][ni], 0, 0, 0);
        }
        __syncthreads();
    }
    const int col = lane & 15, rowq = (lane >> 4)*4;
    if (bx == 26) {
        if (wn == 0) {
#pragma unroll
            for (int mi = 0; mi < 4; ++mi)
#pragma unroll
                for (int ni = 0; ni < 2; ++ni) {
                    int h = ni*16 + col;
                    if (h < NHEADS)
#pragma unroll
                        for (int r = 0; r < 4; ++r) {
                            int m = bm + wm + mi*16 + rowq + r;
                            dtb[(size_t)m*NHEADS + h] =
                                softplusf_(acc[mi][ni][r] + dt_bias[h]);
                        }
                }
        }
        return;
    }
    __hip_bfloat16* Tsm = (__hip_bfloat16*)smem;   // [128][LDE]
    __hip_bfloat16* dst; int ldd;
    if (bx < 12) { dst = z16 + bn;            ldd = DINNER; }
    else         { dst = xbc16 + bn - DINNER; ldd = DXBC;  }
    for (int half = 0; half < 2; ++half) {
        if (((wave & 3) >> 1) == half) {
#pragma unroll
            for (int mi = 0; mi < 4; ++mi)
#pragma unroll
                for (int ni = 0; ni < 4; ++ni)
#pragma unroll
                    for (int r = 0; r < 4; ++r)
                        Tsm[(wm - half*128 + mi*16 + rowq + r)*LDE + wn + ni*16 + col] =
                            __float2bfloat16(acc[mi][ni][r]);
        }
        __syncthreads();
#pragma unroll
        for (int it = 0; it < 4; ++it) {
            int e = it*512 + tid;
            int row = e >> 4, c0 = (e & 15)*8;
            bf16x8 v = *(const bf16x8*)(Tsm + row*LDE + c0);
            *(bf16x8*)(dst + (size_t)(bm + half*128 + row)*ldd + c0) = v;
        }
        __syncthreads();
    }
}

// ======== GEMM2: 256x128 tile; out = sig(gate)*rms_scale_r*(g @ Wn^T) + feature ====
__global__ __launch_bounds__(512)
void gemm2_mfma(const __hip_bfloat16* __restrict__ A,   // y16 [ROWS][1536] (gated)
                const __hip_bfloat16* __restrict__ W,   // owbf [768][1536]
                float* __restrict__ C,
                const float* __restrict__ gate, const float* __restrict__ resid,
                const float* __restrict__ rowsq)
{
    __shared__ __align__(16) char smem[49152];
    __shared__ float scale_lds[256];
    __hip_bfloat16* Asm = (__hip_bfloat16*)smem;        // [256][64]
    __hip_bfloat16* Wsm = Asm + 256*64;                 // [128][64]
    const int tid = threadIdx.x;
    const int lane = tid & 63, wave = tid >> 6;
    const int blk = blockIdx.x;
    const int m_tile = ((blk & 7) << 2) | ((blk >> 3) & 3);
    const int bm = m_tile*256, bn = (blk >> 5)*128;     // n-tile 0..5
    const int wm = (wave & 3)*64, wn = (wave >> 2)*64;
    const int r16 = lane & 15, qbase = lane >> 4, sw = r16 & 7;
    floatx4 acc[4][4] = {};
    for (int k0 = 0; k0 < DINNER; k0 += 64) {
#pragma unroll
        for (int j = 0; j < 4; ++j) {
            int cc = j*512 + tid;
            int row = cc >> 3, jc = cc & 7;
            int sj = jc ^ (row & 7);
            gload_lds16(A + (size_t)(bm+row)*DINNER + k0 + sj*8, Asm + cc*8);
        }
#pragma unroll
        for (int j = 0; j < 2; ++j) {
            int cc = j*512 + tid;
            int row = cc >> 3, jc = cc & 7;
            int sj = jc ^ (row & 7);
            gload_lds16(W + (size_t)(bn+row)*DINNER + k0 + sj*8, Wsm + cc*8);
        }
        __syncthreads();
#pragma unroll
        for (int ks = 0; ks < 2; ++ks) {
            const int kq = ((qbase + ks*4) ^ sw)*8;
            bf16x8 af[4], wf[4];
#pragma unroll
            for (int i = 0; i < 4; ++i) {
                af[i] = *(const bf16x8*)(Asm + (wm + i*16 + r16)*64 + kq);
                wf[i] = *(const bf16x8*)(Wsm + (wn + i*16 + r16)*64 + kq);
            }
#pragma unroll
            for (int mi = 0; mi < 4; ++mi)
#pragma unroll
                for (int ni = 0; ni < 4; ++ni)
                    acc[mi][ni] = __builtin_amdgcn_mfma_f32_16x16x32_bf16(
                        af[mi], wf[ni], acc[mi][ni], 0, 0, 0);
        }
        __syncthreads();
    }
    if (tid < 256)
        scale_lds[tid] = rsqrtf(rowsq[bm + tid] * (1.f/DINNER) + 1e-5f);
    float gs = sigmoidf_(gate[0]);
    __syncthreads();
    const int col = lane & 15, rowq = (lane >> 4)*4;
    float* Tsm = (float*)smem;   // 64 x LDE2 fp32
    for (int qp = 0; qp < 4; ++qp) {
        if ((wave & 3) == qp) {
#pragma unroll
            for (int mi = 0; mi < 4; ++mi)
#pragma unroll
                for (int ni = 0; ni < 4; ++ni)
#pragma unroll
                    for (int r = 0; r < 4; ++r)
                        Tsm[(mi*16 + rowq + r)*LDE2 + wn + ni*16 + col] = acc[mi][ni][r];
        }
        __syncthreads();
#pragma unroll
        for (int it = 0; it < 4; ++it) {
            int e = it*512 + tid;
            int row = e >> 5, c0 = (e & 31)*4;
            float4 v = *(const float4*)(Tsm + row*LDE2 + c0);
            float sc = gs * scale_lds[qp*64 + row];
            size_t off = (size_t)(bm + qp*64 + row)*DMODEL + bn + c0;
            float4 rv = *(const float4*)(resid + off);
            v.x = sc*v.x + rv.x; v.y = sc*v.y + rv.y;
            v.z = sc*v.z + rv.z; v.w = sc*v.w + rv.w;
            *(float4*)(C + off) = v;
        }
        __syncthreads();
    }
}

// ---------------- fused fp32 -> bf16 casts, vectorized 8 elem/thread ----------------
#define NC1 (ROWS*DMODEL)
#define NC2 (NPAD1*DMODEL)
#define NC3 (DMODEL*DINNER)
#define NV1 (NC1/8)
#define NV2 (NC2/8)
#define NV3 (NC3/8)
__global__ __launch_bounds__(256)
void cast_all(const float* __restrict__ feature, const float* __restrict__ in_w,
              const float* __restrict__ out_w, const float* __restrict__ nw,
              __hip_bfloat16* __restrict__ fbf, __hip_bfloat16* __restrict__ wbf,
              __hip_bfloat16* __restrict__ owbf)
{
    int v = blockIdx.x*256 + threadIdx.x;
    if (v < NV1) {
        int i = v*8;
        float4 a = *(const float4*)(feature + i);
        float4 b = *(const float4*)(feature + i + 4);
        bf16x8 o;
        o[0]=cvt_bf(a.x); o[1]=cvt_bf(a.y); o[2]=cvt_bf(a.z); o[3]=cvt_bf(a.w);
        o[4]=cvt_bf(b.x); o[5]=cvt_bf(b.y); o[6]=cvt_bf(b.z); o[7]=cvt_bf(b.w);
        *(bf16x8*)(fbf + i) = o;
    } else if (v < NV1 + NV2) {
        int j = (v - NV1)*8;
        int n = j / DMODEL, k = j - n*DMODEL;
        bf16x8 o;
        if (n < DPROJ) {
            const float* s = in_w + (size_t)n*DMODEL + k;
            float4 a = *(const float4*)(s);
            float4 b = *(const float4*)(s + 4);
            o[0]=cvt_bf(a.x); o[1]=cvt_bf(a.y); o[2]=cvt_bf(a.z); o[3]=cvt_bf(a.w);
            o[4]=cvt_bf(b.x); o[5]=cvt_bf(b.y); o[6]=cvt_bf(b.z); o[7]=cvt_bf(b.w);
        } else {
#pragma unroll
            for (int q = 0; q < 8; ++q) o[q] = (__bf16)0.f;
        }
        *(bf16x8*)(wbf + j) = o;
    } else if (v < NV1 + NV2 + NV3) {
        int j = (v - NV1 - NV2)*8;
        int k = j % DINNER;
        float4 a  = *(const float4*)(out_w + j);
        float4 b  = *(const float4*)(out_w + j + 4);
        float4 na = *(const float4*)(nw + k);
        float4 nb = *(const float4*)(nw + k + 4);
        bf16x8 o;
        o[0]=cvt_bf(a.x*na.x); o[1]=cvt_bf(a.y*na.y); o[2]=cvt_bf(a.z*na.z); o[3]=cvt_bf(a.w*na.w);
        o[4]=cvt_bf(b.x*nb.x); o[5]=cvt_bf(b.y*nb.y); o[6]=cvt_bf(b.z*nb.z); o[7]=cvt_bf(b.w*nb.w);
        *(bf16x8*)(owbf + j) = o;
    }
}

// ======== FUSED conv4+SiLU (blockIdx.x<14) + intra-chunk cumsum scan (>=14) ========
__global__ __launch_bounds__(256)
void conv_scan_k(const __hip_bfloat16* __restrict__ xbc16, const float* __restrict__ cw,
                 const float* __restrict__ cbias,
                 __hip_bfloat16* __restrict__ x_t,
                 __hip_bfloat16* __restrict__ B_n, __hip_bfloat16* __restrict__ B_t,
                 __hip_bfloat16* __restrict__ C_n,
                 const float* __restrict__ dtb, const float* __restrict__ A_log,
                 float* __restrict__ acum)
{
    int xb = blockIdx.x;
    if (xb >= 14) {
        // ---- scan path: h = xb-14, c = blockIdx.y, b = blockIdx.z ----
        __shared__ float sh2[256];
        int h = xb - 14, c = blockIdx.y, b = blockIdx.z;
        int tid = threadIdx.x;
        int l = tid & 127, g2 = tid >> 7;
        float* sh = sh2 + g2*128;
        float Aa = -__expf(A_log[h]);
        size_t row = (size_t)b*SEQ + c*CHUNK + l;
        float v = dtb[row*NHEADS + h] * Aa;
        sh[l] = v; __syncthreads();
        for (int off=1; off<128; off<<=1){
            float t = (l>=off) ? sh[l-off] : 0.f;
            __syncthreads();
            sh[l] += t;
            __syncthreads();
        }
        if (g2 == 0)
            acum[((b*NHEADS+h)*NCHUNK + c)*CHUNK + l] = sh[l];
        return;
    }
    // ---- conv path ----
    __shared__ __align__(16) __hip_bfloat16 in[131*LDTC];
    int ct = xb, lt = blockIdx.y, b = blockIdx.z;
    int tid = threadIdx.x;
    int base = lt*128;
    for (int it = 0; it < 2096; it += 256) {
        int e = it + tid; if (e >= 2096) break;
        int row = e >> 4, c0 = (e & 15)*8;
        int l = base - 3 + row;
        bf16x8 v;
        if (l < 0) { for (int j = 0; j < 8; ++j) v[j] = (__bf16)0.f; }
        else v = *(const bf16x8*)(xbc16 + ((size_t)b*SEQ + l)*DXBC + ct*128 + c0);
        *(bf16x8*)(in + row*LDTC + c0) = v;
    }
    __syncthreads();
    int ch = tid & 127, lh = tid >> 7, l0 = lh*64;
    int g = ct*128 + ch;
    float w0 = cw[g*4+0], w1 = cw[g*4+1], w2 = cw[g*4+2], w3 = cw[g*4+3];
    float bias = cbias[g];
    float a0 = __bfloat162float(in[(l0+0)*LDTC + ch]);
    float a1 = __bfloat162float(in[(l0+1)*LDTC + ch]);
    float a2 = __bfloat162float(in[(l0+2)*LDTC + ch]);
    size_t trow = 0;
    if (ct < 12)      trow = ((size_t)b*NHEADS + (g>>6))*HEADDIM + (g & 63);
    else if (ct == 12) trow = (size_t)b*DSTATE + ch;
    bf16x8 obuf;
#pragma unroll
    for (int li = 0; li < 64; ++li) {
        float a3 = __bfloat162float(in[(l0+li+3)*LDTC + ch]);
        float o = siluf_(bias + w0*a0 + w1*a1 + w2*a2 + w3*a3);
        a0 = a1; a1 = a2; a2 = a3;
        __hip_bfloat16 ob = __float2bfloat16(o);
        size_t rr = (size_t)b*SEQ + base + l0 + li;
        if (ct == 12)      B_n[rr*DSTATE + ch] = ob;
        else if (ct == 13) C_n[rr*DSTATE + ch] = ob;
        obuf[li & 7] = *(const __bf16*)&ob;
        if ((li & 7) == 7 && ct <= 12) {
            __hip_bfloat16* dst = (ct < 12) ? x_t : B_t;
            *(bf16x8*)(dst + trow*SEQ + base + l0 + (li - 7)) = obuf;
        }
    }
}

// ======== FUSED CB (blockIdx.x<64) + states (>=64) ========
__global__ __launch_bounds__(256)
void cbst_k(const __hip_bfloat16* __restrict__ B_n, const __hip_bfloat16* __restrict__ C_n,
            __hip_bfloat16* __restrict__ CB16,
            const __hip_bfloat16* __restrict__ x_t, const __hip_bfloat16* __restrict__ B_t,
            const float* __restrict__ dtb, const float* __restrict__ acum,
            __hip_bfloat16* __restrict__ states)
{
    int bid = blockIdx.x;
    int tid = threadIdx.x, lane = tid & 63, wave = tid >> 6;
    if (bid < 64) {
        int c = bid & 31, b = bid >> 5;
        size_t base = (size_t)b*SEQ + c*CHUNK;
        int r16 = lane & 15, kq = (lane>>4)*8;
        floatx4 acc[2][8] = {};
#pragma unroll
        for (int ks = 0; ks < 4; ++ks) {
            int k0 = ks*32 + kq;
            bf16x8 af[2], bfv[8];
#pragma unroll
            for (int mt = 0; mt < 2; ++mt)
                af[mt] = *(const bf16x8*)(C_n + (base + (wave*2+mt)*16 + r16)*DSTATE + k0);
#pragma unroll
            for (int st = 0; st < 8; ++st)
                bfv[st] = *(const bf16x8*)(B_n + (base + st*16 + r16)*DSTATE + k0);
#pragma unroll
            for (int mt = 0; mt < 2; ++mt)
#pragma unroll
                for (int st = 0; st < 8; ++st)
                    if (st <= wave*2+mt)
                        acc[mt][st] = __builtin_amdgcn_mfma_f32_16x16x32_bf16(
                            af[mt], bfv[st], acc[mt][st], 0,0,0);
        }
        size_t cbb = (size_t)(b*NCHUNK+c)*CHUNK*CHUNK;
        int scol = lane & 15, rowq = (lane>>4)*4;
#pragma unroll
        for (int mt = 0; mt < 2; ++mt)
#pragma unroll
            for (int st = 0; st < 8; ++st)
                if (st <= wave*2+mt)
#pragma unroll
                    for (int r = 0; r < 4; ++r)
                        CB16[cbb + (size_t)((wave*2+mt)*16 + rowq + r)*CHUNK + st*16 + scol] =
                            __float2bfloat16(acc[mt][st][r]);
        return;
    }
    // ---- states[p][n] = sum_l (x[l,p]*f[l]) * B[l,n], f = dt*dec ----
    __shared__ float f[128];
    int t = bid - 64;
    int c = t & 31;
    int h = (t>>5) % NHEADS;
    int b = t/(32*NHEADS);
    int arow = ((b*NHEADS+h)*NCHUNK + c)*CHUNK;
    size_t rbase = (size_t)b*SEQ + c*CHUNK;
    if (tid < 128) {
        float alast = acum[arow + 127];
        f[tid] = dtb[(rbase + tid)*NHEADS + h] * __expf(alast - acum[arow + tid]);
    }
    __syncthreads();
    int r16 = lane & 15, kq = (lane>>4)*8;
    size_t xtb = ((size_t)b*NHEADS + h)*HEADDIM;
    int cl = c*CHUNK;
    floatx4 acc[8] = {};
#pragma unroll
    for (int ks = 0; ks < 4; ++ks) {
        int k0 = ks*32 + kq;
        bf16x8 xa = *(const bf16x8*)(x_t + (xtb + wave*16 + r16)*SEQ + cl + k0);
        bf16x8 af;
#pragma unroll
        for (int j = 0; j < 8; ++j)
            af[j] = (__bf16)((float)xa[j] * f[k0 + j]);
        bf16x8 bfv[8];
#pragma unroll
        for (int nt = 0; nt < 8; ++nt)
            bfv[nt] = *(const bf16x8*)(B_t + ((size_t)b*DSTATE + nt*16 + r16)*SEQ + cl + k0);
#pragma unroll
        for (int nt = 0; nt < 8; ++nt)
            acc[nt] = __builtin_amdgcn_mfma_f32_16x16x32_bf16(af, bfv[nt], acc[nt], 0,0,0);
    }
    size_t sb = ((size_t)(b*NCHUNK+c)*NHEADS + h)*(HEADDIM*DSTATE);
    int ncol = lane & 15, rowq = (lane>>4)*4;
#pragma unroll
    for (int nt = 0; nt < 8; ++nt)
#pragma unroll
        for (int r = 0; r < 4; ++r)
            states[sb + (size_t)(wave*16 + rowq + r)*DSTATE + nt*16 + ncol] =
                __float2bfloat16(acc[nt][r]);
}

// ---- sequential inter-chunk recurrence, in place (bf16): states[c] := prev[c] ----
__global__ __launch_bounds__(64)
void recur_k(__hip_bfloat16* __restrict__ states, const float* __restrict__ acum)
{
    int pb = blockIdx.x & 15;
    int bh = blockIdx.x >> 4;
    int h = bh % NHEADS, b = bh / NHEADS;
    int voff = (pb*64 + threadIdx.x)*8;
    const size_t cstride = (size_t)NHEADS*HEADDIM*DSTATE;
    size_t base0 = ((size_t)(b*NCHUNK)*NHEADS + h)*(HEADDIM*DSTATE) + voff;
    bf16x8 st[NCHUNK];
    float ev[NCHUNK];
#pragma unroll
    for (int c = 0; c < NCHUNK; ++c)
        st[c] = *(const bf16x8*)(states + base0 + (size_t)c*cstride);
#pragma unroll
    for (int c = 0; c < NCHUNK; ++c)
        ev[c] = __expf(acum[((b*NHEADS+h)*NCHUNK + c)*CHUNK + 127]);
    float S[8] = {};
#pragma unroll
    for (int c = 0; c < NCHUNK; ++c) {
        bf16x8 pv;
#pragma unroll
        for (int j = 0; j < 8; ++j) {
            pv[j] = (__bf16)S[j];
            S[j] = S[j]*ev[c] + (float)st[c][j];
        }
        *(bf16x8*)(states + base0 + (size_t)c*cstride) = pv;
    }
}

// ======== Y = [tril(CB*exp(dAc)*dt)+D*I] @ x + (C*exp(ac)) @ prev^T; then
//          g = Y*silu(z) -> y16; rowsq += per-row sum(g^2) (atomic) ========
// Persistent grid: 512 blocks x 3 units. VGPR 68 is past the 64-cliff -> only
// 2 blocks/CU (4 waves/SIMD); 512 = 2x256 all co-resident, perfectly balanced.
// All CB16/C_n/z16 global loads for a unit batched up front (one latency
// exposure, not 8 serial load->exp->MFMA chains). Single-phase [128][LDEY=65]
// fp32 epilogue transpose (bank = row+col: conflict-free reads).
__global__ __launch_bounds__(512, 4)
void y_mfma(const __hip_bfloat16* __restrict__ x_t, const __hip_bfloat16* __restrict__ z16,
            const __hip_bfloat16* __restrict__ C_n, const __hip_bfloat16* __restrict__ CB16,
            const __hip_bfloat16* __restrict__ states, const float* __restrict__ dtb,
            const float* __restrict__ acum, const float* __restrict__ Dp,
            __hip_bfloat16* __restrict__ y16, float* __restrict__ rowsq)
{
    __shared__ __align__(16) char smem[33280];    // max(XT+ST 32K, 128*65*4 epi)
    __hip_bfloat16* XT = (__hip_bfloat16*)smem;   // [64 p][128 k] swizzled (16KB)
    __hip_bfloat16* ST = XT + 64*128;             // [64 p][128 n] swizzled (16KB)
    float* Tsm = (float*)smem;                    // [128][LDEY] fp32 epilogue reuse
    __shared__ float ac[128], dts[128], gk[128];
    const int tid = threadIdx.x, lane = tid & 63, wave = tid >> 6;
    const int r16 = lane & 15, kq = (lane>>4)*8;
    const int l = wave*16 + r16;
    const int pcol = lane & 15, rowq = (lane>>4)*4;
    const int erow = tid >> 2, ec0 = (tid & 3)*16;   // epilogue mapping
#pragma unroll 1
    for (int u = blockIdx.x; u < B_SZ*NHEADS*NCHUNK; u += 512) {
        int c = u & 31;
        int h = (u>>5) % NHEADS;
        int b = u/(32*NHEADS);
        int arow = ((b*NHEADS+h)*NCHUNK + c)*CHUNK;
        size_t rbase = (size_t)b*SEQ + c*CHUNK;
        size_t xtb = ((size_t)b*NHEADS + h)*HEADDIM;
        size_t sb  = ((size_t)(b*NCHUNK+c)*NHEADS + h)*(HEADDIM*DSTATE);
        size_t cbb = (size_t)(b*NCHUNK+c)*CHUNK*CHUNK;
        int cl = c*CHUNK;
        // stage x_t and states tiles (1024 16B-chunks each; 4 per thread)
#pragma unroll
        for (int j = 0; j < 2; ++j) {
            int cc = j*512 + tid;
            int p = cc >> 4, ch = cc & 15;
            int sj = ch ^ (p & 7);
            gload_lds16(x_t + (xtb + p)*SEQ + cl + sj*8, XT + cc*8);
            gload_lds16(states + sb + (size_t)p*DSTATE + sj*8, ST + cc*8);
        }
        if (tid < 128) {
            ac[tid]  = acum[arow + tid];
            dts[tid] = dtb[(rbase + tid)*NHEADS + h];
        }
        __syncthreads();   // drains gload_lds; ac/dts visible
        if (tid < 128)
            gk[tid] = __expf(ac[tid & 96] - ac[tid]) * dts[tid];
        // ---- batch ALL global loads for this unit (independent; in flight
        //      across the barrier; first use waits once) ----
        bf16x8 cb[4], cv[4];
#pragma unroll
        for (int ks = 0; ks < 4; ++ks) {
            cb[ks] = *(const bf16x8*)(CB16 + cbb + (size_t)l*CHUNK + ks*32 + kq);
            cv[ks] = *(const bf16x8*)(C_n + (rbase + l)*DSTATE + ks*32 + kq);
        }
        bf16x8 zA = *(const bf16x8*)(z16 + (rbase + erow)*DINNER + h*HEADDIM + ec0);
        bf16x8 zB = *(const bf16x8*)(z16 + (rbase + erow)*DINNER + h*HEADDIM + ec0 + 8);
        __syncthreads();   // gk visible
        float acl = ac[l];
        float Dh = Dp[h];
        floatx4 acc[4] = {};
        int nks = (wave >> 1) + 1;
#pragma unroll
        for (int ks = 0; ks < 4; ++ks) {
            if (ks < nks) {            // wave-uniform guard
                int k0 = ks*32 + kq;
                float fl = __expf(acl - ac[ks*32]);   // <= 1 (block base <= l)
                bf16x8 af;
#pragma unroll
                for (int j = 0; j < 8; ++j) {
                    int s = k0 + j;
                    float w = (s <= l) ? (float)cb[ks][j] * (fl * gk[s]) : 0.f;
                    if (s == l) w += Dh;           // D*x folded into the diagonal
                    af[j] = (__bf16)w;
                }
                int chL = k0 >> 3;
                bf16x8 bfv[4];
#pragma unroll
                for (int pt = 0; pt < 4; ++pt) {
                    int row = pt*16 + r16;
                    bfv[pt] = *(const bf16x8*)(XT + (row*16 + (chL ^ (row & 7)))*8);
                }
#pragma unroll
                for (int pt = 0; pt < 4; ++pt)
                    acc[pt] = __builtin_amdgcn_mfma_f32_16x16x32_bf16(af, bfv[pt], acc[pt], 0,0,0);
            }
        }
        float eal = __expf(acl);
#pragma unroll
        for (int ks = 0; ks < 4; ++ks) {
            int k0 = ks*32 + kq;
            bf16x8 af;
#pragma unroll
            for (int j = 0; j < 8; ++j)
                af[j] = (__bf16)((float)cv[ks][j] * eal);
            int chL = k0 >> 3;
            bf16x8 bfv[4];
#pragma unroll
            for (int pt = 0; pt < 4; ++pt) {
                int row = pt*16 + r16;
                bfv[pt] = *(const bf16x8*)(ST + (row*16 + (chL ^ (row & 7)))*8);
            }
#pragma unroll
            for (int pt = 0; pt < 4; ++pt)
                acc[pt] = __builtin_amdgcn_mfma_f32_16x16x32_bf16(af, bfv[pt], acc[pt], 0,0,0);
        }
        __syncthreads();   // all XT/ST reads complete before Tsm overwrite
        // single-phase epilogue: 8 waves write disjoint 16-row bands
#pragma unroll
        for (int pt = 0; pt < 4; ++pt)
#pragma unroll
            for (int r = 0; r < 4; ++r)
                Tsm[(wave*16 + rowq + r)*LDEY + pt*16 + pcol] = acc[pt][r];
        __syncthreads();
        {
            float s = 0.f; bf16x8 o1, o2;
#pragma unroll
            for (int j2 = 0; j2 < 8; ++j2) {
                float g = Tsm[erow*LDEY + ec0 + j2] * siluf_(__bfloat162float(zA[j2]));
                o1[j2] = cvt_bf(g); s += g*g;
            }
#pragma unroll
            for (int j2 = 0; j2 < 8; ++j2) {
                float g = Tsm[erow*LDEY + ec0 + 8 + j2] * siluf_(__bfloat162float(zB[j2]));
                o2[j2] = cvt_bf(g); s += g*g;
            }
            size_t grow = rbase + erow;
            *(bf16x8*)(y16 + grow*DINNER + h*HEADDIM + ec0)     = o1;
            *(bf16x8*)(y16 + grow*DINNER + h*HEADDIM + ec0 + 8) = o2;
            s += __shfl_xor(s, 1); s += __shfl_xor(s, 2);
            if ((tid & 3) == 0)
                atomicAdd(rowsq + grow, s);
        }
        __syncthreads();   // Tsm/ac/dts safe to overwrite next unit
    }
}

extern "C" void kernel_launch(void* const* d_in, const int* in_sizes, int n_in,
                              void* d_out, int out_size, void* d_ws, size_t ws_size,
                              hipStream_t stream)
{
    const float* feature = (const float*)d_in[0];
    const float* gate1   = (const float*)d_in[1];
    const float* in_w    = (const float*)d_in[2];
    const float* conv_w  = (const float*)d_in[3];
    const float* conv_b  = (const float*)d_in[4];
    const float* dt_bias = (const float*)d_in[5];
    const float* A_log   = (const float*)d_in[6];
    const float* Dp      = (const float*)d_in[7];
    const float* norm_w  = (const float*)d_in[8];
    const float* out_w   = (const float*)d_in[9];
    float* out = (float*)d_out;

    // workspace layout — ~161 MB (< 256 MiB)
    char* p = (char*)d_ws;
    __hip_bfloat16* z16   = (__hip_bfloat16*)p; p += (size_t)ROWS*DINNER*2;  // 25.2 MB
    __hip_bfloat16* xbc16 = (__hip_bfloat16*)p; p += (size_t)ROWS*DXBC*2;    // 29.4 MB
    __hip_bfloat16* x_t   = (__hip_bfloat16*)p; p += (size_t)ROWS*DINNER*2;  // 25.2 MB
    __hip_bfloat16* B_n   = (__hip_bfloat16*)p; p += (size_t)ROWS*DSTATE*2;  // 2.1 MB
    __hip_bfloat16* B_t   = (__hip_bfloat16*)p; p += (size_t)ROWS*DSTATE*2;  // 2.1 MB
    __hip_bfloat16* C_n   = (__hip_bfloat16*)p; p += (size_t)ROWS*DSTATE*2;  // 2.1 MB
    float* dtb    = (float*)p;            p += (size_t)ROWS*NHEADS*4;        // 0.8 MB
    float* acum   = (float*)p;            p += (size_t)B_SZ*NHEADS*NCHUNK*CHUNK*4; // 0.8 MB
    float* rowsq  = (float*)p;            p += (size_t)ROWS*4;               // 32 KB
    __hip_bfloat16* CB16 = (__hip_bfloat16*)p; p += (size_t)B_SZ*NCHUNK*CHUNK*CHUNK*2; // 2.1 MB
    __hip_bfloat16* states = (__hip_bfloat16*)p; p += (size_t)B_SZ*NCHUNK*NHEADS*HEADDIM*DSTATE*2; // 25.2 MB
    __hip_bfloat16* y16  = (__hip_bfloat16*)p; p += (size_t)ROWS*DINNER*2;   // 25.2 MB
    __hip_bfloat16* fbf  = (__hip_bfloat16*)p; p += (size_t)ROWS*DMODEL*2;   // 12.6 MB
    __hip_bfloat16* wbf  = (__hip_bfloat16*)p; p += (size_t)NPAD1*DMODEL*2;  //  5.3 MB
    __hip_bfloat16* owbf = (__hip_bfloat16*)p; p += (size_t)DMODEL*DINNER*2; //  2.4 MB

    cast_all<<<(NV1+NV2+NV3+255)/256, 256, 0, stream>>>(feature, in_w, out_w, norm_w,
                                                        fbf, wbf, owbf);
    hipMemsetAsync(rowsq, 0, (size_t)ROWS*4, stream);

    gemm1_mfma<<<27*32, 512, 0, stream>>>(fbf, wbf, z16, xbc16, dtb, dt_bias);
    conv_scan_k<<<dim3(14 + NHEADS, 32, B_SZ), 256, 0, stream>>>(
        xbc16, conv_w, conv_b, x_t, B_n, B_t, C_n, dtb, A_log, acum);
    cbst_k<<<64 + B_SZ*NHEADS*NCHUNK, 256, 0, stream>>>(
        B_n, C_n, CB16, x_t, B_t, dtb, acum, states);
    recur_k<<<B_SZ*NHEADS*16, 64, 0, stream>>>(states, acum);
    y_mfma<<<512, 512, 0, stream>>>(x_t, z16, C_n, CB16, states,
                                    dtb, acum, Dp, y16, rowsq);
    gemm2_mfma<<<6*32, 512, 0, stream>>>(y16, owbf, out, gate1, feature, rowsq);
}

// Round 9
// 285.955 us; speedup vs baseline: 1.1812x; 1.0162x over previous
//
#include <hip/hip_runtime.h>
#include <hip/hip_bf16.h>
#include <math.h>

#define B_SZ 2
#define SEQ 4096
#define DMODEL 768
#define DSTATE 128
#define HEADDIM 64
#define DINNER 1536
#define NHEADS 24
#define DXBC 1792
#define DPROJ 3352
#define NPAD1 3456
#define CHUNK 128
#define NCHUNK 32
#define ROWS (B_SZ*SEQ)
#define LDTC 136   // padded LDS stride for conv input tile
#define LDE 136    // padded LDS stride (bf16) for epilogue tiles
#define LDE2 132   // padded LDS stride (fp32) for gemm2 epilogue tile
#define LDEY 65    // padded LDS stride (fp32) for y_mfma epilogue (65 ≡ 1 mod 32: bank = row+col)

typedef float floatx4 __attribute__((ext_vector_type(4)));
typedef __bf16 bf16x8 __attribute__((ext_vector_type(8)));

// fast-exp variants: all consumers are bf16 casts / bf16 MFMA operands, so
// __expf's 2-4 ulp f32 error is far below bf16 rounding.
__device__ __forceinline__ float sigmoidf_(float x){ return 1.f/(1.f+__expf(-x)); }
__device__ __forceinline__ float siluf_(float x){ return x/(1.f+__expf(-x)); }
__device__ __forceinline__ float softplusf_(float x){ return (x>20.f)? x : __logf(1.f+__expf(x)); }
__device__ __forceinline__ __bf16 cvt_bf(float x){ __hip_bfloat16 t = __float2bfloat16(x); return *(__bf16*)&t; }

__device__ __forceinline__ void gload_lds16(const __hip_bfloat16* g, __hip_bfloat16* l){
    __builtin_amdgcn_global_load_lds(
        (const __attribute__((address_space(1))) void*)g,
        (__attribute__((address_space(3))) void*)l, 16, 0, 0);
}

// ======== GEMM1: 256x128 tile, 8 waves; epilogue -> z16 / xbc16 / dtb ========
// R0-exact structure: BK=64, serial stage, 48 KiB LDS, 3 blocks/CU co-residency.
// Measured conflict-free LDS layout: 64-elem rows, 8-slot XOR swizzle. Do NOT
// shrink BK below 64 (R3: 64B rows fold row parity into bank -> 4-way conflict).
__global__ __launch_bounds__(512)
void gemm1_mfma(const __hip_bfloat16* __restrict__ A,   // fbf [ROWS][768]
                const __hip_bfloat16* __restrict__ W,   // wbf [3456][768]
                __hip_bfloat16* __restrict__ z16, __hip_bfloat16* __restrict__ xbc16,
                float* __restrict__ dtb, const float* __restrict__ dt_bias)
{
    __shared__ __align__(16) char smem[49152];          // Asm 32K + Wsm 16K
    __hip_bfloat16* Asm = (__hip_bfloat16*)smem;        // [256][64]
    __hip_bfloat16* Wsm = Asm + 256*64;                 // [128][64]
    const int tid = threadIdx.x;
    const int lane = tid & 63, wave = tid >> 6;
    const int blk = blockIdx.x;
    const int m_tile = ((blk & 7) << 2) | ((blk >> 3) & 3);   // 32 M-tiles, XCD band
    const int bx = blk >> 5;                                   // N-tile 0..26
    const int bm = m_tile*256, bn = bx*128;
    const int wm = (wave & 3)*64, wn = (wave >> 2)*64;
    const int r16 = lane & 15, qbase = lane >> 4, sw = r16 & 7;
    floatx4 acc[4][4] = {};
    for (int k0 = 0; k0 < DMODEL; k0 += 64) {
#pragma unroll
        for (int j = 0; j < 4; ++j) {
            int cc = j*512 + tid;                // A: 2048 chunks
            int row = cc >> 3, jc = cc & 7;
            int sj = jc ^ (row & 7);
            gload_lds16(A + (size_t)(bm+row)*DMODEL + k0 + sj*8, Asm + cc*8);
        }
#pragma unroll
        for (int j = 0; j < 2; ++j) {
            int cc = j*512 + tid;                // W: 1024 chunks
            int row = cc >> 3, jc = cc & 7;
            int sj = jc ^ (row & 7);
            gload_lds16(W + (size_t)(bn+row)*DMODEL + k0 + sj*8, Wsm + cc*8);
        }
        __syncthreads();
#pragma unroll
        for (int ks = 0; ks < 2; ++ks) {
            const int kq = ((qbase + ks*4) ^ sw)*8;
            bf16x8 af[4], wf[4];
#pragma unroll
            for (int i = 0; i < 4; ++i) {
                af[i] = *(const bf16x8*)(Asm + (wm + i*16 + r16)*64 + kq);
                wf[i] = *(const bf16x8*)(Wsm + (wn + i*16 + r16)*64 + kq);
            }
#pragma unroll
            for (int mi = 0; mi < 4; ++mi)
#pragma unroll
                for (int ni = 0; ni < 4; ++ni)
                    acc[mi][ni] = __builtin_amdgcn_mfma_f32_16x16x32_bf16(
                        af[mi], wf[ni], acc[mi][ni], 0, 0, 0);
        }
        __syncthreads();
    }
    const int col = lane & 15, rowq = (lane >> 4)*4;
    if (bx == 26) {
        if (wn == 0) {
#pragma unroll
            for (int mi = 0; mi < 4; ++mi)
#pragma unroll
                for (int ni = 0; ni < 2; ++ni) {
                    int h = ni*16 + col;
                    if (h < NHEADS)
#pragma unroll
                        for (int r = 0; r < 4; ++r) {
                            int m = bm + wm + mi*16 + rowq + r;
                            dtb[(size_t)m*NHEADS + h] =
                                softplusf_(acc[mi][ni][r] + dt_bias[h]);
                        }
                }
        }
        return;
    }
    __hip_bfloat16* Tsm = (__hip_bfloat16*)smem;   // [128][LDE]
    __hip_bfloat16* dst; int ldd;
    if (bx < 12) { dst = z16 + bn;            ldd = DINNER; }
    else         { dst = xbc16 + bn - DINNER; ldd = DXBC;  }
    for (int half = 0; half < 2; ++half) {
        if (((wave & 3) >> 1) == half) {
#pragma unroll
            for (int mi = 0; mi < 4; ++mi)
#pragma unroll
                for (int ni = 0; ni < 4; ++ni)
#pragma unroll
                    for (int r = 0; r < 4; ++r)
                        Tsm[(wm - half*128 + mi*16 + rowq + r)*LDE + wn + ni*16 + col] =
                            __float2bfloat16(acc[mi][ni][r]);
        }
        __syncthreads();
#pragma unroll
        for (int it = 0; it < 4; ++it) {
            int e = it*512 + tid;
            int row = e >> 4, c0 = (e & 15)*8;
            bf16x8 v = *(const bf16x8*)(Tsm + row*LDE + c0);
            *(bf16x8*)(dst + (size_t)(bm + half*128 + row)*ldd + c0) = v;
        }
        __syncthreads();
    }
}

// ======== GEMM2: 128x128 tile, 4 waves (2x2), 384 blocks ========
// R7 grid was 192 blocks x 512 thr on 256 CUs: 64 CUs idle, 1 block/CU (no
// stage/compute overlap). 128x128 x 256 thr doubles the grid: all CUs busy,
// 1.5 blocks/CU avg with 4-block capacity (LDS 34KB) -> co-residency restored.
__global__ __launch_bounds__(256)
void gemm2_mfma(const __hip_bfloat16* __restrict__ A,   // y16 [ROWS][1536] (gated)
                const __hip_bfloat16* __restrict__ W,   // owbf [768][1536]
                float* __restrict__ C,
                const float* __restrict__ gate, const float* __restrict__ resid,
                const float* __restrict__ rowsq)
{
    __shared__ __align__(16) char smem[33792];          // staging 32K; epi 64*LDE2*4
    __shared__ float scale_lds[128];
    __hip_bfloat16* Asm = (__hip_bfloat16*)smem;        // [128][64]
    __hip_bfloat16* Wsm = Asm + 128*64;                 // [128][64]
    const int tid = threadIdx.x;
    const int lane = tid & 63, wave = tid >> 6;         // 4 waves
    const int blk = blockIdx.x;
    const int mblk = blk & 63;
    const int m_tile = ((mblk & 7) << 3) | (mblk >> 3); // 64 M-tiles, XCD band
    const int bm = m_tile*128, bn = (blk >> 6)*128;     // n-tile 0..5
    const int wm = (wave & 1)*64, wn = (wave >> 1)*64;
    const int r16 = lane & 15, qbase = lane >> 4, sw = r16 & 7;
    floatx4 acc[4][4] = {};
    for (int k0 = 0; k0 < DINNER; k0 += 64) {
#pragma unroll
        for (int j = 0; j < 4; ++j) {
            int cc = j*256 + tid;                // A: 1024 chunks (128 rows x 8)
            int row = cc >> 3, jc = cc & 7;
            int sj = jc ^ (row & 7);
            gload_lds16(A + (size_t)(bm+row)*DINNER + k0 + sj*8, Asm + cc*8);
        }
#pragma unroll
        for (int j = 0; j < 4; ++j) {
            int cc = j*256 + tid;                // W: 1024 chunks
            int row = cc >> 3, jc = cc & 7;
            int sj = jc ^ (row & 7);
            gload_lds16(W + (size_t)(bn+row)*DINNER + k0 + sj*8, Wsm + cc*8);
        }
        __syncthreads();
#pragma unroll
        for (int ks = 0; ks < 2; ++ks) {
            const int kq = ((qbase + ks*4) ^ sw)*8;
            bf16x8 af[4], wf[4];
#pragma unroll
            for (int i = 0; i < 4; ++i) {
                af[i] = *(const bf16x8*)(Asm + (wm + i*16 + r16)*64 + kq);
                wf[i] = *(const bf16x8*)(Wsm + (wn + i*16 + r16)*64 + kq);
            }
#pragma unroll
            for (int mi = 0; mi < 4; ++mi)
#pragma unroll
                for (int ni = 0; ni < 4; ++ni)
                    acc[mi][ni] = __builtin_amdgcn_mfma_f32_16x16x32_bf16(
                        af[mi], wf[ni], acc[mi][ni], 0, 0, 0);
        }
        __syncthreads();
    }
    if (tid < 128)
        scale_lds[tid] = rsqrtf(rowsq[bm + tid] * (1.f/DINNER) + 1e-5f);
    float gs = sigmoidf_(gate[0]);
    __syncthreads();
    const int col = lane & 15, rowq = (lane >> 4)*4;
    float* Tsm = (float*)smem;   // 64 x LDE2 fp32
    for (int half = 0; half < 2; ++half) {
        if ((wave & 1) == half) {     // two waves per half, disjoint wn columns
#pragma unroll
            for (int mi = 0; mi < 4; ++mi)
#pragma unroll
                for (int ni = 0; ni < 4; ++ni)
#pragma unroll
                    for (int r = 0; r < 4; ++r)
                        Tsm[(mi*16 + rowq + r)*LDE2 + wn + ni*16 + col] = acc[mi][ni][r];
        }
        __syncthreads();
#pragma unroll
        for (int it = 0; it < 8; ++it) {
            int e = it*256 + tid;
            int row = e >> 5, c0 = (e & 31)*4;
            float4 v = *(const float4*)(Tsm + row*LDE2 + c0);
            float sc = gs * scale_lds[half*64 + row];
            size_t off = (size_t)(bm + half*64 + row)*DMODEL + bn + c0;
            float4 rv = *(const float4*)(resid + off);
            v.x = sc*v.x + rv.x; v.y = sc*v.y + rv.y;
            v.z = sc*v.z + rv.z; v.w = sc*v.w + rv.w;
            *(float4*)(C + off) = v;
        }
        __syncthreads();
    }
}

// ---------------- fused fp32 -> bf16 casts, vectorized 8 elem/thread ----------------
#define NC1 (ROWS*DMODEL)
#define NC2 (NPAD1*DMODEL)
#define NC3 (DMODEL*DINNER)
#define NV1 (NC1/8)
#define NV2 (NC2/8)
#define NV3 (NC3/8)
__global__ __launch_bounds__(256)
void cast_all(const float* __restrict__ feature, const float* __restrict__ in_w,
              const float* __restrict__ out_w, const float* __restrict__ nw,
              __hip_bfloat16* __restrict__ fbf, __hip_bfloat16* __restrict__ wbf,
              __hip_bfloat16* __restrict__ owbf)
{
    int v = blockIdx.x*256 + threadIdx.x;
    if (v < NV1) {
        int i = v*8;
        float4 a = *(const float4*)(feature + i);
        float4 b = *(const float4*)(feature + i + 4);
        bf16x8 o;
        o[0]=cvt_bf(a.x); o[1]=cvt_bf(a.y); o[2]=cvt_bf(a.z); o[3]=cvt_bf(a.w);
        o[4]=cvt_bf(b.x); o[5]=cvt_bf(b.y); o[6]=cvt_bf(b.z); o[7]=cvt_bf(b.w);
        *(bf16x8*)(fbf + i) = o;
    } else if (v < NV1 + NV2) {
        int j = (v - NV1)*8;
        int n = j / DMODEL, k = j - n*DMODEL;
        bf16x8 o;
        if (n < DPROJ) {
            const float* s = in_w + (size_t)n*DMODEL + k;
            float4 a = *(const float4*)(s);
            float4 b = *(const float4*)(s + 4);
            o[0]=cvt_bf(a.x); o[1]=cvt_bf(a.y); o[2]=cvt_bf(a.z); o[3]=cvt_bf(a.w);
            o[4]=cvt_bf(b.x); o[5]=cvt_bf(b.y); o[6]=cvt_bf(b.z); o[7]=cvt_bf(b.w);
        } else {
#pragma unroll
            for (int q = 0; q < 8; ++q) o[q] = (__bf16)0.f;
        }
        *(bf16x8*)(wbf + j) = o;
    } else if (v < NV1 + NV2 + NV3) {
        int j = (v - NV1 - NV2)*8;
        int k = j % DINNER;
        float4 a  = *(const float4*)(out_w + j);
        float4 b  = *(const float4*)(out_w + j + 4);
        float4 na = *(const float4*)(nw + k);
        float4 nb = *(const float4*)(nw + k + 4);
        bf16x8 o;
        o[0]=cvt_bf(a.x*na.x); o[1]=cvt_bf(a.y*na.y); o[2]=cvt_bf(a.z*na.z); o[3]=cvt_bf(a.w*na.w);
        o[4]=cvt_bf(b.x*nb.x); o[5]=cvt_bf(b.y*nb.y); o[6]=cvt_bf(b.z*nb.z); o[7]=cvt_bf(b.w*nb.w);
        *(bf16x8*)(owbf + j) = o;
    }
}

// ======== FUSED conv4+SiLU (blockIdx.x<14) + intra-chunk cumsum scan (>=14) ========
__global__ __launch_bounds__(256)
void conv_scan_k(const __hip_bfloat16* __restrict__ xbc16, const float* __restrict__ cw,
                 const float* __restrict__ cbias,
                 __hip_bfloat16* __restrict__ x_t,
                 __hip_bfloat16* __restrict__ B_n, __hip_bfloat16* __restrict__ B_t,
                 __hip_bfloat16* __restrict__ C_n,
                 const float* __restrict__ dtb, const float* __restrict__ A_log,
                 float* __restrict__ acum)
{
    int xb = blockIdx.x;
    if (xb >= 14) {
        // ---- scan path: h = xb-14, c = blockIdx.y, b = blockIdx.z ----
        __shared__ float sh2[256];
        int h = xb - 14, c = blockIdx.y, b = blockIdx.z;
        int tid = threadIdx.x;
        int l = tid & 127, g2 = tid >> 7;
        float* sh = sh2 + g2*128;
        float Aa = -__expf(A_log[h]);
        size_t row = (size_t)b*SEQ + c*CHUNK + l;
        float v = dtb[row*NHEADS + h] * Aa;
        sh[l] = v; __syncthreads();
        for (int off=1; off<128; off<<=1){
            float t = (l>=off) ? sh[l-off] : 0.f;
            __syncthreads();
            sh[l] += t;
            __syncthreads();
        }
        if (g2 == 0)
            acum[((b*NHEADS+h)*NCHUNK + c)*CHUNK + l] = sh[l];
        return;
    }
    // ---- conv path ----
    __shared__ __align__(16) __hip_bfloat16 in[131*LDTC];
    int ct = xb, lt = blockIdx.y, b = blockIdx.z;
    int tid = threadIdx.x;
    int base = lt*128;
    for (int it = 0; it < 2096; it += 256) {
        int e = it + tid; if (e >= 2096) break;
        int row = e >> 4, c0 = (e & 15)*8;
        int l = base - 3 + row;
        bf16x8 v;
        if (l < 0) { for (int j = 0; j < 8; ++j) v[j] = (__bf16)0.f; }
        else v = *(const bf16x8*)(xbc16 + ((size_t)b*SEQ + l)*DXBC + ct*128 + c0);
        *(bf16x8*)(in + row*LDTC + c0) = v;
    }
    __syncthreads();
    int ch = tid & 127, lh = tid >> 7, l0 = lh*64;
    int g = ct*128 + ch;
    float w0 = cw[g*4+0], w1 = cw[g*4+1], w2 = cw[g*4+2], w3 = cw[g*4+3];
    float bias = cbias[g];
    float a0 = __bfloat162float(in[(l0+0)*LDTC + ch]);
    float a1 = __bfloat162float(in[(l0+1)*LDTC + ch]);
    float a2 = __bfloat162float(in[(l0+2)*LDTC + ch]);
    size_t trow = 0;
    if (ct < 12)      trow = ((size_t)b*NHEADS + (g>>6))*HEADDIM + (g & 63);
    else if (ct == 12) trow = (size_t)b*DSTATE + ch;
    bf16x8 obuf;
#pragma unroll
    for (int li = 0; li < 64; ++li) {
        float a3 = __bfloat162float(in[(l0+li+3)*LDTC + ch]);
        float o = siluf_(bias + w0*a0 + w1*a1 + w2*a2 + w3*a3);
        a0 = a1; a1 = a2; a2 = a3;
        __hip_bfloat16 ob = __float2bfloat16(o);
        size_t rr = (size_t)b*SEQ + base + l0 + li;
        if (ct == 12)      B_n[rr*DSTATE + ch] = ob;
        else if (ct == 13) C_n[rr*DSTATE + ch] = ob;
        obuf[li & 7] = *(const __bf16*)&ob;
        if ((li & 7) == 7 && ct <= 12) {
            __hip_bfloat16* dst = (ct < 12) ? x_t : B_t;
            *(bf16x8*)(dst + trow*SEQ + base + l0 + (li - 7)) = obuf;
        }
    }
}

// ======== FUSED CB (blockIdx.x<64) + states (>=64) ========
__global__ __launch_bounds__(256)
void cbst_k(const __hip_bfloat16* __restrict__ B_n, const __hip_bfloat16* __restrict__ C_n,
            __hip_bfloat16* __restrict__ CB16,
            const __hip_bfloat16* __restrict__ x_t, const __hip_bfloat16* __restrict__ B_t,
            const float* __restrict__ dtb, const float* __restrict__ acum,
            __hip_bfloat16* __restrict__ states)
{
    int bid = blockIdx.x;
    int tid = threadIdx.x, lane = tid & 63, wave = tid >> 6;
    if (bid < 64) {
        int c = bid & 31, b = bid >> 5;
        size_t base = (size_t)b*SEQ + c*CHUNK;
        int r16 = lane & 15, kq = (lane>>4)*8;
        floatx4 acc[2][8] = {};
#pragma unroll
        for (int ks = 0; ks < 4; ++ks) {
            int k0 = ks*32 + kq;
            bf16x8 af[2], bfv[8];
#pragma unroll
            for (int mt = 0; mt < 2; ++mt)
                af[mt] = *(const bf16x8*)(C_n + (base + (wave*2+mt)*16 + r16)*DSTATE + k0);
#pragma unroll
            for (int st = 0; st < 8; ++st)
                bfv[st] = *(const bf16x8*)(B_n + (base + st*16 + r16)*DSTATE + k0);
#pragma unroll
            for (int mt = 0; mt < 2; ++mt)
#pragma unroll
                for (int st = 0; st < 8; ++st)
                    if (st <= wave*2+mt)
                        acc[mt][st] = __builtin_amdgcn_mfma_f32_16x16x32_bf16(
                            af[mt], bfv[st], acc[mt][st], 0,0,0);
        }
        size_t cbb = (size_t)(b*NCHUNK+c)*CHUNK*CHUNK;
        int scol = lane & 15, rowq = (lane>>4)*4;
#pragma unroll
        for (int mt = 0; mt < 2; ++mt)
#pragma unroll
            for (int st = 0; st < 8; ++st)
                if (st <= wave*2+mt)
#pragma unroll
                    for (int r = 0; r < 4; ++r)
                        CB16[cbb + (size_t)((wave*2+mt)*16 + rowq + r)*CHUNK + st*16 + scol] =
                            __float2bfloat16(acc[mt][st][r]);
        return;
    }
    // ---- states[p][n] = sum_l (x[l,p]*f[l]) * B[l,n], f = dt*dec ----
    __shared__ float f[128];
    int t = bid - 64;
    int c = t & 31;
    int h = (t>>5) % NHEADS;
    int b = t/(32*NHEADS);
    int arow = ((b*NHEADS+h)*NCHUNK + c)*CHUNK;
    size_t rbase = (size_t)b*SEQ + c*CHUNK;
    if (tid < 128) {
        float alast = acum[arow + 127];
        f[tid] = dtb[(rbase + tid)*NHEADS + h] * __expf(alast - acum[arow + tid]);
    }
    __syncthreads();
    int r16 = lane & 15, kq = (lane>>4)*8;
    size_t xtb = ((size_t)b*NHEADS + h)*HEADDIM;
    int cl = c*CHUNK;
    floatx4 acc[8] = {};
#pragma unroll
    for (int ks = 0; ks < 4; ++ks) {
        int k0 = ks*32 + kq;
        bf16x8 xa = *(const bf16x8*)(x_t + (xtb + wave*16 + r16)*SEQ + cl + k0);
        bf16x8 af;
#pragma unroll
        for (int j = 0; j < 8; ++j)
            af[j] = (__bf16)((float)xa[j] * f[k0 + j]);
        bf16x8 bfv[8];
#pragma unroll
        for (int nt = 0; nt < 8; ++nt)
            bfv[nt] = *(const bf16x8*)(B_t + ((size_t)b*DSTATE + nt*16 + r16)*SEQ + cl + k0);
#pragma unroll
        for (int nt = 0; nt < 8; ++nt)
            acc[nt] = __builtin_amdgcn_mfma_f32_16x16x32_bf16(af, bfv[nt], acc[nt], 0,0,0);
    }
    size_t sb = ((size_t)(b*NCHUNK+c)*NHEADS + h)*(HEADDIM*DSTATE);
    int ncol = lane & 15, rowq = (lane>>4)*4;
#pragma unroll
    for (int nt = 0; nt < 8; ++nt)
#pragma unroll
        for (int r = 0; r < 4; ++r)
            states[sb + (size_t)(wave*16 + rowq + r)*DSTATE + nt*16 + ncol] =
                __float2bfloat16(acc[nt][r]);
}

// ---- sequential inter-chunk recurrence, in place (bf16): states[c] := prev[c] ----
__global__ __launch_bounds__(64)
void recur_k(__hip_bfloat16* __restrict__ states, const float* __restrict__ acum)
{
    int pb = blockIdx.x & 15;
    int bh = blockIdx.x >> 4;
    int h = bh % NHEADS, b = bh / NHEADS;
    int voff = (pb*64 + threadIdx.x)*8;
    const size_t cstride = (size_t)NHEADS*HEADDIM*DSTATE;
    size_t base0 = ((size_t)(b*NCHUNK)*NHEADS + h)*(HEADDIM*DSTATE) + voff;
    bf16x8 st[NCHUNK];
    float ev[NCHUNK];
#pragma unroll
    for (int c = 0; c < NCHUNK; ++c)
        st[c] = *(const bf16x8*)(states + base0 + (size_t)c*cstride);
#pragma unroll
    for (int c = 0; c < NCHUNK; ++c)
        ev[c] = __expf(acum[((b*NHEADS+h)*NCHUNK + c)*CHUNK + 127]);
    float S[8] = {};
#pragma unroll
    for (int c = 0; c < NCHUNK; ++c) {
        bf16x8 pv;
#pragma unroll
        for (int j = 0; j < 8; ++j) {
            pv[j] = (__bf16)S[j];
            S[j] = S[j]*ev[c] + (float)st[c][j];
        }
        *(bf16x8*)(states + base0 + (size_t)c*cstride) = pv;
    }
}

// ======== Y = [tril(CB*exp(dAc)*dt)+D*I] @ x + (C*exp(ac)) @ prev^T; then
//          g = Y*silu(z) -> y16; rowsq += per-row sum(g^2) (atomic) ========
// Persistent grid: 512 blocks x 3 units, launch_bounds(512,4) (2 blocks/CU,
// all co-resident, balanced). Batched global loads; LDEY=65 epilogue.
__global__ __launch_bounds__(512, 4)
void y_mfma(const __hip_bfloat16* __restrict__ x_t, const __hip_bfloat16* __restrict__ z16,
            const __hip_bfloat16* __restrict__ C_n, const __hip_bfloat16* __restrict__ CB16,
            const __hip_bfloat16* __restrict__ states, const float* __restrict__ dtb,
            const float* __restrict__ acum, const float* __restrict__ Dp,
            __hip_bfloat16* __restrict__ y16, float* __restrict__ rowsq)
{
    __shared__ __align__(16) char smem[33280];    // max(XT+ST 32K, 128*65*4 epi)
    __hip_bfloat16* XT = (__hip_bfloat16*)smem;   // [64 p][128 k] swizzled (16KB)
    __hip_bfloat16* ST = XT + 64*128;             // [64 p][128 n] swizzled (16KB)
    float* Tsm = (float*)smem;                    // [128][LDEY] fp32 epilogue reuse
    __shared__ float ac[128], dts[128], gk[128];
    const int tid = threadIdx.x, lane = tid & 63, wave = tid >> 6;
    const int r16 = lane & 15, kq = (lane>>4)*8;
    const int l = wave*16 + r16;
    const int pcol = lane & 15, rowq = (lane>>4)*4;
    const int erow = tid >> 2, ec0 = (tid & 3)*16;   // epilogue mapping
#pragma unroll 1
    for (int u = blockIdx.x; u < B_SZ*NHEADS*NCHUNK; u += 512) {
        int c = u & 31;
        int h = (u>>5) % NHEADS;
        int b = u/(32*NHEADS);
        int arow = ((b*NHEADS+h)*NCHUNK + c)*CHUNK;
        size_t rbase = (size_t)b*SEQ + c*CHUNK;
        size_t xtb = ((size_t)b*NHEADS + h)*HEADDIM;
        size_t sb  = ((size_t)(b*NCHUNK+c)*NHEADS + h)*(HEADDIM*DSTATE);
        size_t cbb = (size_t)(b*NCHUNK+c)*CHUNK*CHUNK;
        int cl = c*CHUNK;
        // stage x_t and states tiles (1024 16B-chunks each; 4 per thread)
#pragma unroll
        for (int j = 0; j < 2; ++j) {
            int cc = j*512 + tid;
            int p = cc >> 4, ch = cc & 15;
            int sj = ch ^ (p & 7);
            gload_lds16(x_t + (xtb + p)*SEQ + cl + sj*8, XT + cc*8);
            gload_lds16(states + sb + (size_t)p*DSTATE + sj*8, ST + cc*8);
        }
        if (tid < 128) {
            ac[tid]  = acum[arow + tid];
            dts[tid] = dtb[(rbase + tid)*NHEADS + h];
        }
        __syncthreads();   // drains gload_lds; ac/dts visible
        if (tid < 128)
            gk[tid] = __expf(ac[tid & 96] - ac[tid]) * dts[tid];
        // ---- batch ALL global loads for this unit (independent; in flight
        //      across the barrier; first use waits once) ----
        bf16x8 cb[4], cv[4];
#pragma unroll
        for (int ks = 0; ks < 4; ++ks) {
            cb[ks] = *(const bf16x8*)(CB16 + cbb + (size_t)l*CHUNK + ks*32 + kq);
            cv[ks] = *(const bf16x8*)(C_n + (rbase + l)*DSTATE + ks*32 + kq);
        }
        bf16x8 zA = *(const bf16x8*)(z16 + (rbase + erow)*DINNER + h*HEADDIM + ec0);
        bf16x8 zB = *(const bf16x8*)(z16 + (rbase + erow)*DINNER + h*HEADDIM + ec0 + 8);
        __syncthreads();   // gk visible
        float acl = ac[l];
        float Dh = Dp[h];
        floatx4 acc[4] = {};
        int nks = (wave >> 1) + 1;
#pragma unroll
        for (int ks = 0; ks < 4; ++ks) {
            if (ks < nks) {            // wave-uniform guard
                int k0 = ks*32 + kq;
                float fl = __expf(acl - ac[ks*32]);   // <= 1 (block base <= l)
                bf16x8 af;
#pragma unroll
                for (int j = 0; j < 8; ++j) {
                    int s = k0 + j;
                    float w = (s <= l) ? (float)cb[ks][j] * (fl * gk[s]) : 0.f;
                    if (s == l) w += Dh;           // D*x folded into the diagonal
                    af[j] = (__bf16)w;
                }
                int chL = k0 >> 3;
                bf16x8 bfv[4];
#pragma unroll
                for (int pt = 0; pt < 4; ++pt) {
                    int row = pt*16 + r16;
                    bfv[pt] = *(const bf16x8*)(XT + (row*16 + (chL ^ (row & 7)))*8);
                }
#pragma unroll
                for (int pt = 0; pt < 4; ++pt)
                    acc[pt] = __builtin_amdgcn_mfma_f32_16x16x32_bf16(af, bfv[pt], acc[pt], 0,0,0);
            }
        }
        float eal = __expf(acl);
#pragma unroll
        for (int ks = 0; ks < 4; ++ks) {
            int k0 = ks*32 + kq;
            bf16x8 af;
#pragma unroll
            for (int j = 0; j < 8; ++j)
                af[j] = (__bf16)((float)cv[ks][j] * eal);
            int chL = k0 >> 3;
            bf16x8 bfv[4];
#pragma unroll
            for (int pt = 0; pt < 4; ++pt) {
                int row = pt*16 + r16;
                bfv[pt] = *(const bf16x8*)(ST + (row*16 + (chL ^ (row & 7)))*8);
            }
#pragma unroll
            for (int pt = 0; pt < 4; ++pt)
                acc[pt] = __builtin_amdgcn_mfma_f32_16x16x32_bf16(af, bfv[pt], acc[pt], 0,0,0);
        }
        __syncthreads();   // all XT/ST reads complete before Tsm overwrite
        // single-phase epilogue: 8 waves write disjoint 16-row bands
#pragma unroll
        for (int pt = 0; pt < 4; ++pt)
#pragma unroll
            for (int r = 0; r < 4; ++r)
                Tsm[(wave*16 + rowq + r)*LDEY + pt*16 + pcol] = acc[pt][r];
        __syncthreads();
        {
            float s = 0.f; bf16x8 o1, o2;
#pragma unroll
            for (int j2 = 0; j2 < 8; ++j2) {
                float g = Tsm[erow*LDEY + ec0 + j2] * siluf_(__bfloat162float(zA[j2]));
                o1[j2] = cvt_bf(g); s += g*g;
            }
#pragma unroll
            for (int j2 = 0; j2 < 8; ++j2) {
                float g = Tsm[erow*LDEY + ec0 + 8 + j2] * siluf_(__bfloat162float(zB[j2]));
                o2[j2] = cvt_bf(g); s += g*g;
            }
            size_t grow = rbase + erow;
            *(bf16x8*)(y16 + grow*DINNER + h*HEADDIM + ec0)     = o1;
            *(bf16x8*)(y16 + grow*DINNER + h*HEADDIM + ec0 + 8) = o2;
            s += __shfl_xor(s, 1); s += __shfl_xor(s, 2);
            if ((tid & 3) == 0)
                atomicAdd(rowsq + grow, s);
        }
        __syncthreads();   // Tsm/ac/dts safe to overwrite next unit
    }
}

extern "C" void kernel_launch(void* const* d_in, const int* in_sizes, int n_in,
                              void* d_out, int out_size, void* d_ws, size_t ws_size,
                              hipStream_t stream)
{
    const float* feature = (const float*)d_in[0];
    const float* gate1   = (const float*)d_in[1];
    const float* in_w    = (const float*)d_in[2];
    const float* conv_w  = (const float*)d_in[3];
    const float* conv_b  = (const float*)d_in[4];
    const float* dt_bias = (const float*)d_in[5];
    const float* A_log   = (const float*)d_in[6];
    const float* Dp      = (const float*)d_in[7];
    const float* norm_w  = (const float*)d_in[8];
    const float* out_w   = (const float*)d_in[9];
    float* out = (float*)d_out;

    // workspace layout — ~161 MB (< 256 MiB)
    char* p = (char*)d_ws;
    __hip_bfloat16* z16   = (__hip_bfloat16*)p; p += (size_t)ROWS*DINNER*2;  // 25.2 MB
    __hip_bfloat16* xbc16 = (__hip_bfloat16*)p; p += (size_t)ROWS*DXBC*2;    // 29.4 MB
    __hip_bfloat16* x_t   = (__hip_bfloat16*)p; p += (size_t)ROWS*DINNER*2;  // 25.2 MB
    __hip_bfloat16* B_n   = (__hip_bfloat16*)p; p += (size_t)ROWS*DSTATE*2;  // 2.1 MB
    __hip_bfloat16* B_t   = (__hip_bfloat16*)p; p += (size_t)ROWS*DSTATE*2;  // 2.1 MB
    __hip_bfloat16* C_n   = (__hip_bfloat16*)p; p += (size_t)ROWS*DSTATE*2;  // 2.1 MB
    float* dtb    = (float*)p;            p += (size_t)ROWS*NHEADS*4;        // 0.8 MB
    float* acum   = (float*)p;            p += (size_t)B_SZ*NHEADS*NCHUNK*CHUNK*4; // 0.8 MB
    float* rowsq  = (float*)p;            p += (size_t)ROWS*4;               // 32 KB
    __hip_bfloat16* CB16 = (__hip_bfloat16*)p; p += (size_t)B_SZ*NCHUNK*CHUNK*CHUNK*2; // 2.1 MB
    __hip_bfloat16* states = (__hip_bfloat16*)p; p += (size_t)B_SZ*NCHUNK*NHEADS*HEADDIM*DSTATE*2; // 25.2 MB
    __hip_bfloat16* y16  = (__hip_bfloat16*)p; p += (size_t)ROWS*DINNER*2;   // 25.2 MB
    __hip_bfloat16* fbf  = (__hip_bfloat16*)p; p += (size_t)ROWS*DMODEL*2;   // 12.6 MB
    __hip_bfloat16* wbf  = (__hip_bfloat16*)p; p += (size_t)NPAD1*DMODEL*2;  //  5.3 MB
    __hip_bfloat16* owbf = (__hip_bfloat16*)p; p += (size_t)DMODEL*DINNER*2; //  2.4 MB

    cast_all<<<(NV1+NV2+NV3+255)/256, 256, 0, stream>>>(feature, in_w, out_w, norm_w,
                                                        fbf, wbf, owbf);
    hipMemsetAsync(rowsq, 0, (size_t)ROWS*4, stream);

    gemm1_mfma<<<27*32, 512, 0, stream>>>(fbf, wbf, z16, xbc16, dtb, dt_bias);
    conv_scan_k<<<dim3(14 + NHEADS, 32, B_SZ), 256, 0, stream>>>(
        xbc16, conv_w, conv_b, x_t, B_n, B_t, C_n, dtb, A_log, acum);
    cbst_k<<<64 + B_SZ*NHEADS*NCHUNK, 256, 0, stream>>>(
        B_n, C_n, CB16, x_t, B_t, dtb, acum, states);
    recur_k<<<B_SZ*NHEADS*16, 64, 0, stream>>>(states, acum);
    y_mfma<<<512, 512, 0, stream>>>(x_t, z16, C_n, CB16, states,
                                    dtb, acum, Dp, y16, rowsq);
    gemm2_mfma<<<6*64, 256, 0, stream>>>(y16, owbf, out, gate1, feature, rowsq);
}

// Round 10
// 277.429 us; speedup vs baseline: 1.2175x; 1.0307x over previous
//
#include <hip/hip_runtime.h>
#include <hip/hip_bf16.h>
#include <math.h>

#define B_SZ 2
#define SEQ 4096
#define DMODEL 768
#define DSTATE 128
#define HEADDIM 64
#define DINNER 1536
#define NHEADS 24
#define DXBC 1792
#define DPROJ 3352
#define NPAD1 3456
#define CHUNK 128
#define NCHUNK 32
#define ROWS (B_SZ*SEQ)
#define LDTC 136   // padded LDS stride for conv input tile
#define LDE 136    // padded LDS stride (bf16) for epilogue tiles
#define LDE2 132   // padded LDS stride (fp32) for gemm2 epilogue tile
#define LDEY 65    // padded LDS stride (fp32) for y_mfma epilogue (65 ≡ 1 mod 32: bank = row+col)

typedef float floatx4 __attribute__((ext_vector_type(4)));
typedef __bf16 bf16x8 __attribute__((ext_vector_type(8)));

// fast-exp variants: all consumers are bf16 casts / bf16 MFMA operands, so
// __expf's 2-4 ulp f32 error is far below bf16 rounding.
__device__ __forceinline__ float sigmoidf_(float x){ return 1.f/(1.f+__expf(-x)); }
__device__ __forceinline__ float siluf_(float x){ return x/(1.f+__expf(-x)); }
__device__ __forceinline__ float softplusf_(float x){ return (x>20.f)? x : __logf(1.f+__expf(x)); }
__device__ __forceinline__ __bf16 cvt_bf(float x){ __hip_bfloat16 t = __float2bfloat16(x); return *(__bf16*)&t; }

__device__ __forceinline__ void gload_lds16(const __hip_bfloat16* g, __hip_bfloat16* l){
    __builtin_amdgcn_global_load_lds(
        (const __attribute__((address_space(1))) void*)g,
        (__attribute__((address_space(3))) void*)l, 16, 0, 0);
}

// ======== GEMM1: 256x128 tile, 8 waves; epilogue -> z16 / xbc16 / dtb ========
// R0-exact structure: BK=64, serial stage, 48 KiB LDS, 3 blocks/CU co-residency.
// Measured at 845 TF = 93% of the m97-structure ceiling (~900). DONE.
__global__ __launch_bounds__(512)
void gemm1_mfma(const __hip_bfloat16* __restrict__ A,   // fbf [ROWS][768]
                const __hip_bfloat16* __restrict__ W,   // wbf [3456][768]
                __hip_bfloat16* __restrict__ z16, __hip_bfloat16* __restrict__ xbc16,
                float* __restrict__ dtb, const float* __restrict__ dt_bias)
{
    __shared__ __align__(16) char smem[49152];          // Asm 32K + Wsm 16K
    __hip_bfloat16* Asm = (__hip_bfloat16*)smem;        // [256][64]
    __hip_bfloat16* Wsm = Asm + 256*64;                 // [128][64]
    const int tid = threadIdx.x;
    const int lane = tid & 63, wave = tid >> 6;
    const int blk = blockIdx.x;
    const int m_tile = ((blk & 7) << 2) | ((blk >> 3) & 3);   // 32 M-tiles, XCD band
    const int bx = blk >> 5;                                   // N-tile 0..26
    const int bm = m_tile*256, bn = bx*128;
    const int wm = (wave & 3)*64, wn = (wave >> 2)*64;
    const int r16 = lane & 15, qbase = lane >> 4, sw = r16 & 7;
    floatx4 acc[4][4] = {};
    for (int k0 = 0; k0 < DMODEL; k0 += 64) {
#pragma unroll
        for (int j = 0; j < 4; ++j) {
            int cc = j*512 + tid;                // A: 2048 chunks
            int row = cc >> 3, jc = cc & 7;
            int sj = jc ^ (row & 7);
            gload_lds16(A + (size_t)(bm+row)*DMODEL + k0 + sj*8, Asm + cc*8);
        }
#pragma unroll
        for (int j = 0; j < 2; ++j) {
            int cc = j*512 + tid;                // W: 1024 chunks
            int row = cc >> 3, jc = cc & 7;
            int sj = jc ^ (row & 7);
            gload_lds16(W + (size_t)(bn+row)*DMODEL + k0 + sj*8, Wsm + cc*8);
        }
        __syncthreads();
#pragma unroll
        for (int ks = 0; ks < 2; ++ks) {
            const int kq = ((qbase + ks*4) ^ sw)*8;
            bf16x8 af[4], wf[4];
#pragma unroll
            for (int i = 0; i < 4; ++i) {
                af[i] = *(const bf16x8*)(Asm + (wm + i*16 + r16)*64 + kq);
                wf[i] = *(const bf16x8*)(Wsm + (wn + i*16 + r16)*64 + kq);
            }
#pragma unroll
            for (int mi = 0; mi < 4; ++mi)
#pragma unroll
                for (int ni = 0; ni < 4; ++ni)
                    acc[mi][ni] = __builtin_amdgcn_mfma_f32_16x16x32_bf16(
                        af[mi], wf[ni], acc[mi][ni], 0, 0, 0);
        }
        __syncthreads();
    }
    const int col = lane & 15, rowq = (lane >> 4)*4;
    if (bx == 26) {
        if (wn == 0) {
#pragma unroll
            for (int mi = 0; mi < 4; ++mi)
#pragma unroll
                for (int ni = 0; ni < 2; ++ni) {
                    int h = ni*16 + col;
                    if (h < NHEADS)
#pragma unroll
                        for (int r = 0; r < 4; ++r) {
                            int m = bm + wm + mi*16 + rowq + r;
                            dtb[(size_t)m*NHEADS + h] =
                                softplusf_(acc[mi][ni][r] + dt_bias[h]);
                        }
                }
        }
        return;
    }
    __hip_bfloat16* Tsm = (__hip_bfloat16*)smem;   // [128][LDE]
    __hip_bfloat16* dst; int ldd;
    if (bx < 12) { dst = z16 + bn;            ldd = DINNER; }
    else         { dst = xbc16 + bn - DINNER; ldd = DXBC;  }
    for (int half = 0; half < 2; ++half) {
        if (((wave & 3) >> 1) == half) {
#pragma unroll
            for (int mi = 0; mi < 4; ++mi)
#pragma unroll
                for (int ni = 0; ni < 4; ++ni)
#pragma unroll
                    for (int r = 0; r < 4; ++r)
                        Tsm[(wm - half*128 + mi*16 + rowq + r)*LDE + wn + ni*16 + col] =
                            __float2bfloat16(acc[mi][ni][r]);
        }
        __syncthreads();
#pragma unroll
        for (int it = 0; it < 4; ++it) {
            int e = it*512 + tid;
            int row = e >> 4, c0 = (e & 15)*8;
            bf16x8 v = *(const bf16x8*)(Tsm + row*LDE + c0);
            *(bf16x8*)(dst + (size_t)(bm + half*128 + row)*ldd + c0) = v;
        }
        __syncthreads();
    }
}

// ======== GEMM2: 128x128 tile, 4 waves (2x2), 384 blocks (R9, proven) ========
__global__ __launch_bounds__(256)
void gemm2_mfma(const __hip_bfloat16* __restrict__ A,   // y16 [ROWS][1536] (gated)
                const __hip_bfloat16* __restrict__ W,   // owbf [768][1536]
                float* __restrict__ C,
                const float* __restrict__ gate, const float* __restrict__ resid,
                const float* __restrict__ rowsq)
{
    __shared__ __align__(16) char smem[33792];          // staging 32K; epi 64*LDE2*4
    __shared__ float scale_lds[128];
    __hip_bfloat16* Asm = (__hip_bfloat16*)smem;        // [128][64]
    __hip_bfloat16* Wsm = Asm + 128*64;                 // [128][64]
    const int tid = threadIdx.x;
    const int lane = tid & 63, wave = tid >> 6;         // 4 waves
    const int blk = blockIdx.x;
    const int mblk = blk & 63;
    const int m_tile = ((mblk & 7) << 3) | (mblk >> 3); // 64 M-tiles, XCD band
    const int bm = m_tile*128, bn = (blk >> 6)*128;     // n-tile 0..5
    const int wm = (wave & 1)*64, wn = (wave >> 1)*64;
    const int r16 = lane & 15, qbase = lane >> 4, sw = r16 & 7;
    floatx4 acc[4][4] = {};
    for (int k0 = 0; k0 < DINNER; k0 += 64) {
#pragma unroll
        for (int j = 0; j < 4; ++j) {
            int cc = j*256 + tid;                // A: 1024 chunks (128 rows x 8)
            int row = cc >> 3, jc = cc & 7;
            int sj = jc ^ (row & 7);
            gload_lds16(A + (size_t)(bm+row)*DINNER + k0 + sj*8, Asm + cc*8);
        }
#pragma unroll
        for (int j = 0; j < 4; ++j) {
            int cc = j*256 + tid;                // W: 1024 chunks
            int row = cc >> 3, jc = cc & 7;
            int sj = jc ^ (row & 7);
            gload_lds16(W + (size_t)(bn+row)*DINNER + k0 + sj*8, Wsm + cc*8);
        }
        __syncthreads();
#pragma unroll
        for (int ks = 0; ks < 2; ++ks) {
            const int kq = ((qbase + ks*4) ^ sw)*8;
            bf16x8 af[4], wf[4];
#pragma unroll
            for (int i = 0; i < 4; ++i) {
                af[i] = *(const bf16x8*)(Asm + (wm + i*16 + r16)*64 + kq);
                wf[i] = *(const bf16x8*)(Wsm + (wn + i*16 + r16)*64 + kq);
            }
#pragma unroll
            for (int mi = 0; mi < 4; ++mi)
#pragma unroll
                for (int ni = 0; ni < 4; ++ni)
                    acc[mi][ni] = __builtin_amdgcn_mfma_f32_16x16x32_bf16(
                        af[mi], wf[ni], acc[mi][ni], 0, 0, 0);
        }
        __syncthreads();
    }
    if (tid < 128)
        scale_lds[tid] = rsqrtf(rowsq[bm + tid] * (1.f/DINNER) + 1e-5f);
    float gs = sigmoidf_(gate[0]);
    __syncthreads();
    const int col = lane & 15, rowq = (lane >> 4)*4;
    float* Tsm = (float*)smem;   // 64 x LDE2 fp32
    for (int half = 0; half < 2; ++half) {
        if ((wave & 1) == half) {     // two waves per half, disjoint wn columns
#pragma unroll
            for (int mi = 0; mi < 4; ++mi)
#pragma unroll
                for (int ni = 0; ni < 4; ++ni)
#pragma unroll
                    for (int r = 0; r < 4; ++r)
                        Tsm[(mi*16 + rowq + r)*LDE2 + wn + ni*16 + col] = acc[mi][ni][r];
        }
        __syncthreads();
#pragma unroll
        for (int it = 0; it < 8; ++it) {
            int e = it*256 + tid;
            int row = e >> 5, c0 = (e & 31)*4;
            float4 v = *(const float4*)(Tsm + row*LDE2 + c0);
            float sc = gs * scale_lds[half*64 + row];
            size_t off = (size_t)(bm + half*64 + row)*DMODEL + bn + c0;
            float4 rv = *(const float4*)(resid + off);
            v.x = sc*v.x + rv.x; v.y = sc*v.y + rv.y;
            v.z = sc*v.z + rv.z; v.w = sc*v.w + rv.w;
            *(float4*)(C + off) = v;
        }
        __syncthreads();
    }
}

// -------- fused fp32 -> bf16 casts (8 elem/thread) + rowsq zeroing tail --------
#define NC1 (ROWS*DMODEL)
#define NC2 (NPAD1*DMODEL)
#define NC3 (DMODEL*DINNER)
#define NV1 (NC1/8)
#define NV2 (NC2/8)
#define NV3 (NC3/8)
#define NVR (ROWS/8)
__global__ __launch_bounds__(256)
void cast_all(const float* __restrict__ feature, const float* __restrict__ in_w,
              const float* __restrict__ out_w, const float* __restrict__ nw,
              __hip_bfloat16* __restrict__ fbf, __hip_bfloat16* __restrict__ wbf,
              __hip_bfloat16* __restrict__ owbf, float* __restrict__ rowsq)
{
    int v = blockIdx.x*256 + threadIdx.x;
    if (v < NV1) {
        int i = v*8;
        float4 a = *(const float4*)(feature + i);
        float4 b = *(const float4*)(feature + i + 4);
        bf16x8 o;
        o[0]=cvt_bf(a.x); o[1]=cvt_bf(a.y); o[2]=cvt_bf(a.z); o[3]=cvt_bf(a.w);
        o[4]=cvt_bf(b.x); o[5]=cvt_bf(b.y); o[6]=cvt_bf(b.z); o[7]=cvt_bf(b.w);
        *(bf16x8*)(fbf + i) = o;
    } else if (v < NV1 + NV2) {
        int j = (v - NV1)*8;
        int n = j / DMODEL, k = j - n*DMODEL;
        bf16x8 o;
        if (n < DPROJ) {
            const float* s = in_w + (size_t)n*DMODEL + k;
            float4 a = *(const float4*)(s);
            float4 b = *(const float4*)(s + 4);
            o[0]=cvt_bf(a.x); o[1]=cvt_bf(a.y); o[2]=cvt_bf(a.z); o[3]=cvt_bf(a.w);
            o[4]=cvt_bf(b.x); o[5]=cvt_bf(b.y); o[6]=cvt_bf(b.z); o[7]=cvt_bf(b.w);
        } else {
#pragma unroll
            for (int q = 0; q < 8; ++q) o[q] = (__bf16)0.f;
        }
        *(bf16x8*)(wbf + j) = o;
    } else if (v < NV1 + NV2 + NV3) {
        int j = (v - NV1 - NV2)*8;
        int k = j % DINNER;
        float4 a  = *(const float4*)(out_w + j);
        float4 b  = *(const float4*)(out_w + j + 4);
        float4 na = *(const float4*)(nw + k);
        float4 nb = *(const float4*)(nw + k + 4);
        bf16x8 o;
        o[0]=cvt_bf(a.x*na.x); o[1]=cvt_bf(a.y*na.y); o[2]=cvt_bf(a.z*na.z); o[3]=cvt_bf(a.w*na.w);
        o[4]=cvt_bf(b.x*nb.x); o[5]=cvt_bf(b.y*nb.y); o[6]=cvt_bf(b.z*nb.z); o[7]=cvt_bf(b.w*nb.w);
        *(bf16x8*)(owbf + j) = o;
    } else if (v < NV1 + NV2 + NV3 + NVR) {
        int j = (v - NV1 - NV2 - NV3)*8;
        float4 z = {0.f, 0.f, 0.f, 0.f};
        *(float4*)(rowsq + j) = z;
        *(float4*)(rowsq + j + 4) = z;
    }
}

// ======== FUSED conv4+SiLU (blockIdx.x<14) + cumsum scan (>=14), 512 thr ========
// Conv: 8 waves, each thread 32 l-positions (serial chain halved vs 256-thr).
// Scan: wave-shuffle Hillis-Steele (6 shfl steps) + 1 cross-wave LDS handoff
// (1 barrier instead of 14).
__global__ __launch_bounds__(512)
void conv_scan_k(const __hip_bfloat16* __restrict__ xbc16, const float* __restrict__ cw,
                 const float* __restrict__ cbias,
                 __hip_bfloat16* __restrict__ x_t,
                 __hip_bfloat16* __restrict__ B_n, __hip_bfloat16* __restrict__ B_t,
                 __hip_bfloat16* __restrict__ C_n,
                 const float* __restrict__ dtb, const float* __restrict__ A_log,
                 float* __restrict__ acum)
{
    int xb = blockIdx.x;
    int tid = threadIdx.x;
    if (xb >= 14) {
        // ---- scan path: h = xb-14, c = blockIdx.y, b = blockIdx.z ----
        __shared__ float wtot;
        int h = xb - 14, c = blockIdx.y, b = blockIdx.z;
        int lane = tid & 63;
        float s = 0.f;
        if (tid < 128) {
            float Aa = -__expf(A_log[h]);
            s = dtb[((size_t)b*SEQ + c*CHUNK + tid)*NHEADS + h] * Aa;
#pragma unroll
            for (int off = 1; off < 64; off <<= 1) {
                float t = __shfl_up(s, off);
                if (lane >= off) s += t;
            }
            if (tid == 63) wtot = s;
        }
        __syncthreads();
        if (tid >= 64 && tid < 128) s += wtot;
        if (tid < 128)
            acum[((b*NHEADS+h)*NCHUNK + c)*CHUNK + tid] = s;
        return;
    }
    // ---- conv path ----
    __shared__ __align__(16) __hip_bfloat16 in[131*LDTC];
    int ct = xb, lt = blockIdx.y, b = blockIdx.z;
    int base = lt*128;
    for (int it = 0; it < 2096; it += 512) {
        int e = it + tid; if (e >= 2096) break;
        int row = e >> 4, c0 = (e & 15)*8;
        int l = base - 3 + row;
        bf16x8 v;
        if (l < 0) { for (int j = 0; j < 8; ++j) v[j] = (__bf16)0.f; }
        else v = *(const bf16x8*)(xbc16 + ((size_t)b*SEQ + l)*DXBC + ct*128 + c0);
        *(bf16x8*)(in + row*LDTC + c0) = v;
    }
    __syncthreads();
    int ch = tid & 127, lh = tid >> 7, l0 = lh*32;   // 4 l-groups of 32
    int g = ct*128 + ch;
    float w0 = cw[g*4+0], w1 = cw[g*4+1], w2 = cw[g*4+2], w3 = cw[g*4+3];
    float bias = cbias[g];
    float a0 = __bfloat162float(in[(l0+0)*LDTC + ch]);
    float a1 = __bfloat162float(in[(l0+1)*LDTC + ch]);
    float a2 = __bfloat162float(in[(l0+2)*LDTC + ch]);
    size_t trow = 0;
    if (ct < 12)      trow = ((size_t)b*NHEADS + (g>>6))*HEADDIM + (g & 63);
    else if (ct == 12) trow = (size_t)b*DSTATE + ch;
    bf16x8 obuf;
#pragma unroll
    for (int li = 0; li < 32; ++li) {
        float a3 = __bfloat162float(in[(l0+li+3)*LDTC + ch]);
        float o = siluf_(bias + w0*a0 + w1*a1 + w2*a2 + w3*a3);
        a0 = a1; a1 = a2; a2 = a3;
        __hip_bfloat16 ob = __float2bfloat16(o);
        size_t rr = (size_t)b*SEQ + base + l0 + li;
        if (ct == 12)      B_n[rr*DSTATE + ch] = ob;
        else if (ct == 13) C_n[rr*DSTATE + ch] = ob;
        obuf[li & 7] = *(const __bf16*)&ob;
        if ((li & 7) == 7 && ct <= 12) {
            __hip_bfloat16* dst = (ct < 12) ? x_t : B_t;
            *(bf16x8*)(dst + trow*SEQ + base + l0 + (li - 7)) = obuf;
        }
    }
}

// ======== FUSED CB (blockIdx.x<64) + states (>=64) ========
__global__ __launch_bounds__(256)
void cbst_k(const __hip_bfloat16* __restrict__ B_n, const __hip_bfloat16* __restrict__ C_n,
            __hip_bfloat16* __restrict__ CB16,
            const __hip_bfloat16* __restrict__ x_t, const __hip_bfloat16* __restrict__ B_t,
            const float* __restrict__ dtb, const float* __restrict__ acum,
            __hip_bfloat16* __restrict__ states)
{
    int bid = blockIdx.x;
    int tid = threadIdx.x, lane = tid & 63, wave = tid >> 6;
    if (bid < 64) {
        int c = bid & 31, b = bid >> 5;
        size_t base = (size_t)b*SEQ + c*CHUNK;
        int r16 = lane & 15, kq = (lane>>4)*8;
        floatx4 acc[2][8] = {};
#pragma unroll
        for (int ks = 0; ks < 4; ++ks) {
            int k0 = ks*32 + kq;
            bf16x8 af[2], bfv[8];
#pragma unroll
            for (int mt = 0; mt < 2; ++mt)
                af[mt] = *(const bf16x8*)(C_n + (base + (wave*2+mt)*16 + r16)*DSTATE + k0);
#pragma unroll
            for (int st = 0; st < 8; ++st)
                bfv[st] = *(const bf16x8*)(B_n + (base + st*16 + r16)*DSTATE + k0);
#pragma unroll
            for (int mt = 0; mt < 2; ++mt)
#pragma unroll
                for (int st = 0; st < 8; ++st)
                    if (st <= wave*2+mt)
                        acc[mt][st] = __builtin_amdgcn_mfma_f32_16x16x32_bf16(
                            af[mt], bfv[st], acc[mt][st], 0,0,0);
        }
        size_t cbb = (size_t)(b*NCHUNK+c)*CHUNK*CHUNK;
        int scol = lane & 15, rowq = (lane>>4)*4;
#pragma unroll
        for (int mt = 0; mt < 2; ++mt)
#pragma unroll
            for (int st = 0; st < 8; ++st)
                if (st <= wave*2+mt)
#pragma unroll
                    for (int r = 0; r < 4; ++r)
                        CB16[cbb + (size_t)((wave*2+mt)*16 + rowq + r)*CHUNK + st*16 + scol] =
                            __float2bfloat16(acc[mt][st][r]);
        return;
    }
    // ---- states[p][n] = sum_l (x[l,p]*f[l]) * B[l,n], f = dt*dec ----
    __shared__ float f[128];
    int t = bid - 64;
    int c = t & 31;
    int h = (t>>5) % NHEADS;
    int b = t/(32*NHEADS);
    int arow = ((b*NHEADS+h)*NCHUNK + c)*CHUNK;
    size_t rbase = (size_t)b*SEQ + c*CHUNK;
    if (tid < 128) {
        float alast = acum[arow + 127];
        f[tid] = dtb[(rbase + tid)*NHEADS + h] * __expf(alast - acum[arow + tid]);
    }
    __syncthreads();
    int r16 = lane & 15, kq = (lane>>4)*8;
    size_t xtb = ((size_t)b*NHEADS + h)*HEADDIM;
    int cl = c*CHUNK;
    floatx4 acc[8] = {};
#pragma unroll
    for (int ks = 0; ks < 4; ++ks) {
        int k0 = ks*32 + kq;
        bf16x8 xa = *(const bf16x8*)(x_t + (xtb + wave*16 + r16)*SEQ + cl + k0);
        bf16x8 af;
#pragma unroll
        for (int j = 0; j < 8; ++j)
            af[j] = (__bf16)((float)xa[j] * f[k0 + j]);
        bf16x8 bfv[8];
#pragma unroll
        for (int nt = 0; nt < 8; ++nt)
            bfv[nt] = *(const bf16x8*)(B_t + ((size_t)b*DSTATE + nt*16 + r16)*SEQ + cl + k0);
#pragma unroll
        for (int nt = 0; nt < 8; ++nt)
            acc[nt] = __builtin_amdgcn_mfma_f32_16x16x32_bf16(af, bfv[nt], acc[nt], 0,0,0);
    }
    size_t sb = ((size_t)(b*NCHUNK+c)*NHEADS + h)*(HEADDIM*DSTATE);
    int ncol = lane & 15, rowq = (lane>>4)*4;
#pragma unroll
    for (int nt = 0; nt < 8; ++nt)
#pragma unroll
        for (int r = 0; r < 4; ++r)
            states[sb + (size_t)(wave*16 + rowq + r)*DSTATE + nt*16 + ncol] =
                __float2bfloat16(acc[nt][r]);
}

// ---- sequential inter-chunk recurrence, in place (bf16): states[c] := prev[c] ----
__global__ __launch_bounds__(64)
void recur_k(__hip_bfloat16* __restrict__ states, const float* __restrict__ acum)
{
    int pb = blockIdx.x & 15;
    int bh = blockIdx.x >> 4;
    int h = bh % NHEADS, b = bh / NHEADS;
    int voff = (pb*64 + threadIdx.x)*8;
    const size_t cstride = (size_t)NHEADS*HEADDIM*DSTATE;
    size_t base0 = ((size_t)(b*NCHUNK)*NHEADS + h)*(HEADDIM*DSTATE) + voff;
    bf16x8 st[NCHUNK];
    float ev[NCHUNK];
#pragma unroll
    for (int c = 0; c < NCHUNK; ++c)
        st[c] = *(const bf16x8*)(states + base0 + (size_t)c*cstride);
#pragma unroll
    for (int c = 0; c < NCHUNK; ++c)
        ev[c] = __expf(acum[((b*NHEADS+h)*NCHUNK + c)*CHUNK + 127]);
    float S[8] = {};
#pragma unroll
    for (int c = 0; c < NCHUNK; ++c) {
        bf16x8 pv;
#pragma unroll
        for (int j = 0; j < 8; ++j) {
            pv[j] = (__bf16)S[j];
            S[j] = S[j]*ev[c] + (float)st[c][j];
        }
        *(bf16x8*)(states + base0 + (size_t)c*cstride) = pv;
    }
}

// ======== Y = [tril(CB*exp(dAc)*dt)+D*I] @ x + (C*exp(ac)) @ prev^T; then
//          g = Y*silu(z) -> y16; rowsq += per-row sum(g^2) (atomic) ========
// Persistent 512 blocks x 3 units. Separate Tsm region (67.6 KB total, still
// 2 blocks/CU) enables T14 issue-early: next unit's XT/ST staging is issued
// right after this unit's last LDS read barrier, hiding HBM latency under the
// epilogue. Consume-side wait = next iteration's first __syncthreads (vmcnt
// drain).
__global__ __launch_bounds__(512, 4)
void y_mfma(const __hip_bfloat16* __restrict__ x_t, const __hip_bfloat16* __restrict__ z16,
            const __hip_bfloat16* __restrict__ C_n, const __hip_bfloat16* __restrict__ CB16,
            const __hip_bfloat16* __restrict__ states, const float* __restrict__ dtb,
            const float* __restrict__ acum, const float* __restrict__ Dp,
            __hip_bfloat16* __restrict__ y16, float* __restrict__ rowsq)
{
    __shared__ __align__(16) char smem[32768];
    __hip_bfloat16* XT = (__hip_bfloat16*)smem;   // [64 p][128 k] swizzled (16KB)
    __hip_bfloat16* ST = XT + 64*128;             // [64 p][128 n] swizzled (16KB)
    __shared__ __align__(16) float Tsm[128*LDEY]; // separate epilogue buffer
    __shared__ float ac[128], dts[128], gk[128];
    const int tid = threadIdx.x, lane = tid & 63, wave = tid >> 6;
    const int r16 = lane & 15, kq = (lane>>4)*8;
    const int l = wave*16 + r16;
    const int pcol = lane & 15, rowq = (lane>>4)*4;
    const int erow = tid >> 2, ec0 = (tid & 3)*16;   // epilogue mapping
    const int NU = B_SZ*NHEADS*NCHUNK;
    // prologue: stage first unit's XT/ST
    {
        int u = blockIdx.x;
        int c = u & 31, h = (u>>5) % NHEADS, b = u/(32*NHEADS);
        size_t xtb = ((size_t)b*NHEADS + h)*HEADDIM;
        size_t sb  = ((size_t)(b*NCHUNK+c)*NHEADS + h)*(HEADDIM*DSTATE);
        int cl = c*CHUNK;
#pragma unroll
        for (int j = 0; j < 2; ++j) {
            int cc = j*512 + tid;
            int p = cc >> 4, ch = cc & 15;
            int sj = ch ^ (p & 7);
            gload_lds16(x_t + (xtb + p)*SEQ + cl + sj*8, XT + cc*8);
            gload_lds16(states + sb + (size_t)p*DSTATE + sj*8, ST + cc*8);
        }
    }
#pragma unroll 1
    for (int u = blockIdx.x; u < NU; u += 512) {
        int c = u & 31;
        int h = (u>>5) % NHEADS;
        int b = u/(32*NHEADS);
        int arow = ((b*NHEADS+h)*NCHUNK + c)*CHUNK;
        size_t rbase = (size_t)b*SEQ + c*CHUNK;
        size_t cbb = (size_t)(b*NCHUNK+c)*CHUNK*CHUNK;
        if (tid < 128) {
            ac[tid]  = acum[arow + tid];
            dts[tid] = dtb[(rbase + tid)*NHEADS + h];
        }
        __syncthreads();   // drains staged XT/ST for this unit; ac/dts visible
        if (tid < 128)
            gk[tid] = __expf(ac[tid & 96] - ac[tid]) * dts[tid];
        // batch ALL global VGPR loads for this unit (one latency exposure)
        bf16x8 cb[4], cv[4];
#pragma unroll
        for (int ks = 0; ks < 4; ++ks) {
            cb[ks] = *(const bf16x8*)(CB16 + cbb + (size_t)l*CHUNK + ks*32 + kq);
            cv[ks] = *(const bf16x8*)(C_n + (rbase + l)*DSTATE + ks*32 + kq);
        }
        bf16x8 zA = *(const bf16x8*)(z16 + (rbase + erow)*DINNER + h*HEADDIM + ec0);
        bf16x8 zB = *(const bf16x8*)(z16 + (rbase + erow)*DINNER + h*HEADDIM + ec0 + 8);
        __syncthreads();   // gk visible
        float acl = ac[l];
        float Dh = Dp[h];
        floatx4 acc[4] = {};
        int nks = (wave >> 1) + 1;
#pragma unroll
        for (int ks = 0; ks < 4; ++ks) {
            if (ks < nks) {            // wave-uniform guard
                int k0 = ks*32 + kq;
                float fl = __expf(acl - ac[ks*32]);   // <= 1 (block base <= l)
                bf16x8 af;
#pragma unroll
                for (int j = 0; j < 8; ++j) {
                    int s = k0 + j;
                    float w = (s <= l) ? (float)cb[ks][j] * (fl * gk[s]) : 0.f;
                    if (s == l) w += Dh;           // D*x folded into the diagonal
                    af[j] = (__bf16)w;
                }
                int chL = k0 >> 3;
                bf16x8 bfv[4];
#pragma unroll
                for (int pt = 0; pt < 4; ++pt) {
                    int row = pt*16 + r16;
                    bfv[pt] = *(const bf16x8*)(XT + (row*16 + (chL ^ (row & 7)))*8);
                }
#pragma unroll
                for (int pt = 0; pt < 4; ++pt)
                    acc[pt] = __builtin_amdgcn_mfma_f32_16x16x32_bf16(af, bfv[pt], acc[pt], 0,0,0);
            }
        }
        float eal = __expf(acl);
#pragma unroll
        for (int ks = 0; ks < 4; ++ks) {
            int k0 = ks*32 + kq;
            bf16x8 af;
#pragma unroll
            for (int j = 0; j < 8; ++j)
                af[j] = (__bf16)((float)cv[ks][j] * eal);
            int chL = k0 >> 3;
            bf16x8 bfv[4];
#pragma unroll
            for (int pt = 0; pt < 4; ++pt) {
                int row = pt*16 + r16;
                bfv[pt] = *(const bf16x8*)(ST + (row*16 + (chL ^ (row & 7)))*8);
            }
#pragma unroll
            for (int pt = 0; pt < 4; ++pt)
                acc[pt] = __builtin_amdgcn_mfma_f32_16x16x32_bf16(af, bfv[pt], acc[pt], 0,0,0);
        }
        __syncthreads();   // all XT/ST reads for this unit complete
        // T14 issue-early: stage NEXT unit's XT/ST now; latency hides under
        // the epilogue. Consumed at next iteration's first __syncthreads.
        int un = u + 512;
        if (un < NU) {
            int c2 = un & 31, h2 = (un>>5) % NHEADS, b2 = un/(32*NHEADS);
            size_t xtb2 = ((size_t)b2*NHEADS + h2)*HEADDIM;
            size_t sb2  = ((size_t)(b2*NCHUNK+c2)*NHEADS + h2)*(HEADDIM*DSTATE);
            int cl2 = c2*CHUNK;
#pragma unroll
            for (int j = 0; j < 2; ++j) {
                int cc = j*512 + tid;
                int p = cc >> 4, ch = cc & 15;
                int sj = ch ^ (p & 7);
                gload_lds16(x_t + (xtb2 + p)*SEQ + cl2 + sj*8, XT + cc*8);
                gload_lds16(states + sb2 + (size_t)p*DSTATE + sj*8, ST + cc*8);
            }
        }
        // epilogue via separate Tsm: 8 waves write disjoint 16-row bands
#pragma unroll
        for (int pt = 0; pt < 4; ++pt)
#pragma unroll
            for (int r = 0; r < 4; ++r)
                Tsm[(wave*16 + rowq + r)*LDEY + pt*16 + pcol] = acc[pt][r];
        __syncthreads();
        {
            float s = 0.f; bf16x8 o1, o2;
#pragma unroll
            for (int j2 = 0; j2 < 8; ++j2) {
                float g = Tsm[erow*LDEY + ec0 + j2] * siluf_(__bfloat162float(zA[j2]));
                o1[j2] = cvt_bf(g); s += g*g;
            }
#pragma unroll
            for (int j2 = 0; j2 < 8; ++j2) {
                float g = Tsm[erow*LDEY + ec0 + 8 + j2] * siluf_(__bfloat162float(zB[j2]));
                o2[j2] = cvt_bf(g); s += g*g;
            }
            size_t grow = rbase + erow;
            *(bf16x8*)(y16 + grow*DINNER + h*HEADDIM + ec0)     = o1;
            *(bf16x8*)(y16 + grow*DINNER + h*HEADDIM + ec0 + 8) = o2;
            s += __shfl_xor(s, 1); s += __shfl_xor(s, 2);
            if ((tid & 3) == 0)
                atomicAdd(rowsq + grow, s);
        }
        // no trailing barrier: next iteration's first __syncthreads orders
        // Tsm reads (all waves must pass it) before the next Tsm write.
    }
}

extern "C" void kernel_launch(void* const* d_in, const int* in_sizes, int n_in,
                              void* d_out, int out_size, void* d_ws, size_t ws_size,
                              hipStream_t stream)
{
    const float* feature = (const float*)d_in[0];
    const float* gate1   = (const float*)d_in[1];
    const float* in_w    = (const float*)d_in[2];
    const float* conv_w  = (const float*)d_in[3];
    const float* conv_b  = (const float*)d_in[4];
    const float* dt_bias = (const float*)d_in[5];
    const float* A_log   = (const float*)d_in[6];
    const float* Dp      = (const float*)d_in[7];
    const float* norm_w  = (const float*)d_in[8];
    const float* out_w   = (const float*)d_in[9];
    float* out = (float*)d_out;

    // workspace layout — ~161 MB (< 256 MiB)
    char* p = (char*)d_ws;
    __hip_bfloat16* z16   = (__hip_bfloat16*)p; p += (size_t)ROWS*DINNER*2;  // 25.2 MB
    __hip_bfloat16* xbc16 = (__hip_bfloat16*)p; p += (size_t)ROWS*DXBC*2;    // 29.4 MB
    __hip_bfloat16* x_t   = (__hip_bfloat16*)p; p += (size_t)ROWS*DINNER*2;  // 25.2 MB
    __hip_bfloat16* B_n   = (__hip_bfloat16*)p; p += (size_t)ROWS*DSTATE*2;  // 2.1 MB
    __hip_bfloat16* B_t   = (__hip_bfloat16*)p; p += (size_t)ROWS*DSTATE*2;  // 2.1 MB
    __hip_bfloat16* C_n   = (__hip_bfloat16*)p; p += (size_t)ROWS*DSTATE*2;  // 2.1 MB
    float* dtb    = (float*)p;            p += (size_t)ROWS*NHEADS*4;        // 0.8 MB
    float* acum   = (float*)p;            p += (size_t)B_SZ*NHEADS*NCHUNK*CHUNK*4; // 0.8 MB
    float* rowsq  = (float*)p;            p += (size_t)ROWS*4;               // 32 KB
    __hip_bfloat16* CB16 = (__hip_bfloat16*)p; p += (size_t)B_SZ*NCHUNK*CHUNK*CHUNK*2; // 2.1 MB
    __hip_bfloat16* states = (__hip_bfloat16*)p; p += (size_t)B_SZ*NCHUNK*NHEADS*HEADDIM*DSTATE*2; // 25.2 MB
    __hip_bfloat16* y16  = (__hip_bfloat16*)p; p += (size_t)ROWS*DINNER*2;   // 25.2 MB
    __hip_bfloat16* fbf  = (__hip_bfloat16*)p; p += (size_t)ROWS*DMODEL*2;   // 12.6 MB
    __hip_bfloat16* wbf  = (__hip_bfloat16*)p; p += (size_t)NPAD1*DMODEL*2;  //  5.3 MB
    __hip_bfloat16* owbf = (__hip_bfloat16*)p; p += (size_t)DMODEL*DINNER*2; //  2.4 MB

    cast_all<<<(NV1+NV2+NV3+NVR+255)/256, 256, 0, stream>>>(feature, in_w, out_w, norm_w,
                                                            fbf, wbf, owbf, rowsq);

    gemm1_mfma<<<27*32, 512, 0, stream>>>(fbf, wbf, z16, xbc16, dtb, dt_bias);
    conv_scan_k<<<dim3(14 + NHEADS, 32, B_SZ), 512, 0, stream>>>(
        xbc16, conv_w, conv_b, x_t, B_n, B_t, C_n, dtb, A_log, acum);
    cbst_k<<<64 + B_SZ*NHEADS*NCHUNK, 256, 0, stream>>>(
        B_n, C_n, CB16, x_t, B_t, dtb, acum, states);
    recur_k<<<B_SZ*NHEADS*16, 64, 0, stream>>>(states, acum);
    y_mfma<<<512, 512, 0, stream>>>(x_t, z16, C_n, CB16, states,
                                    dtb, acum, Dp, y16, rowsq);
    gemm2_mfma<<<6*64, 256, 0, stream>>>(y16, owbf, out, gate1, feature, rowsq);
}

// Round 11
// 264.064 us; speedup vs baseline: 1.2791x; 1.0506x over previous
//
#include <hip/hip_runtime.h>
#include <hip/hip_bf16.h>
#include <math.h>

#define B_SZ 2
#define SEQ 4096
#define DMODEL 768
#define DSTATE 128
#define HEADDIM 64
#define DINNER 1536
#define NHEADS 24
#define DXBC 1792
#define DPROJ 3352
#define NPAD1 3456
#define CHUNK 128
#define NCHUNK 32
#define ROWS (B_SZ*SEQ)
#define LDTC 136   // padded LDS stride for conv input tile
#define LDTT 132   // padded LDS stride for conv output-transpose tile
#define LDE 136    // padded LDS stride (bf16) for epilogue tiles
#define LDE2 132   // padded LDS stride (fp32) for gemm2 epilogue tile
#define LDEY 65    // padded LDS stride (fp32) for y_mfma epilogue (65 ≡ 1 mod 32)

typedef float floatx4 __attribute__((ext_vector_type(4)));
typedef __bf16 bf16x8 __attribute__((ext_vector_type(8)));

// fast-exp variants: all consumers are bf16 casts / bf16 MFMA operands, so
// __expf's 2-4 ulp f32 error is far below bf16 rounding.
__device__ __forceinline__ float sigmoidf_(float x){ return 1.f/(1.f+__expf(-x)); }
__device__ __forceinline__ float siluf_(float x){ return x/(1.f+__expf(-x)); }
__device__ __forceinline__ float softplusf_(float x){ return (x>20.f)? x : __logf(1.f+__expf(x)); }
__device__ __forceinline__ __bf16 cvt_bf(float x){ __hip_bfloat16 t = __float2bfloat16(x); return *(__bf16*)&t; }

__device__ __forceinline__ void gload_lds16(const __hip_bfloat16* g, __hip_bfloat16* l){
    __builtin_amdgcn_global_load_lds(
        (const __attribute__((address_space(1))) void*)g,
        (__attribute__((address_space(3))) void*)l, 16, 0, 0);
}

// ======== GEMM1: 256x128 tile, 8 waves; epilogue -> z16 / xbc16 / dtb ========
// R0-exact structure: BK=64, serial stage, 48 KiB LDS, 3 blocks/CU co-residency.
// Measured at 845 TF = 93% of the m97-structure ceiling (~900). DONE.
__global__ __launch_bounds__(512)
void gemm1_mfma(const __hip_bfloat16* __restrict__ A,   // fbf [ROWS][768]
                const __hip_bfloat16* __restrict__ W,   // wbf [3456][768]
                __hip_bfloat16* __restrict__ z16, __hip_bfloat16* __restrict__ xbc16,
                float* __restrict__ dtb, const float* __restrict__ dt_bias)
{
    __shared__ __align__(16) char smem[49152];          // Asm 32K + Wsm 16K
    __hip_bfloat16* Asm = (__hip_bfloat16*)smem;        // [256][64]
    __hip_bfloat16* Wsm = Asm + 256*64;                 // [128][64]
    const int tid = threadIdx.x;
    const int lane = tid & 63, wave = tid >> 6;
    const int blk = blockIdx.x;
    const int m_tile = ((blk & 7) << 2) | ((blk >> 3) & 3);   // 32 M-tiles, XCD band
    const int bx = blk >> 5;                                   // N-tile 0..26
    const int bm = m_tile*256, bn = bx*128;
    const int wm = (wave & 3)*64, wn = (wave >> 2)*64;
    const int r16 = lane & 15, qbase = lane >> 4, sw = r16 & 7;
    floatx4 acc[4][4] = {};
    for (int k0 = 0; k0 < DMODEL; k0 += 64) {
#pragma unroll
        for (int j = 0; j < 4; ++j) {
            int cc = j*512 + tid;                // A: 2048 chunks
            int row = cc >> 3, jc = cc & 7;
            int sj = jc ^ (row & 7);
            gload_lds16(A + (size_t)(bm+row)*DMODEL + k0 + sj*8, Asm + cc*8);
        }
#pragma unroll
        for (int j = 0; j < 2; ++j) {
            int cc = j*512 + tid;                // W: 1024 chunks
            int row = cc >> 3, jc = cc & 7;
            int sj = jc ^ (row & 7);
            gload_lds16(W + (size_t)(bn+row)*DMODEL + k0 + sj*8, Wsm + cc*8);
        }
        __syncthreads();
#pragma unroll
        for (int ks = 0; ks < 2; ++ks) {
            const int kq = ((qbase + ks*4) ^ sw)*8;
            bf16x8 af[4], wf[4];
#pragma unroll
            for (int i = 0; i < 4; ++i) {
                af[i] = *(const bf16x8*)(Asm + (wm + i*16 + r16)*64 + kq);
                wf[i] = *(const bf16x8*)(Wsm + (wn + i*16 + r16)*64 + kq);
            }
#pragma unroll
            for (int mi = 0; mi < 4; ++mi)
#pragma unroll
                for (int ni = 0; ni < 4; ++ni)
                    acc[mi][ni] = __builtin_amdgcn_mfma_f32_16x16x32_bf16(
                        af[mi], wf[ni], acc[mi][ni], 0, 0, 0);
        }
        __syncthreads();
    }
    const int col = lane & 15, rowq = (lane >> 4)*4;
    if (bx == 26) {
        if (wn == 0) {
#pragma unroll
            for (int mi = 0; mi < 4; ++mi)
#pragma unroll
                for (int ni = 0; ni < 2; ++ni) {
                    int h = ni*16 + col;
                    if (h < NHEADS)
#pragma unroll
                        for (int r = 0; r < 4; ++r) {
                            int m = bm + wm + mi*16 + rowq + r;
                            dtb[(size_t)m*NHEADS + h] =
                                softplusf_(acc[mi][ni][r] + dt_bias[h]);
                        }
                }
        }
        return;
    }
    __hip_bfloat16* Tsm = (__hip_bfloat16*)smem;   // [128][LDE]
    __hip_bfloat16* dst; int ldd;
    if (bx < 12) { dst = z16 + bn;            ldd = DINNER; }
    else         { dst = xbc16 + bn - DINNER; ldd = DXBC;  }
    for (int half = 0; half < 2; ++half) {
        if (((wave & 3) >> 1) == half) {
#pragma unroll
            for (int mi = 0; mi < 4; ++mi)
#pragma unroll
                for (int ni = 0; ni < 4; ++ni)
#pragma unroll
                    for (int r = 0; r < 4; ++r)
                        Tsm[(wm - half*128 + mi*16 + rowq + r)*LDE + wn + ni*16 + col] =
                            __float2bfloat16(acc[mi][ni][r]);
        }
        __syncthreads();
#pragma unroll
        for (int it = 0; it < 4; ++it) {
            int e = it*512 + tid;
            int row = e >> 4, c0 = (e & 15)*8;
            bf16x8 v = *(const bf16x8*)(Tsm + row*LDE + c0);
            *(bf16x8*)(dst + (size_t)(bm + half*128 + row)*ldd + c0) = v;
        }
        __syncthreads();
    }
}

// ======== GEMM2: 128x128 tile, 4 waves (2x2), 384 blocks (R9, proven) ========
__global__ __launch_bounds__(256)
void gemm2_mfma(const __hip_bfloat16* __restrict__ A,   // y16 [ROWS][1536] (gated)
                const __hip_bfloat16* __restrict__ W,   // owbf [768][1536]
                float* __restrict__ C,
                const float* __restrict__ gate, const float* __restrict__ resid,
                const float* __restrict__ rowsq)
{
    __shared__ __align__(16) char smem[33792];          // staging 32K; epi 64*LDE2*4
    __shared__ float scale_lds[128];
    __hip_bfloat16* Asm = (__hip_bfloat16*)smem;        // [128][64]
    __hip_bfloat16* Wsm = Asm + 128*64;                 // [128][64]
    const int tid = threadIdx.x;
    const int lane = tid & 63, wave = tid >> 6;         // 4 waves
    const int blk = blockIdx.x;
    const int mblk = blk & 63;
    const int m_tile = ((mblk & 7) << 3) | (mblk >> 3); // 64 M-tiles, XCD band
    const int bm = m_tile*128, bn = (blk >> 6)*128;     // n-tile 0..5
    const int wm = (wave & 1)*64, wn = (wave >> 1)*64;
    const int r16 = lane & 15, qbase = lane >> 4, sw = r16 & 7;
    floatx4 acc[4][4] = {};
    for (int k0 = 0; k0 < DINNER; k0 += 64) {
#pragma unroll
        for (int j = 0; j < 4; ++j) {
            int cc = j*256 + tid;                // A: 1024 chunks (128 rows x 8)
            int row = cc >> 3, jc = cc & 7;
            int sj = jc ^ (row & 7);
            gload_lds16(A + (size_t)(bm+row)*DINNER + k0 + sj*8, Asm + cc*8);
        }
#pragma unroll
        for (int j = 0; j < 4; ++j) {
            int cc = j*256 + tid;                // W: 1024 chunks
            int row = cc >> 3, jc = cc & 7;
            int sj = jc ^ (row & 7);
            gload_lds16(W + (size_t)(bn+row)*DINNER + k0 + sj*8, Wsm + cc*8);
        }
        __syncthreads();
#pragma unroll
        for (int ks = 0; ks < 2; ++ks) {
            const int kq = ((qbase + ks*4) ^ sw)*8;
            bf16x8 af[4], wf[4];
#pragma unroll
            for (int i = 0; i < 4; ++i) {
                af[i] = *(const bf16x8*)(Asm + (wm + i*16 + r16)*64 + kq);
                wf[i] = *(const bf16x8*)(Wsm + (wn + i*16 + r16)*64 + kq);
            }
#pragma unroll
            for (int mi = 0; mi < 4; ++mi)
#pragma unroll
                for (int ni = 0; ni < 4; ++ni)
                    acc[mi][ni] = __builtin_amdgcn_mfma_f32_16x16x32_bf16(
                        af[mi], wf[ni], acc[mi][ni], 0, 0, 0);
        }
        __syncthreads();
    }
    if (tid < 128)
        scale_lds[tid] = rsqrtf(rowsq[bm + tid] * (1.f/DINNER) + 1e-5f);
    float gs = sigmoidf_(gate[0]);
    __syncthreads();
    const int col = lane & 15, rowq = (lane >> 4)*4;
    float* Tsm = (float*)smem;   // 64 x LDE2 fp32
    for (int half = 0; half < 2; ++half) {
        if ((wave & 1) == half) {     // two waves per half, disjoint wn columns
#pragma unroll
            for (int mi = 0; mi < 4; ++mi)
#pragma unroll
                for (int ni = 0; ni < 4; ++ni)
#pragma unroll
                    for (int r = 0; r < 4; ++r)
                        Tsm[(mi*16 + rowq + r)*LDE2 + wn + ni*16 + col] = acc[mi][ni][r];
        }
        __syncthreads();
#pragma unroll
        for (int it = 0; it < 8; ++it) {
            int e = it*256 + tid;
            int row = e >> 5, c0 = (e & 31)*4;
            float4 v = *(const float4*)(Tsm + row*LDE2 + c0);
            float sc = gs * scale_lds[half*64 + row];
            size_t off = (size_t)(bm + half*64 + row)*DMODEL + bn + c0;
            float4 rv = *(const float4*)(resid + off);
            v.x = sc*v.x + rv.x; v.y = sc*v.y + rv.y;
            v.z = sc*v.z + rv.z; v.w = sc*v.w + rv.w;
            *(float4*)(C + off) = v;
        }
        __syncthreads();
    }
}

// -------- fused fp32 -> bf16 casts (8 elem/thread) + rowsq zeroing tail --------
#define NC1 (ROWS*DMODEL)
#define NC2 (NPAD1*DMODEL)
#define NC3 (DMODEL*DINNER)
#define NV1 (NC1/8)
#define NV2 (NC2/8)
#define NV3 (NC3/8)
#define NVR (ROWS/8)
__global__ __launch_bounds__(256)
void cast_all(const float* __restrict__ feature, const float* __restrict__ in_w,
              const float* __restrict__ out_w, const float* __restrict__ nw,
              __hip_bfloat16* __restrict__ fbf, __hip_bfloat16* __restrict__ wbf,
              __hip_bfloat16* __restrict__ owbf, float* __restrict__ rowsq)
{
    int v = blockIdx.x*256 + threadIdx.x;
    if (v < NV1) {
        int i = v*8;
        float4 a = *(const float4*)(feature + i);
        float4 b = *(const float4*)(feature + i + 4);
        bf16x8 o;
        o[0]=cvt_bf(a.x); o[1]=cvt_bf(a.y); o[2]=cvt_bf(a.z); o[3]=cvt_bf(a.w);
        o[4]=cvt_bf(b.x); o[5]=cvt_bf(b.y); o[6]=cvt_bf(b.z); o[7]=cvt_bf(b.w);
        *(bf16x8*)(fbf + i) = o;
    } else if (v < NV1 + NV2) {
        int j = (v - NV1)*8;
        int n = j / DMODEL, k = j - n*DMODEL;
        bf16x8 o;
        if (n < DPROJ) {
            const float* s = in_w + (size_t)n*DMODEL + k;
            float4 a = *(const float4*)(s);
            float4 b = *(const float4*)(s + 4);
            o[0]=cvt_bf(a.x); o[1]=cvt_bf(a.y); o[2]=cvt_bf(a.z); o[3]=cvt_bf(a.w);
            o[4]=cvt_bf(b.x); o[5]=cvt_bf(b.y); o[6]=cvt_bf(b.z); o[7]=cvt_bf(b.w);
        } else {
#pragma unroll
            for (int q = 0; q < 8; ++q) o[q] = (__bf16)0.f;
        }
        *(bf16x8*)(wbf + j) = o;
    } else if (v < NV1 + NV2 + NV3) {
        int j = (v - NV1 - NV2)*8;
        int k = j % DINNER;
        float4 a  = *(const float4*)(out_w + j);
        float4 b  = *(const float4*)(out_w + j + 4);
        float4 na = *(const float4*)(nw + k);
        float4 nb = *(const float4*)(nw + k + 4);
        bf16x8 o;
        o[0]=cvt_bf(a.x*na.x); o[1]=cvt_bf(a.y*na.y); o[2]=cvt_bf(a.z*na.z); o[3]=cvt_bf(a.w*na.w);
        o[4]=cvt_bf(b.x*nb.x); o[5]=cvt_bf(b.y*nb.y); o[6]=cvt_bf(b.z*nb.z); o[7]=cvt_bf(b.w*nb.w);
        *(bf16x8*)(owbf + j) = o;
    } else if (v < NV1 + NV2 + NV3 + NVR) {
        int j = (v - NV1 - NV2 - NV3)*8;
        float4 z = {0.f, 0.f, 0.f, 0.f};
        *(float4*)(rowsq + j) = z;
        *(float4*)(rowsq + j + 4) = z;
    }
}

// ======== FUSED conv4+SiLU (blockIdx.x<14) + cumsum scan (>=14), 512 thr ========
// Conv transposed outputs (x_t / B_t) now go through an LDS tile T[128ch][132l]
// and are flushed with lanes along l: 16 consecutive lanes write 256B contiguous
// (was: 64 scattered 16B stores per wave, 8KB apart — fully uncoalesced).
__global__ __launch_bounds__(512)
void conv_scan_k(const __hip_bfloat16* __restrict__ xbc16, const float* __restrict__ cw,
                 const float* __restrict__ cbias,
                 __hip_bfloat16* __restrict__ x_t,
                 __hip_bfloat16* __restrict__ B_n, __hip_bfloat16* __restrict__ B_t,
                 __hip_bfloat16* __restrict__ C_n,
                 const float* __restrict__ dtb, const float* __restrict__ A_log,
                 float* __restrict__ acum)
{
    int xb = blockIdx.x;
    int tid = threadIdx.x;
    if (xb >= 14) {
        // ---- scan path: h = xb-14, c = blockIdx.y, b = blockIdx.z ----
        __shared__ float wtot;
        int h = xb - 14, c = blockIdx.y, b = blockIdx.z;
        int lane = tid & 63;
        float s = 0.f;
        if (tid < 128) {
            float Aa = -__expf(A_log[h]);
            s = dtb[((size_t)b*SEQ + c*CHUNK + tid)*NHEADS + h] * Aa;
#pragma unroll
            for (int off = 1; off < 64; off <<= 1) {
                float t = __shfl_up(s, off);
                if (lane >= off) s += t;
            }
            if (tid == 63) wtot = s;
        }
        __syncthreads();
        if (tid >= 64 && tid < 128) s += wtot;
        if (tid < 128)
            acum[((b*NHEADS+h)*NCHUNK + c)*CHUNK + tid] = s;
        return;
    }
    // ---- conv path ----
    __shared__ __align__(16) __hip_bfloat16 in[131*LDTC];
    __shared__ __align__(16) __hip_bfloat16 T[128*LDTT];   // [ch][l] output tile
    int ct = xb, lt = blockIdx.y, b = blockIdx.z;
    int base = lt*128;
    for (int it = 0; it < 2096; it += 512) {
        int e = it + tid; if (e >= 2096) break;
        int row = e >> 4, c0 = (e & 15)*8;
        int l = base - 3 + row;
        bf16x8 v;
        if (l < 0) { for (int j = 0; j < 8; ++j) v[j] = (__bf16)0.f; }
        else v = *(const bf16x8*)(xbc16 + ((size_t)b*SEQ + l)*DXBC + ct*128 + c0);
        *(bf16x8*)(in + row*LDTC + c0) = v;
    }
    __syncthreads();
    int ch = tid & 127, lh = tid >> 7, l0 = lh*32;   // 4 l-groups of 32
    int g = ct*128 + ch;
    float w0 = cw[g*4+0], w1 = cw[g*4+1], w2 = cw[g*4+2], w3 = cw[g*4+3];
    float bias = cbias[g];
    float a0 = __bfloat162float(in[(l0+0)*LDTC + ch]);
    float a1 = __bfloat162float(in[(l0+1)*LDTC + ch]);
    float a2 = __bfloat162float(in[(l0+2)*LDTC + ch]);
#pragma unroll
    for (int li = 0; li < 32; ++li) {
        float a3 = __bfloat162float(in[(l0+li+3)*LDTC + ch]);
        float o = siluf_(bias + w0*a0 + w1*a1 + w2*a2 + w3*a3);
        a0 = a1; a1 = a2; a2 = a3;
        __hip_bfloat16 ob = __float2bfloat16(o);
        size_t rr = (size_t)b*SEQ + base + l0 + li;
        if (ct == 12)      B_n[rr*DSTATE + ch] = ob;    // coalesced across ch
        else if (ct == 13) C_n[rr*DSTATE + ch] = ob;
        if (ct <= 12)
            T[ch*LDTT + l0 + li] = ob;   // 2-way bank pattern (stride 66 words) = free
    }
    if (ct <= 12) {
        __syncthreads();
        __hip_bfloat16* dst = (ct < 12) ? x_t : B_t;
#pragma unroll
        for (int it = 0; it < 4; ++it) {
            int e = it*512 + tid;              // 2048 chunks = 128 rows x 16
            int chn = e >> 4, c0 = (e & 15)*8;
            int g2 = ct*128 + chn;
            size_t trow = (ct < 12)
                ? ((size_t)b*NHEADS + (g2>>6))*HEADDIM + (g2 & 63)
                : (size_t)b*DSTATE + chn;
            bf16x8 v = *(const bf16x8*)(T + chn*LDTT + c0);
            *(bf16x8*)(dst + trow*SEQ + base + c0) = v;   // 256B contiguous / 16 lanes
        }
    }
}

// ======== FUSED CB (blockIdx.x<64) + states (>=64) ========
// states path: B_t panel (128x128, 32KB) staged ONCE into LDS with the proven
// chunk-XOR swizzle — was read 4x redundantly from global by the 4 waves
// (196 MB of L2 traffic across the grid -> 49 MB).
__global__ __launch_bounds__(256)
void cbst_k(const __hip_bfloat16* __restrict__ B_n, const __hip_bfloat16* __restrict__ C_n,
            __hip_bfloat16* __restrict__ CB16,
            const __hip_bfloat16* __restrict__ x_t, const __hip_bfloat16* __restrict__ B_t,
            const float* __restrict__ dtb, const float* __restrict__ acum,
            __hip_bfloat16* __restrict__ states)
{
    __shared__ __align__(16) __hip_bfloat16 BT[128*128];   // 32 KB, swizzled
    __shared__ float f[128];
    int bid = blockIdx.x;
    int tid = threadIdx.x, lane = tid & 63, wave = tid >> 6;
    if (bid < 64) {
        int c = bid & 31, b = bid >> 5;
        size_t base = (size_t)b*SEQ + c*CHUNK;
        int r16 = lane & 15, kq = (lane>>4)*8;
        floatx4 acc[2][8] = {};
#pragma unroll
        for (int ks = 0; ks < 4; ++ks) {
            int k0 = ks*32 + kq;
            bf16x8 af[2], bfv[8];
#pragma unroll
            for (int mt = 0; mt < 2; ++mt)
                af[mt] = *(const bf16x8*)(C_n + (base + (wave*2+mt)*16 + r16)*DSTATE + k0);
#pragma unroll
            for (int st = 0; st < 8; ++st)
                bfv[st] = *(const bf16x8*)(B_n + (base + st*16 + r16)*DSTATE + k0);
#pragma unroll
            for (int mt = 0; mt < 2; ++mt)
#pragma unroll
                for (int st = 0; st < 8; ++st)
                    if (st <= wave*2+mt)
                        acc[mt][st] = __builtin_amdgcn_mfma_f32_16x16x32_bf16(
                            af[mt], bfv[st], acc[mt][st], 0,0,0);
        }
        size_t cbb = (size_t)(b*NCHUNK+c)*CHUNK*CHUNK;
        int scol = lane & 15, rowq = (lane>>4)*4;
#pragma unroll
        for (int mt = 0; mt < 2; ++mt)
#pragma unroll
            for (int st = 0; st < 8; ++st)
                if (st <= wave*2+mt)
#pragma unroll
                    for (int r = 0; r < 4; ++r)
                        CB16[cbb + (size_t)((wave*2+mt)*16 + rowq + r)*CHUNK + st*16 + scol] =
                            __float2bfloat16(acc[mt][st][r]);
        return;
    }
    // ---- states[p][n] = sum_l (x[l,p]*f[l]) * B[l,n], f = dt*dec ----
    int t = bid - 64;
    int c = t & 31;
    int h = (t>>5) % NHEADS;
    int b = t/(32*NHEADS);
    int arow = ((b*NHEADS+h)*NCHUNK + c)*CHUNK;
    size_t rbase = (size_t)b*SEQ + c*CHUNK;
    int cl = c*CHUNK;
    // stage B_t panel: 2048 chunks of 16B, 8 per thread, chunk-XOR swizzle
#pragma unroll
    for (int j = 0; j < 8; ++j) {
        int cc = j*256 + tid;
        int n = cc >> 4, chk = cc & 15;
        int sj = chk ^ (n & 7);
        gload_lds16(B_t + ((size_t)b*DSTATE + n)*SEQ + cl + sj*8, BT + cc*8);
    }
    if (tid < 128) {
        float alast = acum[arow + 127];
        f[tid] = dtb[(rbase + tid)*NHEADS + h] * __expf(alast - acum[arow + tid]);
    }
    __syncthreads();   // drains gload_lds; f visible
    int r16 = lane & 15, kq = (lane>>4)*8;
    size_t xtb = ((size_t)b*NHEADS + h)*HEADDIM;
    floatx4 acc[8] = {};
#pragma unroll
    for (int ks = 0; ks < 4; ++ks) {
        int k0 = ks*32 + kq;
        bf16x8 xa = *(const bf16x8*)(x_t + (xtb + wave*16 + r16)*SEQ + cl + k0);
        bf16x8 af;
#pragma unroll
        for (int j = 0; j < 8; ++j)
            af[j] = (__bf16)((float)xa[j] * f[k0 + j]);
        int chL = k0 >> 3;
        bf16x8 bfv[8];
#pragma unroll
        for (int nt = 0; nt < 8; ++nt) {
            int row = nt*16 + r16;
            bfv[nt] = *(const bf16x8*)(BT + (row*16 + (chL ^ (row & 7)))*8);
        }
#pragma unroll
        for (int nt = 0; nt < 8; ++nt)
            acc[nt] = __builtin_amdgcn_mfma_f32_16x16x32_bf16(af, bfv[nt], acc[nt], 0,0,0);
    }
    size_t sb = ((size_t)(b*NCHUNK+c)*NHEADS + h)*(HEADDIM*DSTATE);
    int ncol = lane & 15, rowq = (lane>>4)*4;
#pragma unroll
    for (int nt = 0; nt < 8; ++nt)
#pragma unroll
        for (int r = 0; r < 4; ++r)
            states[sb + (size_t)(wave*16 + rowq + r)*DSTATE + nt*16 + ncol] =
                __float2bfloat16(acc[nt][r]);
}

// ---- sequential inter-chunk recurrence, in place (bf16): states[c] := prev[c] ----
__global__ __launch_bounds__(64)
void recur_k(__hip_bfloat16* __restrict__ states, const float* __restrict__ acum)
{
    int pb = blockIdx.x & 15;
    int bh = blockIdx.x >> 4;
    int h = bh % NHEADS, b = bh / NHEADS;
    int voff = (pb*64 + threadIdx.x)*8;
    const size_t cstride = (size_t)NHEADS*HEADDIM*DSTATE;
    size_t base0 = ((size_t)(b*NCHUNK)*NHEADS + h)*(HEADDIM*DSTATE) + voff;
    bf16x8 st[NCHUNK];
    float ev[NCHUNK];
#pragma unroll
    for (int c = 0; c < NCHUNK; ++c)
        st[c] = *(const bf16x8*)(states + base0 + (size_t)c*cstride);
#pragma unroll
    for (int c = 0; c < NCHUNK; ++c)
        ev[c] = __expf(acum[((b*NHEADS+h)*NCHUNK + c)*CHUNK + 127]);
    float S[8] = {};
#pragma unroll
    for (int c = 0; c < NCHUNK; ++c) {
        bf16x8 pv;
#pragma unroll
        for (int j = 0; j < 8; ++j) {
            pv[j] = (__bf16)S[j];
            S[j] = S[j]*ev[c] + (float)st[c][j];
        }
        *(bf16x8*)(states + base0 + (size_t)c*cstride) = pv;
    }
}

// ======== Y = [tril(CB*exp(dAc)*dt)+D*I] @ x + (C*exp(ac)) @ prev^T; then
//          g = Y*silu(z) -> y16; rowsq += per-row sum(g^2) (atomic) ========
// Persistent 512 blocks x 3 units; T14 issue-early staging (R10, proven).
__global__ __launch_bounds__(512, 4)
void y_mfma(const __hip_bfloat16* __restrict__ x_t, const __hip_bfloat16* __restrict__ z16,
            const __hip_bfloat16* __restrict__ C_n, const __hip_bfloat16* __restrict__ CB16,
            const __hip_bfloat16* __restrict__ states, const float* __restrict__ dtb,
            const float* __restrict__ acum, const float* __restrict__ Dp,
            __hip_bfloat16* __restrict__ y16, float* __restrict__ rowsq)
{
    __shared__ __align__(16) char smem[32768];
    __hip_bfloat16* XT = (__hip_bfloat16*)smem;   // [64 p][128 k] swizzled (16KB)
    __hip_bfloat16* ST = XT + 64*128;             // [64 p][128 n] swizzled (16KB)
    __shared__ __align__(16) float Tsm[128*LDEY]; // separate epilogue buffer
    __shared__ float ac[128], dts[128], gk[128];
    const int tid = threadIdx.x, lane = tid & 63, wave = tid >> 6;
    const int r16 = lane & 15, kq = (lane>>4)*8;
    const int l = wave*16 + r16;
    const int pcol = lane & 15, rowq = (lane>>4)*4;
    const int erow = tid >> 2, ec0 = (tid & 3)*16;   // epilogue mapping
    const int NU = B_SZ*NHEADS*NCHUNK;
    // prologue: stage first unit's XT/ST
    {
        int u = blockIdx.x;
        int c = u & 31, h = (u>>5) % NHEADS, b = u/(32*NHEADS);
        size_t xtb = ((size_t)b*NHEADS + h)*HEADDIM;
        size_t sb  = ((size_t)(b*NCHUNK+c)*NHEADS + h)*(HEADDIM*DSTATE);
        int cl = c*CHUNK;
#pragma unroll
        for (int j = 0; j < 2; ++j) {
            int cc = j*512 + tid;
            int p = cc >> 4, ch = cc & 15;
            int sj = ch ^ (p & 7);
            gload_lds16(x_t + (xtb + p)*SEQ + cl + sj*8, XT + cc*8);
            gload_lds16(states + sb + (size_t)p*DSTATE + sj*8, ST + cc*8);
        }
    }
#pragma unroll 1
    for (int u = blockIdx.x; u < NU; u += 512) {
        int c = u & 31;
        int h = (u>>5) % NHEADS;
        int b = u/(32*NHEADS);
        int arow = ((b*NHEADS+h)*NCHUNK + c)*CHUNK;
        size_t rbase = (size_t)b*SEQ + c*CHUNK;
        size_t cbb = (size_t)(b*NCHUNK+c)*CHUNK*CHUNK;
        if (tid < 128) {
            ac[tid]  = acum[arow + tid];
            dts[tid] = dtb[(rbase + tid)*NHEADS + h];
        }
        __syncthreads();   // drains staged XT/ST for this unit; ac/dts visible
        if (tid < 128)
            gk[tid] = __expf(ac[tid & 96] - ac[tid]) * dts[tid];
        // batch ALL global VGPR loads for this unit (one latency exposure)
        bf16x8 cb[4], cv[4];
#pragma unroll
        for (int ks = 0; ks < 4; ++ks) {
            cb[ks] = *(const bf16x8*)(CB16 + cbb + (size_t)l*CHUNK + ks*32 + kq);
            cv[ks] = *(const bf16x8*)(C_n + (rbase + l)*DSTATE + ks*32 + kq);
        }
        bf16x8 zA = *(const bf16x8*)(z16 + (rbase + erow)*DINNER + h*HEADDIM + ec0);
        bf16x8 zB = *(const bf16x8*)(z16 + (rbase + erow)*DINNER + h*HEADDIM + ec0 + 8);
        __syncthreads();   // gk visible
        float acl = ac[l];
        float Dh = Dp[h];
        floatx4 acc[4] = {};
        int nks = (wave >> 1) + 1;
#pragma unroll
        for (int ks = 0; ks < 4; ++ks) {
            if (ks < nks) {            // wave-uniform guard
                int k0 = ks*32 + kq;
                float fl = __expf(acl - ac[ks*32]);   // <= 1 (block base <= l)
                bf16x8 af;
#pragma unroll
                for (int j = 0; j < 8; ++j) {
                    int s = k0 + j;
                    float w = (s <= l) ? (float)cb[ks][j] * (fl * gk[s]) : 0.f;
                    if (s == l) w += Dh;           // D*x folded into the diagonal
                    af[j] = (__bf16)w;
                }
                int chL = k0 >> 3;
                bf16x8 bfv[4];
#pragma unroll
                for (int pt = 0; pt < 4; ++pt) {
                    int row = pt*16 + r16;
                    bfv[pt] = *(const bf16x8*)(XT + (row*16 + (chL ^ (row & 7)))*8);
                }
#pragma unroll
                for (int pt = 0; pt < 4; ++pt)
                    acc[pt] = __builtin_amdgcn_mfma_f32_16x16x32_bf16(af, bfv[pt], acc[pt], 0,0,0);
            }
        }
        float eal = __expf(acl);
#pragma unroll
        for (int ks = 0; ks < 4; ++ks) {
            int k0 = ks*32 + kq;
            bf16x8 af;
#pragma unroll
            for (int j = 0; j < 8; ++j)
                af[j] = (__bf16)((float)cv[ks][j] * eal);
            int chL = k0 >> 3;
            bf16x8 bfv[4];
#pragma unroll
            for (int pt = 0; pt < 4; ++pt) {
                int row = pt*16 + r16;
                bfv[pt] = *(const bf16x8*)(ST + (row*16 + (chL ^ (row & 7)))*8);
            }
#pragma unroll
            for (int pt = 0; pt < 4; ++pt)
                acc[pt] = __builtin_amdgcn_mfma_f32_16x16x32_bf16(af, bfv[pt], acc[pt], 0,0,0);
        }
        __syncthreads();   // all XT/ST reads for this unit complete
        // T14 issue-early: stage NEXT unit's XT/ST now; latency hides under
        // the epilogue. Consumed at next iteration's first __syncthreads.
        int un = u + 512;
        if (un < NU) {
            int c2 = un & 31, h2 = (un>>5) % NHEADS, b2 = un/(32*NHEADS);
            size_t xtb2 = ((size_t)b2*NHEADS + h2)*HEADDIM;
            size_t sb2  = ((size_t)(b2*NCHUNK+c2)*NHEADS + h2)*(HEADDIM*DSTATE);
            int cl2 = c2*CHUNK;
#pragma unroll
            for (int j = 0; j < 2; ++j) {
                int cc = j*512 + tid;
                int p = cc >> 4, ch = cc & 15;
                int sj = ch ^ (p & 7);
                gload_lds16(x_t + (xtb2 + p)*SEQ + cl2 + sj*8, XT + cc*8);
                gload_lds16(states + sb2 + (size_t)p*DSTATE + sj*8, ST + cc*8);
            }
        }
        // epilogue via separate Tsm: 8 waves write disjoint 16-row bands
#pragma unroll
        for (int pt = 0; pt < 4; ++pt)
#pragma unroll
            for (int r = 0; r < 4; ++r)
                Tsm[(wave*16 + rowq + r)*LDEY + pt*16 + pcol] = acc[pt][r];
        __syncthreads();
        {
            float s = 0.f; bf16x8 o1, o2;
#pragma unroll
            for (int j2 = 0; j2 < 8; ++j2) {
                float g = Tsm[erow*LDEY + ec0 + j2] * siluf_(__bfloat162float(zA[j2]));
                o1[j2] = cvt_bf(g); s += g*g;
            }
#pragma unroll
            for (int j2 = 0; j2 < 8; ++j2) {
                float g = Tsm[erow*LDEY + ec0 + 8 + j2] * siluf_(__bfloat162float(zB[j2]));
                o2[j2] = cvt_bf(g); s += g*g;
            }
            size_t grow = rbase + erow;
            *(bf16x8*)(y16 + grow*DINNER + h*HEADDIM + ec0)     = o1;
            *(bf16x8*)(y16 + grow*DINNER + h*HEADDIM + ec0 + 8) = o2;
            s += __shfl_xor(s, 1); s += __shfl_xor(s, 2);
            if ((tid & 3) == 0)
                atomicAdd(rowsq + grow, s);
        }
        // no trailing barrier: next iteration's first __syncthreads orders
        // Tsm reads (all waves must pass it) before the next Tsm write.
    }
}

extern "C" void kernel_launch(void* const* d_in, const int* in_sizes, int n_in,
                              void* d_out, int out_size, void* d_ws, size_t ws_size,
                              hipStream_t stream)
{
    const float* feature = (const float*)d_in[0];
    const float* gate1   = (const float*)d_in[1];
    const float* in_w    = (const float*)d_in[2];
    const float* conv_w  = (const float*)d_in[3];
    const float* conv_b  = (const float*)d_in[4];
    const float* dt_bias = (const float*)d_in[5];
    const float* A_log   = (const float*)d_in[6];
    const float* Dp      = (const float*)d_in[7];
    const float* norm_w  = (const float*)d_in[8];
    const float* out_w   = (const float*)d_in[9];
    float* out = (float*)d_out;

    // workspace layout — ~161 MB (< 256 MiB)
    char* p = (char*)d_ws;
    __hip_bfloat16* z16   = (__hip_bfloat16*)p; p += (size_t)ROWS*DINNER*2;  // 25.2 MB
    __hip_bfloat16* xbc16 = (__hip_bfloat16*)p; p += (size_t)ROWS*DXBC*2;    // 29.4 MB
    __hip_bfloat16* x_t   = (__hip_bfloat16*)p; p += (size_t)ROWS*DINNER*2;  // 25.2 MB
    __hip_bfloat16* B_n   = (__hip_bfloat16*)p; p += (size_t)ROWS*DSTATE*2;  // 2.1 MB
    __hip_bfloat16* B_t   = (__hip_bfloat16*)p; p += (size_t)ROWS*DSTATE*2;  // 2.1 MB
    __hip_bfloat16* C_n   = (__hip_bfloat16*)p; p += (size_t)ROWS*DSTATE*2;  // 2.1 MB
    float* dtb    = (float*)p;            p += (size_t)ROWS*NHEADS*4;        // 0.8 MB
    float* acum   = (float*)p;            p += (size_t)B_SZ*NHEADS*NCHUNK*CHUNK*4; // 0.8 MB
    float* rowsq  = (float*)p;            p += (size_t)ROWS*4;               // 32 KB
    __hip_bfloat16* CB16 = (__hip_bfloat16*)p; p += (size_t)B_SZ*NCHUNK*CHUNK*CHUNK*2; // 2.1 MB
    __hip_bfloat16* states = (__hip_bfloat16*)p; p += (size_t)B_SZ*NCHUNK*NHEADS*HEADDIM*DSTATE*2; // 25.2 MB
    __hip_bfloat16* y16  = (__hip_bfloat16*)p; p += (size_t)ROWS*DINNER*2;   // 25.2 MB
    __hip_bfloat16* fbf  = (__hip_bfloat16*)p; p += (size_t)ROWS*DMODEL*2;   // 12.6 MB
    __hip_bfloat16* wbf  = (__hip_bfloat16*)p; p += (size_t)NPAD1*DMODEL*2;  //  5.3 MB
    __hip_bfloat16* owbf = (__hip_bfloat16*)p; p += (size_t)DMODEL*DINNER*2; //  2.4 MB

    cast_all<<<(NV1+NV2+NV3+NVR+255)/256, 256, 0, stream>>>(feature, in_w, out_w, norm_w,
                                                            fbf, wbf, owbf, rowsq);

    gemm1_mfma<<<27*32, 512, 0, stream>>>(fbf, wbf, z16, xbc16, dtb, dt_bias);
    conv_scan_k<<<dim3(14 + NHEADS, 32, B_SZ), 512, 0, stream>>>(
        xbc16, conv_w, conv_b, x_t, B_n, B_t, C_n, dtb, A_log, acum);
    cbst_k<<<64 + B_SZ*NHEADS*NCHUNK, 256, 0, stream>>>(
        B_n, C_n, CB16, x_t, B_t, dtb, acum, states);
    recur_k<<<B_SZ*NHEADS*16, 64, 0, stream>>>(states, acum);
    y_mfma<<<512, 512, 0, stream>>>(x_t, z16, C_n, CB16, states,
                                    dtb, acum, Dp, y16, rowsq);
    gemm2_mfma<<<6*64, 256, 0, stream>>>(y16, owbf, out, gate1, feature, rowsq);
}